// Round 6
// baseline (1219.818 us; speedup 1.0000x reference)
//
#include <hip/hip_runtime.h>

#define Tn 2048
#define Dn 2048
#define Hn 32

typedef float f32x4 __attribute__((ext_vector_type(4)));
typedef __bf16 bf16x8 __attribute__((ext_vector_type(8)));
typedef __bf16 bf16x4 __attribute__((ext_vector_type(4)));

// ---- fast wave-64 sum: DPP row reductions (VALU) + readlane, no DS pipe ----
template <int CTRL>
__device__ __forceinline__ float dpp_add(float x) {
  int xi = __builtin_bit_cast(int, x);
  int sh = __builtin_amdgcn_update_dpp(0, xi, CTRL, 0xf, 0xf, true);
  return x + __builtin_bit_cast(float, sh);
}
__device__ __forceinline__ float rdlane(float x, int l) {
  int xi = __builtin_bit_cast(int, x);
  return __builtin_bit_cast(float, __builtin_amdgcn_readlane(xi, l));
}
__device__ __forceinline__ float waveSum(float v) {
  v = dpp_add<0x111>(v);
  v = dpp_add<0x112>(v);
  v = dpp_add<0x114>(v);
  v = dpp_add<0x118>(v);
  return (rdlane(v, 15) + rdlane(v, 31)) + (rdlane(v, 47) + rdlane(v, 63));
}
// two independent reductions, DPP chains interleaved for ILP
__device__ __forceinline__ void waveSum2(float a, float b, float& ra, float& rb) {
  a = dpp_add<0x111>(a); b = dpp_add<0x111>(b);
  a = dpp_add<0x112>(a); b = dpp_add<0x112>(b);
  a = dpp_add<0x114>(a); b = dpp_add<0x114>(b);
  a = dpp_add<0x118>(a); b = dpp_add<0x118>(b);
  ra = (rdlane(a, 15) + rdlane(a, 31)) + (rdlane(a, 47) + rdlane(a, 63));
  rb = (rdlane(b, 15) + rdlane(b, 31)) + (rdlane(b, 47) + rdlane(b, 63));
}

__device__ __forceinline__ float sigm(float x) { return 1.f / (1.f + expf(-x)); }

__device__ __forceinline__ void gl_lds16(const void* g, void* l) {
  __builtin_amdgcn_global_load_lds(
      (__attribute__((address_space(1))) void*)(g),
      (__attribute__((address_space(3))) void*)(l), 16, 0, 0);
}

// ---------------- weight casts ----------------

__global__ __launch_bounds__(256) void castw3_kernel(
    const float* __restrict__ A, const float* __restrict__ B,
    const float* __restrict__ C, __bf16* __restrict__ o0,
    __bf16* __restrict__ o1, __bf16* __restrict__ o2) {
  const int z = blockIdx.y;
  const float* src = z == 0 ? A : (z == 1 ? B : C);
  __bf16* dst = z == 0 ? o0 : (z == 1 ? o1 : o2);
  const size_t i4 = (size_t)blockIdx.x * 256 + threadIdx.x;
  f32x4 v = *(const f32x4*)(src + i4 * 4);
  bf16x4 o;
  o[0] = (__bf16)v[0]; o[1] = (__bf16)v[1]; o[2] = (__bf16)v[2]; o[3] = (__bf16)v[3];
  ((bf16x4*)dst)[i4] = o;
}

__global__ __launch_bounds__(256) void cast1_kernel(
    const float* __restrict__ src, __bf16* __restrict__ dst) {
  const size_t i4 = (size_t)blockIdx.x * 256 + threadIdx.x;
  f32x4 v = *(const f32x4*)(src + i4 * 4);
  bf16x4 o;
  o[0] = (__bf16)v[0]; o[1] = (__bf16)v[1]; o[2] = (__bf16)v[2]; o[3] = (__bf16)v[3];
  ((bf16x4*)dst)[i4] = o;
}

__global__ __launch_bounds__(256) void castT_kernel(
    const float* __restrict__ w2, const float* __restrict__ a2,
    const float* __restrict__ v2, const float* __restrict__ g2,
    __bf16* __restrict__ w2T, __bf16* __restrict__ a2T,
    __bf16* __restrict__ v2T, __bf16* __restrict__ g2T) {
  const int i = blockIdx.x;   // D index
  const int k = threadIdx.x;
  if (k < 64)  w2T[(size_t)i * 64 + k]  = (__bf16)w2[(size_t)k * Dn + i];
  if (k < 64)  a2T[(size_t)i * 64 + k]  = (__bf16)a2[(size_t)k * Dn + i];
  if (k < 32)  v2T[(size_t)i * 32 + k]  = (__bf16)v2[(size_t)k * Dn + i];
  if (k < 128) g2T[(size_t)i * 128 + k] = (__bf16)g2[(size_t)k * Dn + i];
}

// ---------------- layernorm (ln1) ----------------

__global__ __launch_bounds__(256) void ln_kernel(
    const float* __restrict__ x, const float* __restrict__ lw,
    const float* __restrict__ lb, __bf16* __restrict__ xn,
    float* __restrict__ xn_last) {
  __shared__ float red[8];
  const int t = blockIdx.x, tid = threadIdx.x;
  const int lane = tid & 63, wv = tid >> 6;
  const float* xr = x + (size_t)t * Dn;
  float v[8];
  float s = 0.f;
#pragma unroll
  for (int c = 0; c < 8; ++c) { v[c] = xr[tid + c * 256]; s += v[c]; }
  s = waveSum(s);
  if (lane == 0) red[wv] = s;
  __syncthreads();
  const float mu = (red[0] + red[1] + red[2] + red[3]) * (1.f / (float)Dn);
  float q = 0.f;
#pragma unroll
  for (int c = 0; c < 8; ++c) { float d0 = v[c] - mu; q += d0 * d0; }
  q = waveSum(q);
  if (lane == 0) red[4 + wv] = q;
  __syncthreads();
  const float var = (red[4] + red[5] + red[6] + red[7]) * (1.f / (float)Dn);
  const float rstd = rsqrtf(var + 1e-5f);
#pragma unroll
  for (int c = 0; c < 8; ++c) {
    const int d = tid + c * 256;
    const float y = (v[c] - mu) * rstd * lw[d] + lb[d];
    xn[(size_t)t * Dn + d] = (__bf16)y;
    if (t == Tn - 1) xn_last[d] = y;
  }
}

// ---------------- token-shift mix -> 6 bf16 operands ----------------

__global__ __launch_bounds__(256) void mix_kernel(
    const __bf16* __restrict__ xn, const float* __restrict__ state1,
    const float* __restrict__ cr, const float* __restrict__ cw,
    const float* __restrict__ ck, const float* __restrict__ cv,
    const float* __restrict__ ca, const float* __restrict__ cg,
    __bf16* __restrict__ br, __bf16* __restrict__ bw, __bf16* __restrict__ bk,
    __bf16* __restrict__ bv, __bf16* __restrict__ ba, __bf16* __restrict__ bg) {
  const size_t i4 = (size_t)blockIdx.x * 256 + threadIdx.x;  // quad index
  const int t = (int)(i4 >> 9);
  const int d = (int)(i4 & 511) * 4;
  const bf16x4 cb = ((const bf16x4*)xn)[i4];
  f32x4 cur;
#pragma unroll
  for (int e = 0; e < 4; ++e) cur[e] = (float)cb[e];
  f32x4 prv;
  if (t == 0) {
    prv = *(const f32x4*)(state1 + d);
  } else {
    const bf16x4 pb = ((const bf16x4*)xn)[i4 - 512];
#pragma unroll
    for (int e = 0; e < 4; ++e) prv[e] = (float)pb[e];
  }
  const f32x4 sx = prv - cur;
  auto mix1 = [&](const float* c, __bf16* o) {
    const f32x4 cc = *(const f32x4*)(c + d);
    bf16x4 ob;
#pragma unroll
    for (int e = 0; e < 4; ++e) ob[e] = (__bf16)(cur[e] + sx[e] * cc[e]);
    ((bf16x4*)o)[i4] = ob;
  };
  mix1(cr, br); mix1(cw, bw); mix1(ck, bk);
  mix1(cv, bv); mix1(ca, ba); mix1(cg, bg);
}

// ---------------- MFMA GEMM tile core: C[m,n] = sum_k A[m,k]*B[n,k] ----------------

__device__ __forceinline__ void gemm_tile(const __bf16* __restrict__ A,
                                          const __bf16* __restrict__ B,
                                          int K, int row0, int col0,
                                          f32x4 (&acc)[4][4]) {
  __shared__ __attribute__((aligned(16))) __bf16 As[4096];
  __shared__ __attribute__((aligned(16))) __bf16 Bs[4096];
  const int tid = threadIdx.x;
  const int lane = tid & 63, wid = tid >> 6;
  const int wm = (wid >> 1) * 64, wn = (wid & 1) * 64;
  const int lr = lane & 15, lk = (lane >> 4) * 8;
  for (int kt = 0; kt < K; kt += 32) {
#pragma unroll
    for (int it = 0; it < 2; ++it) {
      const int L = it * 256 + tid;
      const int rr = L >> 2, kc = (L & 3) * 8;
      const int lb = (it * 256 + wid * 64) * 8;
      gl_lds16(A + (size_t)(row0 + rr) * K + (kt + kc), &As[lb]);
      gl_lds16(B + (size_t)(col0 + rr) * K + (kt + kc), &Bs[lb]);
    }
    __syncthreads();
    bf16x8 af[4], bfv[4];
#pragma unroll
    for (int mf = 0; mf < 4; ++mf)
      af[mf] = *(const bf16x8*)&As[(wm + mf * 16 + lr) * 32 + lk];
#pragma unroll
    for (int nf = 0; nf < 4; ++nf)
      bfv[nf] = *(const bf16x8*)&Bs[(wn + nf * 16 + lr) * 32 + lk];
#pragma unroll
    for (int mf = 0; mf < 4; ++mf)
#pragma unroll
      for (int nf = 0; nf < 4; ++nf)
        acc[mf][nf] = __builtin_amdgcn_mfma_f32_16x16x32_bf16(
            af[mf], bfv[nf], acc[mf][nf], 0, 0, 0);
    __syncthreads();
  }
}

// r/k/v fused (z selects), bf16 outputs
__global__ __launch_bounds__(256) void gemm3_kernel(
    const __bf16* __restrict__ A0, const __bf16* __restrict__ A1,
    const __bf16* __restrict__ A2, const __bf16* __restrict__ B0,
    const __bf16* __restrict__ B1, const __bf16* __restrict__ B2,
    __bf16* __restrict__ C0, __bf16* __restrict__ C1, __bf16* __restrict__ C2) {
  const int z = blockIdx.z;
  const __bf16* A = z == 0 ? A0 : (z == 1 ? A1 : A2);
  const __bf16* B = z == 0 ? B0 : (z == 1 ? B1 : B2);
  __bf16* C = z == 0 ? C0 : (z == 1 ? C1 : C2);
  const int row0 = blockIdx.x * 128, col0 = blockIdx.y * 128;
  f32x4 acc[4][4] = {};
  gemm_tile(A, B, Dn, row0, col0, acc);
  const int lane = threadIdx.x & 63, wid = threadIdx.x >> 6;
  const int wm = (wid >> 1) * 64, wn = (wid & 1) * 64;
#pragma unroll
  for (int mf = 0; mf < 4; ++mf) {
    const int r0 = row0 + wm + mf * 16 + ((lane >> 4) << 2);
#pragma unroll
    for (int nf = 0; nf < 4; ++nf) {
      const int c0 = col0 + wn + nf * 16 + (lane & 15);
#pragma unroll
      for (int rg = 0; rg < 4; ++rg)
        C[(size_t)(r0 + rg) * Dn + c0] = (__bf16)acc[mf][nf][rg];
    }
  }
}

// LoRA stage-2 fused (z: 0=w decay, 1=a, 2=v-blend-gate, 3=g), bf16 outputs
__global__ __launch_bounds__(256) void gemm_s2_kernel(
    const __bf16* __restrict__ Aw, const __bf16* __restrict__ Aa,
    const __bf16* __restrict__ Av, const __bf16* __restrict__ Ag,
    const __bf16* __restrict__ Bw, const __bf16* __restrict__ Ba,
    const __bf16* __restrict__ Bv, const __bf16* __restrict__ Bg,
    const float* __restrict__ w0, const float* __restrict__ a0,
    const float* __restrict__ v0, __bf16* __restrict__ Cw,
    __bf16* __restrict__ Ca, __bf16* __restrict__ Cv, __bf16* __restrict__ Cg) {
  const int z = blockIdx.z;
  const __bf16* A = z == 0 ? Aw : (z == 1 ? Aa : (z == 2 ? Av : Ag));
  const __bf16* B = z == 0 ? Bw : (z == 1 ? Ba : (z == 2 ? Bv : Bg));
  const float* bias = z == 0 ? w0 : (z == 1 ? a0 : (z == 2 ? v0 : (const float*)0));
  __bf16* C = z == 0 ? Cw : (z == 1 ? Ca : (z == 2 ? Cv : Cg));
  const int K = z == 0 ? 64 : (z == 1 ? 64 : (z == 2 ? 32 : 128));
  const int row0 = blockIdx.x * 128, col0 = blockIdx.y * 128;
  f32x4 acc[4][4] = {};
  gemm_tile(A, B, K, row0, col0, acc);
  const int lane = threadIdx.x & 63, wid = threadIdx.x >> 6;
  const int wm = (wid >> 1) * 64, wn = (wid & 1) * 64;
#pragma unroll
  for (int mf = 0; mf < 4; ++mf) {
    const int r0 = row0 + wm + mf * 16 + ((lane >> 4) << 2);
#pragma unroll
    for (int nf = 0; nf < 4; ++nf) {
      const int c0 = col0 + wn + nf * 16 + (lane & 15);
#pragma unroll
      for (int rg = 0; rg < 4; ++rg) {
        float val = acc[mf][nf][rg];
        if (z == 0)      val = expf(-0.606531f * sigm(val + bias[c0]));
        else if (z < 3)  val = sigm(val + bias[c0]);
        C[(size_t)(r0 + rg) * Dn + c0] = (__bf16)val;
      }
    }
  }
}

// W_o with residual add, fp32 output
__global__ __launch_bounds__(256) void gemm_wo_kernel(
    const __bf16* __restrict__ A, const __bf16* __restrict__ B,
    const float* __restrict__ xres, float* __restrict__ C) {
  const int row0 = blockIdx.x * 128, col0 = blockIdx.y * 128;
  f32x4 acc[4][4] = {};
  gemm_tile(A, B, Dn, row0, col0, acc);
  const int lane = threadIdx.x & 63, wid = threadIdx.x >> 6;
  const int wm = (wid >> 1) * 64, wn = (wid & 1) * 64;
#pragma unroll
  for (int mf = 0; mf < 4; ++mf) {
    const int r0 = row0 + wm + mf * 16 + ((lane >> 4) << 2);
#pragma unroll
    for (int nf = 0; nf < 4; ++nf) {
      const int c0 = col0 + wn + nf * 16 + (lane & 15);
#pragma unroll
      for (int rg = 0; rg < 4; ++rg)
        C[(size_t)(r0 + rg) * Dn + c0] =
            acc[mf][nf][rg] + xres[(size_t)(r0 + rg) * Dn + c0];
    }
  }
}

// ---------------- LoRA stage-1 (skinny, fp32 accum, 4 paths fused) ----------------

__global__ __launch_bounds__(256) void lora1_kernel(
    const __bf16* __restrict__ Xw, const __bf16* __restrict__ Xa,
    const __bf16* __restrict__ Xv, const __bf16* __restrict__ Xg,
    const float* __restrict__ Uw, const float* __restrict__ Ua,
    const float* __restrict__ Uv, const float* __restrict__ Ug,
    __bf16* __restrict__ Yw, __bf16* __restrict__ Ya,
    __bf16* __restrict__ Yv, __bf16* __restrict__ Yg) {
  __shared__ __bf16 xs[8][2048];
  const int path = blockIdx.y;
  const __bf16* X = path == 0 ? Xw : (path == 1 ? Xa : (path == 2 ? Xv : Xg));
  const float* U  = path == 0 ? Uw : (path == 1 ? Ua : (path == 2 ? Uv : Ug));
  __bf16* Y       = path == 0 ? Yw : (path == 1 ? Ya : (path == 2 ? Yv : Yg));
  const int R  = path == 0 ? 64 : (path == 1 ? 64 : (path == 2 ? 32 : 128));
  const int sh = path == 2 ? 3 : (path == 3 ? 1 : 2);   // log2(256/R)
  const int TPO = 1 << sh;
  const int t0 = blockIdx.x * 8;
  const int tid = threadIdx.x;
  for (int c = 0; c < 64; ++c) {
    const int e = c * 256 + tid;
    xs[e >> 11][e & 2047] = X[(size_t)t0 * Dn + e];
  }
  __syncthreads();
  const int j = tid >> sh, p = tid & (TPO - 1);
  float acc[8] = {0.f, 0.f, 0.f, 0.f, 0.f, 0.f, 0.f, 0.f};
  for (int d = p; d < 2048; d += TPO) {
    const float u = U[(size_t)d * R + j];
    const __bf16* xc = &xs[0][d];
#pragma unroll
    for (int rr = 0; rr < 8; ++rr) acc[rr] += (float)xc[rr * 2048] * u;
  }
  for (int m = TPO >> 1; m; m >>= 1) {
#pragma unroll
    for (int rr = 0; rr < 8; ++rr) acc[rr] += __shfl_xor(acc[rr], m);
  }
  if (p == 0) {
#pragma unroll
    for (int rr = 0; rr < 8; ++rr) {
      float y = acc[rr];
      if (path == 0) y = tanhf(y);
      else if (path == 3) y = sigm(y);
      Y[(size_t)(t0 + rr) * R + j] = (__bf16)y;
    }
  }
}

// ---------------- prep: v-blend, kk-norm, k-mod, ab, wr, dots ----------------

__global__ __launch_bounds__(256) void prep_kernel(
    __bf16* r, __bf16* k, __bf16* v,
    const __bf16* __restrict__ a, const __bf16* __restrict__ vb,
    const __bf16* __restrict__ wd,
    const float* __restrict__ v_first, const float* __restrict__ k_k,
    const float* __restrict__ k_a, const float* __restrict__ r_k,
    __bf16* __restrict__ kk_out, __bf16* __restrict__ ab_out,
    float* __restrict__ dot_out, float* __restrict__ krd_out,
    float* __restrict__ abrd_out) {
  const int t = blockIdx.x;
  const int lane = threadIdx.x & 63, wv = threadIdx.x >> 6;
#pragma unroll 1
  for (int c = 0; c < 8; ++c) {
    const int d = c * 256 + wv * 64 + lane;
    const size_t idx = (size_t)t * Dn + d;
    const float rv = (float)r[idx];
    const float kvv = (float)k[idx];
    const float kh = kvv * k_k[d];
    const float nrm = sqrtf(waveSum(kh * kh)) + 1e-6f;
    const float kkv = kh / nrm;
    const float av = (float)a[idx];
    float vv = (float)v[idx];
    vv = vv + (v_first[idx] - vv) * (float)vb[idx];
    const float kfv = kvv * (1.f + (av - 1.f) * k_a[d]);
    const float abv = kkv * av;
    const float wvv = (float)wd[idx];
    const float dt = waveSum(rv * kfv * r_k[d]);
    const float krdv = waveSum(rv * kfv);
    const float abrdv = waveSum(rv * abv);
    kk_out[idx] = (__bf16)kkv;
    ab_out[idx] = (__bf16)abv;
    k[idx] = (__bf16)kfv;
    v[idx] = (__bf16)vv;
    r[idx] = (__bf16)(wvv * rv);   // wr = w * r (in-place over r)
    if (lane == 0) {
      const int h = d >> 6;
      dot_out[t * Hn + h] = dt;
      krd_out[(size_t)h * Tn + t] = krdv;
      abrd_out[(size_t)h * Tn + t] = abrdv;
    }
  }
}

// ---------------- transpose [T][D] -> [D][T] for 6 arrays ----------------

__global__ __launch_bounds__(256) void transp_kernel(
    const __bf16* __restrict__ i0, const __bf16* __restrict__ i1,
    const __bf16* __restrict__ i2, const __bf16* __restrict__ i3,
    const __bf16* __restrict__ i4, const __bf16* __restrict__ i5,
    __bf16* __restrict__ o0, __bf16* __restrict__ o1,
    __bf16* __restrict__ o2, __bf16* __restrict__ o3,
    __bf16* __restrict__ o4, __bf16* __restrict__ o5) {
  const int z = blockIdx.z;
  const __bf16* in = z == 0 ? i0 : (z == 1 ? i1 : (z == 2 ? i2 :
                     (z == 3 ? i3 : (z == 4 ? i4 : i5))));
  __bf16* out      = z == 0 ? o0 : (z == 1 ? o1 : (z == 2 ? o2 :
                     (z == 3 ? o3 : (z == 4 ? o4 : o5))));
  const int d0 = blockIdx.x * 64, t0 = blockIdx.y * 64;
  __shared__ __bf16 tile[64][65];
  const int tid = threadIdx.x;
#pragma unroll
  for (int m = 0; m < 4; ++m) {
    const int e4 = m * 256 + tid;
    const int r = e4 >> 4, c = (e4 & 15) * 4;   // r: t-local, c: d-local
    const bf16x4 vv = *(const bf16x4*)(in + (size_t)(t0 + r) * Dn + d0 + c);
    tile[r][c] = vv[0]; tile[r][c + 1] = vv[1];
    tile[r][c + 2] = vv[2]; tile[r][c + 3] = vv[3];
  }
  __syncthreads();
#pragma unroll
  for (int m = 0; m < 4; ++m) {
    const int e4 = m * 256 + tid;
    const int r = e4 >> 4, c = (e4 & 15) * 4;   // r: d-local, c: t-local
    bf16x4 vv;
    vv[0] = tile[c][r]; vv[1] = tile[c + 1][r];
    vv[2] = tile[c + 2][r]; vv[3] = tile[c + 3][r];
    *(bf16x4*)(out + (size_t)(d0 + r) * Tn + t0 + c) = vv;
  }
}

// ---------------- sequential scan: wave per (h,i), [D][T] streams ----------------

__global__ __launch_bounds__(256) void scan_kernel(
    const __bf16* __restrict__ kkT, const __bf16* __restrict__ wrT,
    const __bf16* __restrict__ wT, const __bf16* __restrict__ kT,
    const __bf16* __restrict__ abT, const __bf16* __restrict__ vT,
    const float* __restrict__ krd, const float* __restrict__ abrd,
    const float* __restrict__ st_in, __bf16* __restrict__ xo,
    float* __restrict__ st_out) {
  const int h = blockIdx.x;
  const int i = blockIdx.y * 4 + (threadIdx.x >> 6);
  const int j = threadIdx.x & 63;
  float S = st_in[(size_t)h * 4096 + i * 64 + j];
  const size_t lb = (size_t)(h * 64 + j) * Tn;   // lane stream base
  const size_t vbse = (size_t)(h * 64 + i) * Tn; // wave-uniform v stream
  const float* krdh = krd + (size_t)h * Tn;
  const float* abrdh = abrd + (size_t)h * Tn;
  __bf16* xop = xo + h * 64 + i;

  bf16x8 c_kk = *(const bf16x8*)(kkT + lb);
  bf16x8 c_wr = *(const bf16x8*)(wrT + lb);
  bf16x8 c_w  = *(const bf16x8*)(wT + lb);
  bf16x8 c_k  = *(const bf16x8*)(kT + lb);
  bf16x8 c_ab = *(const bf16x8*)(abT + lb);
  bf16x8 c_v  = *(const bf16x8*)(vT + vbse);
  f32x4 c_kr0 = *(const f32x4*)(krdh);
  f32x4 c_kr1 = *(const f32x4*)(krdh + 4);
  f32x4 c_ar0 = *(const f32x4*)(abrdh);
  f32x4 c_ar1 = *(const f32x4*)(abrdh + 4);

  for (int t0 = 0; t0 < Tn; t0 += 8) {
    const int tn0 = (t0 + 8 < Tn) ? t0 + 8 : t0;   // clamp: redundant reload at end
    const bf16x8 n_kk = *(const bf16x8*)(kkT + lb + tn0);
    const bf16x8 n_wr = *(const bf16x8*)(wrT + lb + tn0);
    const bf16x8 n_w  = *(const bf16x8*)(wT + lb + tn0);
    const bf16x8 n_k  = *(const bf16x8*)(kT + lb + tn0);
    const bf16x8 n_ab = *(const bf16x8*)(abT + lb + tn0);
    const bf16x8 n_v  = *(const bf16x8*)(vT + vbse + tn0);
    const f32x4 n_kr0 = *(const f32x4*)(krdh + tn0);
    const f32x4 n_kr1 = *(const f32x4*)(krdh + tn0 + 4);
    const f32x4 n_ar0 = *(const f32x4*)(abrdh + tn0);
    const f32x4 n_ar1 = *(const f32x4*)(abrdh + tn0 + 4);
#pragma unroll
    for (int e = 0; e < 8; ++e) {
      const float kkv = (float)c_kk[e], wrv = (float)c_wr[e];
      const float wv = (float)c_w[e], kv = (float)c_k[e], abv = (float)c_ab[e];
      const float vt = (float)c_v[e];
      const float krdv = (e < 4) ? c_kr0[e] : c_kr1[e - 4];
      const float abrdv = (e < 4) ? c_ar0[e] : c_ar1[e - 4];
      float sa, A;
      waveSum2(S * kkv, S * wrv, sa, A);
      const float o = A + vt * krdv - sa * abrdv;
      S = (S * wv + vt * kv) - sa * abv;
      if (j == 0) xop[(size_t)(t0 + e) * Dn] = (__bf16)o;
    }
    c_kk = n_kk; c_wr = n_wr; c_w = n_w; c_k = n_k; c_ab = n_ab; c_v = n_v;
    c_kr0 = n_kr0; c_kr1 = n_kr1; c_ar0 = n_ar0; c_ar1 = n_ar1;
  }
  st_out[(size_t)h * 4096 + i * 64 + j] = S;
}

// ---------------- post: per-head LN + bonus + gate -> bf16 ----------------

__global__ __launch_bounds__(256) void post_kernel(
    const __bf16* __restrict__ xo, const __bf16* __restrict__ v,
    const __bf16* __restrict__ g, const float* __restrict__ dot,
    const float* __restrict__ lnw, const float* __restrict__ lnb,
    __bf16* __restrict__ out) {
  const int t = blockIdx.x;
  const int lane = threadIdx.x & 63, wv = threadIdx.x >> 6;
#pragma unroll 1
  for (int c = 0; c < 8; ++c) {
    const int d = c * 256 + wv * 64 + lane;
    const size_t idx = (size_t)t * Dn + d;
    const float val = (float)xo[idx];
    const float mu = waveSum(val) * (1.f / 64.f);
    const float ctr = val - mu;
    const float var = waveSum(ctr * ctr) * (1.f / 64.f);
    float y = ctr * rsqrtf(var + 0.00064f);
    y = y * lnw[d] + lnb[d];
    const float res = (y + dot[t * Hn + (d >> 6)] * (float)v[idx]) * (float)g[idx];
    out[idx] = (__bf16)res;
  }
}

// ---------------- launcher ----------------

extern "C" void kernel_launch(void* const* d_in, const int* in_sizes, int n_in,
                              void* d_out, int out_size, void* d_ws, size_t ws_size,
                              hipStream_t stream) {
  (void)in_sizes; (void)n_in; (void)out_size; (void)ws_size;
  const float* x       = (const float*)d_in[0];
  const float* state1  = (const float*)d_in[1];
  const float* state2  = (const float*)d_in[2];
  const float* v_first = (const float*)d_in[3];
  const float* ln1_w   = (const float*)d_in[4];
  const float* ln1_b   = (const float*)d_in[5];
  const float* x_r     = (const float*)d_in[6];
  const float* x_w     = (const float*)d_in[7];
  const float* x_k     = (const float*)d_in[8];
  const float* x_v     = (const float*)d_in[9];
  const float* x_a     = (const float*)d_in[10];
  const float* x_g     = (const float*)d_in[11];
  const float* W_r     = (const float*)d_in[12];
  const float* W_k     = (const float*)d_in[13];
  const float* W_v     = (const float*)d_in[14];
  const float* W_o     = (const float*)d_in[15];
  const float* w1      = (const float*)d_in[16];
  const float* w2      = (const float*)d_in[17];
  const float* w0      = (const float*)d_in[18];
  const float* a1      = (const float*)d_in[19];
  const float* a2      = (const float*)d_in[20];
  const float* a0      = (const float*)d_in[21];
  const float* v1      = (const float*)d_in[22];
  const float* v2      = (const float*)d_in[23];
  const float* v0      = (const float*)d_in[24];
  const float* g1      = (const float*)d_in[25];
  const float* g2      = (const float*)d_in[26];
  const float* k_k     = (const float*)d_in[27];
  const float* k_a     = (const float*)d_in[28];
  const float* r_k     = (const float*)d_in[29];
  const float* lnx_w   = (const float*)d_in[30];
  const float* lnx_b   = (const float*)d_in[31];

  char* p = (char*)d_ws;
  const size_t MB = 1ull << 20;
  // 14 slots x 8 MB = 112 MB + ~3.1 MB smalls. Lifetime map:
  //  S0: xn(ln->mix)        -> kkT(transp->scan)
  //  S1: xr(mix->gemm3)     -> Wo_b(cast1->gemm_wo)
  //  S2: xw(mix->lora1)     -> wdec(s2->prep,transp) -> xo_b(post->gemm_wo)
  //  S3: xk(mix->gemm3)     -> abuf(s2->prep)  -> wrT(transp->scan)
  //  S4: xv(mix->g3,lora1)  -> vbl(s2->prep)   -> wT(transp->scan)
  //  S5: xa(mix->lora1)     -> gbuf(s2->post)
  //  S6: xg(mix->lora1)     -> kkbuf(prep->transp) -> xobuf(scan->post)
  //  S7: Wr(castw3->gemm3)  -> abbuf(prep->transp)
  //  S8: Wk(castw3->gemm3)  -> kT(transp->scan)
  //  S9: Wv(castw3->gemm3)  -> abT(transp->scan)
  //  S10: rbuf(gemm3->prep, wr in-place ->transp)
  //  S11: kbuf(gemm3->prep in-place ->transp)
  //  S12: vbuf(gemm3->prep in-place ->transp, post)
  //  S13: vT(transp->scan)
  __bf16* xn    = (__bf16*)(p + 0 * MB);
  __bf16* kkT   = (__bf16*)(p + 0 * MB);
  __bf16* xr_b  = (__bf16*)(p + 8 * MB);
  __bf16* Wo_b  = (__bf16*)(p + 8 * MB);
  __bf16* xw_b  = (__bf16*)(p + 16 * MB);
  __bf16* wdec  = (__bf16*)(p + 16 * MB);
  __bf16* xo_b  = (__bf16*)(p + 16 * MB);
  __bf16* xk_b  = (__bf16*)(p + 24 * MB);
  __bf16* abuf  = (__bf16*)(p + 24 * MB);
  __bf16* wrT   = (__bf16*)(p + 24 * MB);
  __bf16* xv_b  = (__bf16*)(p + 32 * MB);
  __bf16* vbl   = (__bf16*)(p + 32 * MB);
  __bf16* wT    = (__bf16*)(p + 32 * MB);
  __bf16* xa_b  = (__bf16*)(p + 40 * MB);
  __bf16* gbuf  = (__bf16*)(p + 40 * MB);
  __bf16* xg_b  = (__bf16*)(p + 48 * MB);
  __bf16* kkbuf = (__bf16*)(p + 48 * MB);
  __bf16* xobuf = (__bf16*)(p + 48 * MB);
  __bf16* Wr_b  = (__bf16*)(p + 56 * MB);
  __bf16* abbuf = (__bf16*)(p + 56 * MB);
  __bf16* Wk_b  = (__bf16*)(p + 64 * MB);
  __bf16* kT    = (__bf16*)(p + 64 * MB);
  __bf16* Wv_b  = (__bf16*)(p + 72 * MB);
  __bf16* abT   = (__bf16*)(p + 72 * MB);
  __bf16* rbuf  = (__bf16*)(p + 80 * MB);
  __bf16* kbuf  = (__bf16*)(p + 88 * MB);
  __bf16* vbuf  = (__bf16*)(p + 96 * MB);
  __bf16* vT    = (__bf16*)(p + 104 * MB);
  char* q = p + 112 * MB;                   // smalls, ~3.1 MB
  __bf16* yw  = (__bf16*)q; q += (size_t)Tn * 64 * 2;
  __bf16* ya  = (__bf16*)q; q += (size_t)Tn * 64 * 2;
  __bf16* yv  = (__bf16*)q; q += (size_t)Tn * 32 * 2;
  __bf16* yg  = (__bf16*)q; q += (size_t)Tn * 128 * 2;
  __bf16* w2T = (__bf16*)q; q += (size_t)Dn * 64 * 2;
  __bf16* a2T = (__bf16*)q; q += (size_t)Dn * 64 * 2;
  __bf16* v2T = (__bf16*)q; q += (size_t)Dn * 32 * 2;
  __bf16* g2T = (__bf16*)q; q += (size_t)Dn * 128 * 2;
  float*  dot = (float*)q;  q += (size_t)Tn * Hn * 4;
  float*  krd = (float*)q;  q += (size_t)Hn * Tn * 4;
  float*  abrd= (float*)q;  q += (size_t)Hn * Tn * 4;

  float* out     = (float*)d_out;
  float* out_xnl = out + (size_t)Tn * Dn;
  float* out_st  = out_xnl + Dn;

  castw3_kernel<<<dim3(4096, 3), 256, 0, stream>>>(W_r, W_k, W_v, Wr_b, Wk_b, Wv_b);
  castT_kernel<<<2048, 256, 0, stream>>>(w2, a2, v2, g2, w2T, a2T, v2T, g2T);
  ln_kernel<<<2048, 256, 0, stream>>>(x, ln1_w, ln1_b, xn, out_xnl);
  mix_kernel<<<4096, 256, 0, stream>>>(xn, state1, x_r, x_w, x_k, x_v, x_a, x_g,
                                       xr_b, xw_b, xk_b, xv_b, xa_b, xg_b);
  gemm3_kernel<<<dim3(16, 16, 3), 256, 0, stream>>>(
      xr_b, xk_b, xv_b, Wr_b, Wk_b, Wv_b, rbuf, kbuf, vbuf);
  cast1_kernel<<<4096, 256, 0, stream>>>(W_o, Wo_b);  // S1 free after gemm3
  lora1_kernel<<<dim3(256, 4), 256, 0, stream>>>(
      xw_b, xa_b, xv_b, xg_b, w1, a1, v1, g1, yw, ya, yv, yg);
  gemm_s2_kernel<<<dim3(16, 16, 4), 256, 0, stream>>>(
      yw, ya, yv, yg, w2T, a2T, v2T, g2T, w0, a0, v0, wdec, abuf, vbl, gbuf);
  prep_kernel<<<2048, 256, 0, stream>>>(rbuf, kbuf, vbuf, abuf, vbl, wdec,
                                        v_first, k_k, k_a, r_k,
                                        kkbuf, abbuf, dot, krd, abrd);
  transp_kernel<<<dim3(32, 32, 6), 256, 0, stream>>>(
      kkbuf, rbuf, wdec, kbuf, abbuf, vbuf,
      kkT,   wrT,  wT,   kT,   abT,   vT);
  scan_kernel<<<dim3(32, 16), 256, 0, stream>>>(
      kkT, wrT, wT, kT, abT, vT, krd, abrd, state2, xobuf, out_st);
  post_kernel<<<2048, 256, 0, stream>>>(xobuf, vbuf, gbuf, dot, lnx_w, lnx_b, xo_b);
  gemm_wo_kernel<<<dim3(16, 16), 256, 0, stream>>>(xo_b, Wo_b, x, out);
}

// Round 7
// 934.492 us; speedup vs baseline: 1.3053x; 1.3053x over previous
//
#include <hip/hip_runtime.h>

#define Tn 2048
#define Dn 2048
#define Hn 32
#define Cn 32
#define NCH (Tn / Cn)

typedef float f32x4 __attribute__((ext_vector_type(4)));
typedef __bf16 bf16x8 __attribute__((ext_vector_type(8)));
typedef __bf16 bf16x4 __attribute__((ext_vector_type(4)));

// ---- fast wave-64 sum: DPP row reductions (VALU) + readlane ----
template <int CTRL>
__device__ __forceinline__ float dpp_add(float x) {
  int xi = __builtin_bit_cast(int, x);
  int sh = __builtin_amdgcn_update_dpp(0, xi, CTRL, 0xf, 0xf, true);
  return x + __builtin_bit_cast(float, sh);
}
__device__ __forceinline__ float rdlane(float x, int l) {
  int xi = __builtin_bit_cast(int, x);
  return __builtin_bit_cast(float, __builtin_amdgcn_readlane(xi, l));
}
__device__ __forceinline__ float waveSum(float v) {
  v = dpp_add<0x111>(v);
  v = dpp_add<0x112>(v);
  v = dpp_add<0x114>(v);
  v = dpp_add<0x118>(v);
  return (rdlane(v, 15) + rdlane(v, 31)) + (rdlane(v, 47) + rdlane(v, 63));
}

__device__ __forceinline__ float sigm(float x) { return 1.f / (1.f + expf(-x)); }

__device__ __forceinline__ void gl_lds16(const void* g, void* l) {
  __builtin_amdgcn_global_load_lds(
      (__attribute__((address_space(1))) void*)(g),
      (__attribute__((address_space(3))) void*)(l), 16, 0, 0);
}

// ---------------- weight casts ----------------

__global__ __launch_bounds__(256) void castw3_kernel(
    const float* __restrict__ A, const float* __restrict__ B,
    const float* __restrict__ C, __bf16* __restrict__ o0,
    __bf16* __restrict__ o1, __bf16* __restrict__ o2) {
  const int z = blockIdx.y;
  const float* src = z == 0 ? A : (z == 1 ? B : C);
  __bf16* dst = z == 0 ? o0 : (z == 1 ? o1 : o2);
  const size_t i4 = (size_t)blockIdx.x * 256 + threadIdx.x;
  f32x4 v = *(const f32x4*)(src + i4 * 4);
  bf16x4 o;
  o[0] = (__bf16)v[0]; o[1] = (__bf16)v[1]; o[2] = (__bf16)v[2]; o[3] = (__bf16)v[3];
  ((bf16x4*)dst)[i4] = o;
}

__global__ __launch_bounds__(256) void cast1_kernel(
    const float* __restrict__ src, __bf16* __restrict__ dst) {
  const size_t i4 = (size_t)blockIdx.x * 256 + threadIdx.x;
  f32x4 v = *(const f32x4*)(src + i4 * 4);
  bf16x4 o;
  o[0] = (__bf16)v[0]; o[1] = (__bf16)v[1]; o[2] = (__bf16)v[2]; o[3] = (__bf16)v[3];
  ((bf16x4*)dst)[i4] = o;
}

__global__ __launch_bounds__(256) void castT_kernel(
    const float* __restrict__ w2, const float* __restrict__ a2,
    const float* __restrict__ v2, const float* __restrict__ g2,
    __bf16* __restrict__ w2T, __bf16* __restrict__ a2T,
    __bf16* __restrict__ v2T, __bf16* __restrict__ g2T) {
  const int i = blockIdx.x;
  const int k = threadIdx.x;
  if (k < 64)  w2T[(size_t)i * 64 + k]  = (__bf16)w2[(size_t)k * Dn + i];
  if (k < 64)  a2T[(size_t)i * 64 + k]  = (__bf16)a2[(size_t)k * Dn + i];
  if (k < 32)  v2T[(size_t)i * 32 + k]  = (__bf16)v2[(size_t)k * Dn + i];
  if (k < 128) g2T[(size_t)i * 128 + k] = (__bf16)g2[(size_t)k * Dn + i];
}

// ---------------- layernorm (ln1) ----------------

__global__ __launch_bounds__(256) void ln_kernel(
    const float* __restrict__ x, const float* __restrict__ lw,
    const float* __restrict__ lb, __bf16* __restrict__ xn,
    float* __restrict__ xn_last) {
  __shared__ float red[8];
  const int t = blockIdx.x, tid = threadIdx.x;
  const int lane = tid & 63, wv = tid >> 6;
  const float* xr = x + (size_t)t * Dn;
  float v[8];
  float s = 0.f;
#pragma unroll
  for (int c = 0; c < 8; ++c) { v[c] = xr[tid + c * 256]; s += v[c]; }
  s = waveSum(s);
  if (lane == 0) red[wv] = s;
  __syncthreads();
  const float mu = (red[0] + red[1] + red[2] + red[3]) * (1.f / (float)Dn);
  float q = 0.f;
#pragma unroll
  for (int c = 0; c < 8; ++c) { float d0 = v[c] - mu; q += d0 * d0; }
  q = waveSum(q);
  if (lane == 0) red[4 + wv] = q;
  __syncthreads();
  const float var = (red[4] + red[5] + red[6] + red[7]) * (1.f / (float)Dn);
  const float rstd = rsqrtf(var + 1e-5f);
#pragma unroll
  for (int c = 0; c < 8; ++c) {
    const int d = tid + c * 256;
    const float y = (v[c] - mu) * rstd * lw[d] + lb[d];
    xn[(size_t)t * Dn + d] = (__bf16)y;
    if (t == Tn - 1) xn_last[d] = y;
  }
}

// ---------------- token-shift mix ----------------

__global__ __launch_bounds__(256) void mix_kernel(
    const __bf16* __restrict__ xn, const float* __restrict__ state1,
    const float* __restrict__ cr, const float* __restrict__ cw,
    const float* __restrict__ ck, const float* __restrict__ cv,
    const float* __restrict__ ca, const float* __restrict__ cg,
    __bf16* __restrict__ br, __bf16* __restrict__ bw, __bf16* __restrict__ bk,
    __bf16* __restrict__ bv, __bf16* __restrict__ ba, __bf16* __restrict__ bg) {
  const size_t i4 = (size_t)blockIdx.x * 256 + threadIdx.x;
  const int t = (int)(i4 >> 9);
  const int d = (int)(i4 & 511) * 4;
  const bf16x4 cb = ((const bf16x4*)xn)[i4];
  f32x4 cur;
#pragma unroll
  for (int e = 0; e < 4; ++e) cur[e] = (float)cb[e];
  f32x4 prv;
  if (t == 0) {
    prv = *(const f32x4*)(state1 + d);
  } else {
    const bf16x4 pb = ((const bf16x4*)xn)[i4 - 512];
#pragma unroll
    for (int e = 0; e < 4; ++e) prv[e] = (float)pb[e];
  }
  const f32x4 sx = prv - cur;
  auto mix1 = [&](const float* c, __bf16* o) {
    const f32x4 cc = *(const f32x4*)(c + d);
    bf16x4 ob;
#pragma unroll
    for (int e = 0; e < 4; ++e) ob[e] = (__bf16)(cur[e] + sx[e] * cc[e]);
    ((bf16x4*)o)[i4] = ob;
  };
  mix1(cr, br); mix1(cw, bw); mix1(ck, bk);
  mix1(cv, bv); mix1(ca, ba); mix1(cg, bg);
}

// ---------------- MFMA GEMM tile core ----------------

__device__ __forceinline__ void gemm_tile(const __bf16* __restrict__ A,
                                          const __bf16* __restrict__ B,
                                          int K, int row0, int col0,
                                          f32x4 (&acc)[4][4]) {
  __shared__ __attribute__((aligned(16))) __bf16 As[4096];
  __shared__ __attribute__((aligned(16))) __bf16 Bs[4096];
  const int tid = threadIdx.x;
  const int lane = tid & 63, wid = tid >> 6;
  const int wm = (wid >> 1) * 64, wn = (wid & 1) * 64;
  const int lr = lane & 15, lk = (lane >> 4) * 8;
  for (int kt = 0; kt < K; kt += 32) {
#pragma unroll
    for (int it = 0; it < 2; ++it) {
      const int L = it * 256 + tid;
      const int rr = L >> 2, kc = (L & 3) * 8;
      const int lb = (it * 256 + wid * 64) * 8;
      gl_lds16(A + (size_t)(row0 + rr) * K + (kt + kc), &As[lb]);
      gl_lds16(B + (size_t)(col0 + rr) * K + (kt + kc), &Bs[lb]);
    }
    __syncthreads();
    bf16x8 af[4], bfv[4];
#pragma unroll
    for (int mf = 0; mf < 4; ++mf)
      af[mf] = *(const bf16x8*)&As[(wm + mf * 16 + lr) * 32 + lk];
#pragma unroll
    for (int nf = 0; nf < 4; ++nf)
      bfv[nf] = *(const bf16x8*)&Bs[(wn + nf * 16 + lr) * 32 + lk];
#pragma unroll
    for (int mf = 0; mf < 4; ++mf)
#pragma unroll
      for (int nf = 0; nf < 4; ++nf)
        acc[mf][nf] = __builtin_amdgcn_mfma_f32_16x16x32_bf16(
            af[mf], bfv[nf], acc[mf][nf], 0, 0, 0);
    __syncthreads();
  }
}

__global__ __launch_bounds__(256) void gemm3_kernel(
    const __bf16* __restrict__ A0, const __bf16* __restrict__ A1,
    const __bf16* __restrict__ A2, const __bf16* __restrict__ B0,
    const __bf16* __restrict__ B1, const __bf16* __restrict__ B2,
    __bf16* __restrict__ C0, __bf16* __restrict__ C1, __bf16* __restrict__ C2) {
  const int z = blockIdx.z;
  const __bf16* A = z == 0 ? A0 : (z == 1 ? A1 : A2);
  const __bf16* B = z == 0 ? B0 : (z == 1 ? B1 : B2);
  __bf16* C = z == 0 ? C0 : (z == 1 ? C1 : C2);
  const int row0 = blockIdx.x * 128, col0 = blockIdx.y * 128;
  f32x4 acc[4][4] = {};
  gemm_tile(A, B, Dn, row0, col0, acc);
  const int lane = threadIdx.x & 63, wid = threadIdx.x >> 6;
  const int wm = (wid >> 1) * 64, wn = (wid & 1) * 64;
#pragma unroll
  for (int mf = 0; mf < 4; ++mf) {
    const int r0 = row0 + wm + mf * 16 + ((lane >> 4) << 2);
#pragma unroll
    for (int nf = 0; nf < 4; ++nf) {
      const int c0 = col0 + wn + nf * 16 + (lane & 15);
#pragma unroll
      for (int rg = 0; rg < 4; ++rg)
        C[(size_t)(r0 + rg) * Dn + c0] = (__bf16)acc[mf][nf][rg];
    }
  }
}

__global__ __launch_bounds__(256) void gemm_s2_kernel(
    const __bf16* __restrict__ Aw, const __bf16* __restrict__ Aa,
    const __bf16* __restrict__ Av, const __bf16* __restrict__ Ag,
    const __bf16* __restrict__ Bw, const __bf16* __restrict__ Ba,
    const __bf16* __restrict__ Bv, const __bf16* __restrict__ Bg,
    const float* __restrict__ w0, const float* __restrict__ a0,
    const float* __restrict__ v0, __bf16* __restrict__ Cw,
    __bf16* __restrict__ Ca, __bf16* __restrict__ Cv, __bf16* __restrict__ Cg) {
  const int z = blockIdx.z;
  const __bf16* A = z == 0 ? Aw : (z == 1 ? Aa : (z == 2 ? Av : Ag));
  const __bf16* B = z == 0 ? Bw : (z == 1 ? Ba : (z == 2 ? Bv : Bg));
  const float* bias = z == 0 ? w0 : (z == 1 ? a0 : (z == 2 ? v0 : (const float*)0));
  __bf16* C = z == 0 ? Cw : (z == 1 ? Ca : (z == 2 ? Cv : Cg));
  const int K = z == 0 ? 64 : (z == 1 ? 64 : (z == 2 ? 32 : 128));
  const int row0 = blockIdx.x * 128, col0 = blockIdx.y * 128;
  f32x4 acc[4][4] = {};
  gemm_tile(A, B, K, row0, col0, acc);
  const int lane = threadIdx.x & 63, wid = threadIdx.x >> 6;
  const int wm = (wid >> 1) * 64, wn = (wid & 1) * 64;
#pragma unroll
  for (int mf = 0; mf < 4; ++mf) {
    const int r0 = row0 + wm + mf * 16 + ((lane >> 4) << 2);
#pragma unroll
    for (int nf = 0; nf < 4; ++nf) {
      const int c0 = col0 + wn + nf * 16 + (lane & 15);
#pragma unroll
      for (int rg = 0; rg < 4; ++rg) {
        float val = acc[mf][nf][rg];
        if (z == 0)      val = expf(-0.606531f * sigm(val + bias[c0]));
        else if (z < 3)  val = sigm(val + bias[c0]);
        C[(size_t)(r0 + rg) * Dn + c0] = (__bf16)val;
      }
    }
  }
}

__global__ __launch_bounds__(256) void gemm_wo_kernel(
    const __bf16* __restrict__ A, const __bf16* __restrict__ B,
    const float* __restrict__ xres, float* __restrict__ C) {
  const int row0 = blockIdx.x * 128, col0 = blockIdx.y * 128;
  f32x4 acc[4][4] = {};
  gemm_tile(A, B, Dn, row0, col0, acc);
  const int lane = threadIdx.x & 63, wid = threadIdx.x >> 6;
  const int wm = (wid >> 1) * 64, wn = (wid & 1) * 64;
#pragma unroll
  for (int mf = 0; mf < 4; ++mf) {
    const int r0 = row0 + wm + mf * 16 + ((lane >> 4) << 2);
#pragma unroll
    for (int nf = 0; nf < 4; ++nf) {
      const int c0 = col0 + wn + nf * 16 + (lane & 15);
#pragma unroll
      for (int rg = 0; rg < 4; ++rg)
        C[(size_t)(r0 + rg) * Dn + c0] =
            acc[mf][nf][rg] + xres[(size_t)(r0 + rg) * Dn + c0];
    }
  }
}

// ---------------- LoRA stage-1 ----------------

__global__ __launch_bounds__(256) void lora1_kernel(
    const __bf16* __restrict__ Xw, const __bf16* __restrict__ Xa,
    const __bf16* __restrict__ Xv, const __bf16* __restrict__ Xg,
    const float* __restrict__ Uw, const float* __restrict__ Ua,
    const float* __restrict__ Uv, const float* __restrict__ Ug,
    __bf16* __restrict__ Yw, __bf16* __restrict__ Ya,
    __bf16* __restrict__ Yv, __bf16* __restrict__ Yg) {
  __shared__ __bf16 xs[8][2048];
  const int path = blockIdx.y;
  const __bf16* X = path == 0 ? Xw : (path == 1 ? Xa : (path == 2 ? Xv : Xg));
  const float* U  = path == 0 ? Uw : (path == 1 ? Ua : (path == 2 ? Uv : Ug));
  __bf16* Y       = path == 0 ? Yw : (path == 1 ? Ya : (path == 2 ? Yv : Yg));
  const int R  = path == 0 ? 64 : (path == 1 ? 64 : (path == 2 ? 32 : 128));
  const int sh = path == 2 ? 3 : (path == 3 ? 1 : 2);
  const int TPO = 1 << sh;
  const int t0 = blockIdx.x * 8;
  const int tid = threadIdx.x;
  for (int c = 0; c < 64; ++c) {
    const int e = c * 256 + tid;
    xs[e >> 11][e & 2047] = X[(size_t)t0 * Dn + e];
  }
  __syncthreads();
  const int j = tid >> sh, p = tid & (TPO - 1);
  float acc[8] = {0.f, 0.f, 0.f, 0.f, 0.f, 0.f, 0.f, 0.f};
  for (int d = p; d < 2048; d += TPO) {
    const float u = U[(size_t)d * R + j];
    const __bf16* xc = &xs[0][d];
#pragma unroll
    for (int rr = 0; rr < 8; ++rr) acc[rr] += (float)xc[rr * 2048] * u;
  }
  for (int m = TPO >> 1; m; m >>= 1) {
#pragma unroll
    for (int rr = 0; rr < 8; ++rr) acc[rr] += __shfl_xor(acc[rr], m);
  }
  if (p == 0) {
#pragma unroll
    for (int rr = 0; rr < 8; ++rr) {
      float y = acc[rr];
      if (path == 0) y = tanhf(y);
      else if (path == 3) y = sigm(y);
      Y[(size_t)(t0 + rr) * R + j] = (__bf16)y;
    }
  }
}

// ---------------- prep: v-blend, kk-norm, k-mod, ab, bonus dot ----------------

__global__ __launch_bounds__(256) void prep_kernel(
    const __bf16* __restrict__ r, __bf16* __restrict__ k, __bf16* __restrict__ v,
    const __bf16* __restrict__ a, const __bf16* __restrict__ vb,
    const float* __restrict__ v_first, const float* __restrict__ k_k,
    const float* __restrict__ k_a, const float* __restrict__ r_k,
    __bf16* __restrict__ kk_out, __bf16* __restrict__ ab_out,
    float* __restrict__ dot_out) {
  const int t = blockIdx.x;
  const int lane = threadIdx.x & 63, wv = threadIdx.x >> 6;
#pragma unroll 1
  for (int c = 0; c < 8; ++c) {
    const int d = c * 256 + wv * 64 + lane;
    const size_t idx = (size_t)t * Dn + d;
    const float kvv = (float)k[idx];
    const float kh = kvv * k_k[d];
    const float nrm = sqrtf(waveSum(kh * kh)) + 1e-6f;
    const float kkv = kh / nrm;
    const float av = (float)a[idx];
    float vv = (float)v[idx];
    vv = vv + (v_first[idx] - vv) * (float)vb[idx];
    const float kfv = kvv * (1.f + (av - 1.f) * k_a[d]);
    const float dt = waveSum((float)r[idx] * kfv * r_k[d]);
    kk_out[idx] = (__bf16)kkv;
    ab_out[idx] = (__bf16)(kkv * av);
    k[idx] = (__bf16)kfv;
    v[idx] = (__bf16)vv;
    if (lane == 0) dot_out[t * Hn + (d >> 6)] = dt;
  }
}

// ---------------- chunkA: per-chunk decay mats + triangular inverse ----------------
// Recurrence: S_t = S_{t-1}(diag(w_t) + a_t b_t^T) + v_t k_t^T, a=-kk, b=ab.
// Exports (per chunk c, head h):
//   Atil = -kk .* W_exc ; Rtil = r .* W_inc ; Bhat = (ab./W_inc).*W_C ;
//   Khat = (k./W_inc).*W_C  [bf16, [T][D] layout]
//   P = (I - M_ba)^-1, PK = P*M_ka, Gb, Gk  [bf16, 32x32 per (c,h)]
//   WC [f32]

__global__ __launch_bounds__(256) void chunkA_kernel(
    const __bf16* __restrict__ wd, const __bf16* __restrict__ kk,
    const __bf16* __restrict__ ab, const __bf16* __restrict__ kf,
    const __bf16* __restrict__ r,
    __bf16* __restrict__ Atil, __bf16* __restrict__ Rtil,
    __bf16* __restrict__ Bhat, __bf16* __restrict__ Khat,
    __bf16* __restrict__ Pg, __bf16* __restrict__ PKg,
    __bf16* __restrict__ Gbg, __bf16* __restrict__ Gkg,
    float* __restrict__ WCg) {
  const int c = blockIdx.x, h = blockIdx.y;
  const int tid = threadIdx.x;
  __shared__ __bf16 A_l[32][72];   // first used as w staging
  __shared__ __bf16 B_l[32][72], K_l[32][72], R_l[32][72];
  __shared__ float W_l[33][64];
  __shared__ float Mba[32][36], Mka[32][36];
  __shared__ float P0[32][36], P1[32][36], T0[32][36], T1[32][36];

  const size_t rowbase = (size_t)(c * Cn) * Dn + (size_t)h * 64;
  const int tt = tid >> 3, j0 = (tid & 7) * 8;
  const size_t g = rowbase + (size_t)tt * Dn + j0;
  // stage w
  *(bf16x8*)&A_l[tt][j0] = *(const bf16x8*)(wd + g);
  __syncthreads();
  if (tid < 64) {
    const int j = tid;
    float cur = 1.f;
    W_l[0][j] = 1.f;
    for (int t = 0; t < Cn; ++t) {
      cur *= (float)A_l[t][j];
      W_l[t + 1][j] = cur;
    }
    WCg[((size_t)c * Hn + h) * 64 + j] = cur;
  }
  __syncthreads();
  // decayed sequences (overwrites A_l w-staging)
  {
    bf16x8 kkv = *(const bf16x8*)(kk + g);
    bf16x8 abv = *(const bf16x8*)(ab + g);
    bf16x8 kv  = *(const bf16x8*)(kf + g);
    bf16x8 rv  = *(const bf16x8*)(r + g);
    bf16x8 oa, ob, ok, orr, obh, okh;
#pragma unroll
    for (int e = 0; e < 8; ++e) {
      const int j = j0 + e;
      const float Wexc = W_l[tt][j], Winc = W_l[tt + 1][j], WC = W_l[32][j];
      const float inv = 1.f / Winc;
      const float at = -(float)kkv[e] * Wexc;
      const float bt = (float)abv[e] * inv;
      const float kt = (float)kv[e] * inv;
      const float rt = (float)rv[e] * Winc;
      oa[e] = (__bf16)at; ob[e] = (__bf16)bt; ok[e] = (__bf16)kt;
      orr[e] = (__bf16)rt;
      obh[e] = (__bf16)(bt * WC); okh[e] = (__bf16)(kt * WC);
    }
    *(bf16x8*)&A_l[tt][j0] = oa;
    *(bf16x8*)&B_l[tt][j0] = ob;
    *(bf16x8*)&K_l[tt][j0] = ok;
    *(bf16x8*)&R_l[tt][j0] = orr;
    *(bf16x8*)(Atil + g) = oa;
    *(bf16x8*)(Rtil + g) = orr;
    *(bf16x8*)(Bhat + g) = obh;
    *(bf16x8*)(Khat + g) = okh;
  }
  __syncthreads();
  // C x C matrices
  const size_t matbase = ((size_t)c * Hn + h) * (Cn * Cn);
#pragma unroll 1
  for (int rep = 0; rep < 4; ++rep) {
    const int id = rep * 256 + tid;
    const int t = id >> 5, ta = id & 31;
    float d_ab = 0.f, d_ak = 0.f, d_rb = 0.f, d_rk = 0.f;
    for (int j8 = 0; j8 < 8; ++j8) {
      const bf16x8 av = *(const bf16x8*)&A_l[t][j8 * 8];
      const bf16x8 rv = *(const bf16x8*)&R_l[t][j8 * 8];
      const bf16x8 bv = *(const bf16x8*)&B_l[ta][j8 * 8];
      const bf16x8 kv = *(const bf16x8*)&K_l[ta][j8 * 8];
#pragma unroll
      for (int e = 0; e < 8; ++e) {
        const float af = (float)av[e], rf = (float)rv[e];
        const float bf2 = (float)bv[e], kf2 = (float)kv[e];
        d_ab += af * bf2; d_ak += af * kf2;
        d_rb += rf * bf2; d_rk += rf * kf2;
      }
    }
    Mba[t][ta] = (ta < t) ? d_ab : 0.f;
    Mka[t][ta] = (ta < t) ? d_ak : 0.f;
    Gbg[matbase + id] = (__bf16)((ta <= t) ? d_rb : 0.f);
    Gkg[matbase + id] = (__bf16)((ta <= t) ? d_rk : 0.f);
  }
  __syncthreads();
  // P0 = I + M
  for (int rep = 0; rep < 4; ++rep) {
    const int id = rep * 256 + tid;
    const int t = id >> 5, ta = id & 31;
    P0[t][ta] = Mba[t][ta] + (t == ta ? 1.f : 0.f);
  }
  __syncthreads();
  auto mm = [&](float (*D)[36], float (*Aa)[36], float (*Bb)[36]) {
    for (int rep = 0; rep < 4; ++rep) {
      const int id = rep * 256 + tid;
      const int t = id >> 5, ta = id & 31;
      float s = 0.f;
      for (int u = 0; u < 32; ++u) s += Aa[t][u] * Bb[u][ta];
      D[t][ta] = s;
    }
    __syncthreads();
  };
  auto mmadd = [&](float (*D)[36], float (*Pp)[36], float (*Tt)[36]) {
    for (int rep = 0; rep < 4; ++rep) {
      const int id = rep * 256 + tid;
      const int t = id >> 5, ta = id & 31;
      float s = Pp[t][ta];
      for (int u = 0; u < 32; ++u) s += Pp[t][u] * Tt[u][ta];
      D[t][ta] = s;
    }
    __syncthreads();
  };
  mm(T0, Mba, Mba);      // M^2
  mmadd(P1, P0, T0);
  mm(T1, T0, T0);        // M^4
  mmadd(P0, P1, T1);
  mm(T0, T1, T1);        // M^8
  mmadd(P1, P0, T0);
  mm(T1, T0, T0);        // M^16
  mmadd(P0, P1, T1);     // final in P0
  for (int rep = 0; rep < 4; ++rep) {
    const int id = rep * 256 + tid;
    const int t = id >> 5, ta = id & 31;
    Pg[matbase + id] = (__bf16)P0[t][ta];
    float s = 0.f;
    for (int u = 0; u < 32; ++u) s += P0[t][u] * Mka[u][ta];
    PKg[matbase + id] = (__bf16)s;
  }
}

// ---------------- chunkB: sequential over chunks, parallel (head, i-quad) ----------------

__global__ __launch_bounds__(256) void chunkB_kernel(
    const __bf16* __restrict__ Atil, const __bf16* __restrict__ Rtil,
    const __bf16* __restrict__ Bhat, const __bf16* __restrict__ Khat,
    const __bf16* __restrict__ Pg, const __bf16* __restrict__ PKg,
    const __bf16* __restrict__ Gbg, const __bf16* __restrict__ Gkg,
    const float* __restrict__ WCg, const __bf16* __restrict__ vbuf,
    const float* __restrict__ st_in, __bf16* __restrict__ xo,
    float* __restrict__ st_out) {
  const int h = blockIdx.x >> 2, iq = blockIdx.x & 3;
  const int ib = iq * 16;
  const int tid = threadIdx.x;
  __shared__ float S_l[16][68];
  __shared__ float P_l[32][36], PK_l[32][36], Gb_l[32][36], Gk_l[32][36];
  __shared__ __bf16 A_l[32][72], R_l[32][72], Bh_l[32][72], Kh_l[32][72];
  __shared__ float X_l[32][20], SA_l[32][20], V_l[32][20];
  __shared__ float WC_l[64];

  for (int rep = 0; rep < 4; ++rep) {
    const int id = rep * 256 + tid;
    const int i = id >> 6, j = id & 63;
    S_l[i][j] = st_in[(size_t)h * 4096 + (size_t)(ib + i) * 64 + j];
  }
  const int i16 = tid & 15, tq = tid >> 4;
  const int jl = tid & 63, wvi = tid >> 6;

#pragma unroll 1
  for (int c = 0; c < NCH; ++c) {
    __syncthreads();
    const size_t rowbase = (size_t)(c * Cn) * Dn + (size_t)h * 64;
    {
      const int tt = tid >> 3, j0 = (tid & 7) * 8;
      const size_t g = rowbase + (size_t)tt * Dn + j0;
      *(bf16x8*)&A_l[tt][j0]  = *(const bf16x8*)(Atil + g);
      *(bf16x8*)&R_l[tt][j0]  = *(const bf16x8*)(Rtil + g);
      *(bf16x8*)&Bh_l[tt][j0] = *(const bf16x8*)(Bhat + g);
      *(bf16x8*)&Kh_l[tt][j0] = *(const bf16x8*)(Khat + g);
    }
    const size_t matbase = ((size_t)c * Hn + h) * (Cn * Cn);
    for (int rep = 0; rep < 4; ++rep) {
      const int id = rep * 256 + tid;
      const int t = id >> 5, ta = id & 31;
      P_l[t][ta]  = (float)Pg[matbase + id];
      PK_l[t][ta] = (float)PKg[matbase + id];
      Gb_l[t][ta] = (float)Gbg[matbase + id];
      Gk_l[t][ta] = (float)Gkg[matbase + id];
    }
    for (int rep = 0; rep < 2; ++rep) {
      const int id = rep * 256 + tid;
      const int tt = id >> 4, i = id & 15;
      V_l[tt][i] = (float)vbuf[rowbase + (size_t)tt * Dn + ib + i];
    }
    if (tid < 64) WC_l[tid] = WCg[((size_t)c * Hn + h) * 64 + tid];
    __syncthreads();
    // X = Atil * S^T
    {
      float a0 = 0.f, a1 = 0.f;
      for (int j4 = 0; j4 < 16; ++j4) {
        const f32x4 s = *(const f32x4*)&S_l[i16][j4 * 4];
#pragma unroll
        for (int e = 0; e < 4; ++e) {
          const int j = j4 * 4 + e;
          a0 += s[e] * (float)A_l[tq][j];
          a1 += s[e] * (float)A_l[tq + 16][j];
        }
      }
      X_l[tq][i16] = a0; X_l[tq + 16][i16] = a1;
    }
    __syncthreads();
    // SA = P*X + PK*V
    {
      float a0 = 0.f, a1 = 0.f;
      for (int u = 0; u < 32; ++u) {
        const float xv = X_l[u][i16], vv2 = V_l[u][i16];
        a0 += P_l[tq][u] * xv + PK_l[tq][u] * vv2;
        a1 += P_l[tq + 16][u] * xv + PK_l[tq + 16][u] * vv2;
      }
      SA_l[tq][i16] = a0; SA_l[tq + 16][i16] = a1;
    }
    __syncthreads();
    // O = Gb*SA + Gk*V + Rtil*S^T
    {
      float a0 = 0.f, a1 = 0.f;
      for (int u = 0; u < 32; ++u) {
        const float sv = SA_l[u][i16], vv2 = V_l[u][i16];
        a0 += Gb_l[tq][u] * sv + Gk_l[tq][u] * vv2;
        a1 += Gb_l[tq + 16][u] * sv + Gk_l[tq + 16][u] * vv2;
      }
      for (int j4 = 0; j4 < 16; ++j4) {
        const f32x4 s = *(const f32x4*)&S_l[i16][j4 * 4];
#pragma unroll
        for (int e = 0; e < 4; ++e) {
          const int j = j4 * 4 + e;
          a0 += s[e] * (float)R_l[tq][j];
          a1 += s[e] * (float)R_l[tq + 16][j];
        }
      }
      xo[(size_t)(c * Cn + tq) * Dn + h * 64 + ib + i16] = (__bf16)a0;
      xo[(size_t)(c * Cn + tq + 16) * Dn + h * 64 + ib + i16] = (__bf16)a1;
    }
    __syncthreads();
    // S = S .* WC + SA^T * Bhat + V^T * Khat
    {
      const float wc = WC_l[jl];
      float acc[4];
#pragma unroll
      for (int ii = 0; ii < 4; ++ii) acc[ii] = S_l[wvi * 4 + ii][jl] * wc;
      for (int u = 0; u < 32; ++u) {
        const float bh = (float)Bh_l[u][jl], kh = (float)Kh_l[u][jl];
        const f32x4 sa4 = *(const f32x4*)&SA_l[u][wvi * 4];
        const f32x4 vv4 = *(const f32x4*)&V_l[u][wvi * 4];
#pragma unroll
        for (int ii = 0; ii < 4; ++ii)
          acc[ii] += sa4[ii] * bh + vv4[ii] * kh;
      }
#pragma unroll
      for (int ii = 0; ii < 4; ++ii) S_l[wvi * 4 + ii][jl] = acc[ii];
    }
  }
  __syncthreads();
  for (int rep = 0; rep < 4; ++rep) {
    const int id = rep * 256 + tid;
    const int i = id >> 6, j = id & 63;
    st_out[(size_t)h * 4096 + (size_t)(ib + i) * 64 + j] = S_l[i][j];
  }
}

// ---------------- post: per-head LN + bonus + gate -> bf16 ----------------

__global__ __launch_bounds__(256) void post_kernel(
    const __bf16* __restrict__ xo, const __bf16* __restrict__ v,
    const __bf16* __restrict__ g, const float* __restrict__ dot,
    const float* __restrict__ lnw, const float* __restrict__ lnb,
    __bf16* __restrict__ out) {
  const int t = blockIdx.x;
  const int lane = threadIdx.x & 63, wv = threadIdx.x >> 6;
#pragma unroll 1
  for (int c = 0; c < 8; ++c) {
    const int d = c * 256 + wv * 64 + lane;
    const size_t idx = (size_t)t * Dn + d;
    const float val = (float)xo[idx];
    const float mu = waveSum(val) * (1.f / 64.f);
    const float ctr = val - mu;
    const float var = waveSum(ctr * ctr) * (1.f / 64.f);
    float y = ctr * rsqrtf(var + 0.00064f);
    y = y * lnw[d] + lnb[d];
    const float res = (y + dot[t * Hn + (d >> 6)] * (float)v[idx]) * (float)g[idx];
    out[idx] = (__bf16)res;
  }
}

// ---------------- launcher ----------------

extern "C" void kernel_launch(void* const* d_in, const int* in_sizes, int n_in,
                              void* d_out, int out_size, void* d_ws, size_t ws_size,
                              hipStream_t stream) {
  (void)in_sizes; (void)n_in; (void)out_size; (void)ws_size;
  const float* x       = (const float*)d_in[0];
  const float* state1  = (const float*)d_in[1];
  const float* state2  = (const float*)d_in[2];
  const float* v_first = (const float*)d_in[3];
  const float* ln1_w   = (const float*)d_in[4];
  const float* ln1_b   = (const float*)d_in[5];
  const float* x_r     = (const float*)d_in[6];
  const float* x_w     = (const float*)d_in[7];
  const float* x_k     = (const float*)d_in[8];
  const float* x_v     = (const float*)d_in[9];
  const float* x_a     = (const float*)d_in[10];
  const float* x_g     = (const float*)d_in[11];
  const float* W_r     = (const float*)d_in[12];
  const float* W_k     = (const float*)d_in[13];
  const float* W_v     = (const float*)d_in[14];
  const float* W_o     = (const float*)d_in[15];
  const float* w1      = (const float*)d_in[16];
  const float* w2      = (const float*)d_in[17];
  const float* w0      = (const float*)d_in[18];
  const float* a1      = (const float*)d_in[19];
  const float* a2      = (const float*)d_in[20];
  const float* a0      = (const float*)d_in[21];
  const float* v1      = (const float*)d_in[22];
  const float* v2      = (const float*)d_in[23];
  const float* v0      = (const float*)d_in[24];
  const float* g1      = (const float*)d_in[25];
  const float* g2      = (const float*)d_in[26];
  const float* k_k     = (const float*)d_in[27];
  const float* k_a     = (const float*)d_in[28];
  const float* r_k     = (const float*)d_in[29];
  const float* lnx_w   = (const float*)d_in[30];
  const float* lnx_b   = (const float*)d_in[31];

  char* p = (char*)d_ws;
  const size_t MB = 1ull << 20;
  // 14 slots x 8 MB + smalls(~3.4MB) = ~115.4 MB. Lifetimes:
  //  S0: xn(ln->mix)       -> Atil(chunkA->chunkB)
  //  S1: xr(mix->gemm3)    -> Wo_b(cast1->gemm_wo)
  //  S2: xw(mix->lora1)    -> wdec(s2->chunkA) -> xo_b(post->gemm_wo)
  //  S3: xk(mix->gemm3)    -> abuf(s2->prep)   -> Rtil(chunkA->chunkB)
  //  S4: xv(mix->g3,lora1) -> vbl(s2->prep)    -> Bhat(chunkA->chunkB)
  //  S5: xa(mix->lora1)    -> gbuf(s2->post)
  //  S6: xg(mix->lora1)    -> kkbuf(prep->chunkA) -> xobuf(chunkB->post)
  //  S7: Wr(castw3->gemm3) -> abbuf(prep->chunkA)
  //  S8: Wk(castw3->gemm3) -> Khat(chunkA->chunkB)
  //  S9: Wv(castw3->gemm3) -> Pg(4MB)+PKg(4MB)
  //  S10: rbuf  S11: kbuf  S12: vbuf
  //  S13: Gbg(4MB)+Gkg(4MB)
  __bf16* xn    = (__bf16*)(p + 0 * MB);
  __bf16* Atil  = (__bf16*)(p + 0 * MB);
  __bf16* xr_b  = (__bf16*)(p + 8 * MB);
  __bf16* Wo_b  = (__bf16*)(p + 8 * MB);
  __bf16* xw_b  = (__bf16*)(p + 16 * MB);
  __bf16* wdec  = (__bf16*)(p + 16 * MB);
  __bf16* xo_b  = (__bf16*)(p + 16 * MB);
  __bf16* xk_b  = (__bf16*)(p + 24 * MB);
  __bf16* abuf  = (__bf16*)(p + 24 * MB);
  __bf16* Rtil  = (__bf16*)(p + 24 * MB);
  __bf16* xv_b  = (__bf16*)(p + 32 * MB);
  __bf16* vbl   = (__bf16*)(p + 32 * MB);
  __bf16* Bhat  = (__bf16*)(p + 32 * MB);
  __bf16* xa_b  = (__bf16*)(p + 40 * MB);
  __bf16* gbuf  = (__bf16*)(p + 40 * MB);
  __bf16* xg_b  = (__bf16*)(p + 48 * MB);
  __bf16* kkbuf = (__bf16*)(p + 48 * MB);
  __bf16* xobuf = (__bf16*)(p + 48 * MB);
  __bf16* Wr_b  = (__bf16*)(p + 56 * MB);
  __bf16* abbuf = (__bf16*)(p + 56 * MB);
  __bf16* Wk_b  = (__bf16*)(p + 64 * MB);
  __bf16* Khat  = (__bf16*)(p + 64 * MB);
  __bf16* Wv_b  = (__bf16*)(p + 72 * MB);
  __bf16* Pg    = (__bf16*)(p + 72 * MB);
  __bf16* PKg   = (__bf16*)(p + 76 * MB);
  __bf16* rbuf  = (__bf16*)(p + 80 * MB);
  __bf16* kbuf  = (__bf16*)(p + 88 * MB);
  __bf16* vbuf  = (__bf16*)(p + 96 * MB);
  __bf16* Gbg   = (__bf16*)(p + 104 * MB);
  __bf16* Gkg   = (__bf16*)(p + 108 * MB);
  char* q = p + 112 * MB;
  __bf16* yw  = (__bf16*)q; q += (size_t)Tn * 64 * 2;
  __bf16* ya  = (__bf16*)q; q += (size_t)Tn * 64 * 2;
  __bf16* yv  = (__bf16*)q; q += (size_t)Tn * 32 * 2;
  __bf16* yg  = (__bf16*)q; q += (size_t)Tn * 128 * 2;
  __bf16* w2T = (__bf16*)q; q += (size_t)Dn * 64 * 2;
  __bf16* a2T = (__bf16*)q; q += (size_t)Dn * 64 * 2;
  __bf16* v2T = (__bf16*)q; q += (size_t)Dn * 32 * 2;
  __bf16* g2T = (__bf16*)q; q += (size_t)Dn * 128 * 2;
  float*  dot = (float*)q;  q += (size_t)Tn * Hn * 4;
  float*  WCg = (float*)q;  q += (size_t)NCH * Hn * 64 * 4;

  float* out     = (float*)d_out;
  float* out_xnl = out + (size_t)Tn * Dn;
  float* out_st  = out_xnl + Dn;

  castw3_kernel<<<dim3(4096, 3), 256, 0, stream>>>(W_r, W_k, W_v, Wr_b, Wk_b, Wv_b);
  castT_kernel<<<2048, 256, 0, stream>>>(w2, a2, v2, g2, w2T, a2T, v2T, g2T);
  ln_kernel<<<2048, 256, 0, stream>>>(x, ln1_w, ln1_b, xn, out_xnl);
  mix_kernel<<<4096, 256, 0, stream>>>(xn, state1, x_r, x_w, x_k, x_v, x_a, x_g,
                                       xr_b, xw_b, xk_b, xv_b, xa_b, xg_b);
  gemm3_kernel<<<dim3(16, 16, 3), 256, 0, stream>>>(
      xr_b, xk_b, xv_b, Wr_b, Wk_b, Wv_b, rbuf, kbuf, vbuf);
  cast1_kernel<<<4096, 256, 0, stream>>>(W_o, Wo_b);
  lora1_kernel<<<dim3(256, 4), 256, 0, stream>>>(
      xw_b, xa_b, xv_b, xg_b, w1, a1, v1, g1, yw, ya, yv, yg);
  gemm_s2_kernel<<<dim3(16, 16, 4), 256, 0, stream>>>(
      yw, ya, yv, yg, w2T, a2T, v2T, g2T, w0, a0, v0, wdec, abuf, vbl, gbuf);
  prep_kernel<<<2048, 256, 0, stream>>>(rbuf, kbuf, vbuf, abuf, vbl, v_first,
                                        k_k, k_a, r_k, kkbuf, abbuf, dot);
  chunkA_kernel<<<dim3(NCH, Hn), 256, 0, stream>>>(
      wdec, kkbuf, abbuf, kbuf, rbuf,
      Atil, Rtil, Bhat, Khat, Pg, PKg, Gbg, Gkg, WCg);
  chunkB_kernel<<<128, 256, 0, stream>>>(
      Atil, Rtil, Bhat, Khat, Pg, PKg, Gbg, Gkg, WCg, vbuf,
      state2, xobuf, out_st);
  post_kernel<<<2048, 256, 0, stream>>>(xobuf, vbuf, gbuf, dot, lnx_w, lnx_b, xo_b);
  gemm_wo_kernel<<<dim3(16, 16), 256, 0, stream>>>(xo_b, Wo_b, x, out);
}

// Round 8
// 724.142 us; speedup vs baseline: 1.6845x; 1.2905x over previous
//
#include <hip/hip_runtime.h>

#define Tn 2048
#define Dn 2048
#define Hn 32
#define Cn 32
#define NCH (Tn / Cn)

typedef float f32x4 __attribute__((ext_vector_type(4)));
typedef __bf16 bf16x8 __attribute__((ext_vector_type(8)));
typedef __bf16 bf16x4 __attribute__((ext_vector_type(4)));

// ---- fast wave-64 sum: DPP row reductions (VALU) + readlane ----
template <int CTRL>
__device__ __forceinline__ float dpp_add(float x) {
  int xi = __builtin_bit_cast(int, x);
  int sh = __builtin_amdgcn_update_dpp(0, xi, CTRL, 0xf, 0xf, true);
  return x + __builtin_bit_cast(float, sh);
}
__device__ __forceinline__ float rdlane(float x, int l) {
  int xi = __builtin_bit_cast(int, x);
  return __builtin_bit_cast(float, __builtin_amdgcn_readlane(xi, l));
}
__device__ __forceinline__ float waveSum(float v) {
  v = dpp_add<0x111>(v);
  v = dpp_add<0x112>(v);
  v = dpp_add<0x114>(v);
  v = dpp_add<0x118>(v);
  return (rdlane(v, 15) + rdlane(v, 31)) + (rdlane(v, 47) + rdlane(v, 63));
}

__device__ __forceinline__ float sigm(float x) { return 1.f / (1.f + expf(-x)); }

__device__ __forceinline__ void gl_lds16(const void* g, void* l) {
  __builtin_amdgcn_global_load_lds(
      (__attribute__((address_space(1))) void*)(g),
      (__attribute__((address_space(3))) void*)(l), 16, 0, 0);
}

// ---------------- weight casts ----------------

__global__ __launch_bounds__(256) void castw3_kernel(
    const float* __restrict__ A, const float* __restrict__ B,
    const float* __restrict__ C, __bf16* __restrict__ o0,
    __bf16* __restrict__ o1, __bf16* __restrict__ o2) {
  const int z = blockIdx.y;
  const float* src = z == 0 ? A : (z == 1 ? B : C);
  __bf16* dst = z == 0 ? o0 : (z == 1 ? o1 : o2);
  const size_t i4 = (size_t)blockIdx.x * 256 + threadIdx.x;
  f32x4 v = *(const f32x4*)(src + i4 * 4);
  bf16x4 o;
  o[0] = (__bf16)v[0]; o[1] = (__bf16)v[1]; o[2] = (__bf16)v[2]; o[3] = (__bf16)v[3];
  ((bf16x4*)dst)[i4] = o;
}

__global__ __launch_bounds__(256) void cast1_kernel(
    const float* __restrict__ src, __bf16* __restrict__ dst) {
  const size_t i4 = (size_t)blockIdx.x * 256 + threadIdx.x;
  f32x4 v = *(const f32x4*)(src + i4 * 4);
  bf16x4 o;
  o[0] = (__bf16)v[0]; o[1] = (__bf16)v[1]; o[2] = (__bf16)v[2]; o[3] = (__bf16)v[3];
  ((bf16x4*)dst)[i4] = o;
}

// stage-2 weights: transpose-cast to [D][128] bf16, zero-padded beyond R
__global__ __launch_bounds__(256) void castT_kernel(
    const float* __restrict__ w2, const float* __restrict__ a2,
    const float* __restrict__ v2, const float* __restrict__ g2,
    __bf16* __restrict__ w2T, __bf16* __restrict__ a2T,
    __bf16* __restrict__ v2T, __bf16* __restrict__ g2T) {
  const int i = blockIdx.x;   // D index
  const int k = threadIdx.x;
  if (k < 128) {
    w2T[(size_t)i * 128 + k] = (k < 64) ? (__bf16)w2[(size_t)k * Dn + i] : (__bf16)0.f;
    a2T[(size_t)i * 128 + k] = (k < 64) ? (__bf16)a2[(size_t)k * Dn + i] : (__bf16)0.f;
    v2T[(size_t)i * 128 + k] = (k < 32) ? (__bf16)v2[(size_t)k * Dn + i] : (__bf16)0.f;
    g2T[(size_t)i * 128 + k] = (__bf16)g2[(size_t)k * Dn + i];
  }
}

// stage-1 (LoRA down) weights: [D][R] f32 -> [128][D] bf16, zero-padded rows
__global__ __launch_bounds__(256) void castU_kernel(
    const float* __restrict__ w1, const float* __restrict__ a1,
    const float* __restrict__ v1, const float* __restrict__ g1,
    __bf16* __restrict__ uwT, __bf16* __restrict__ uaT,
    __bf16* __restrict__ uvT, __bf16* __restrict__ ugT) {
  const int z = blockIdx.y;
  const float* src = z == 0 ? w1 : (z == 1 ? a1 : (z == 2 ? v1 : g1));
  __bf16* dst = z == 0 ? uwT : (z == 1 ? uaT : (z == 2 ? uvT : ugT));
  const int R = z == 0 ? 64 : (z == 1 ? 64 : (z == 2 ? 32 : 128));
  const int d = blockIdx.x;
  const int k = threadIdx.x;
  if (k < 128)
    dst[(size_t)k * Dn + d] = (k < R) ? (__bf16)src[(size_t)d * R + k] : (__bf16)0.f;
}

// ---------------- layernorm (ln1) ----------------

__global__ __launch_bounds__(256) void ln_kernel(
    const float* __restrict__ x, const float* __restrict__ lw,
    const float* __restrict__ lb, __bf16* __restrict__ xn,
    float* __restrict__ xn_last) {
  __shared__ float red[8];
  const int t = blockIdx.x, tid = threadIdx.x;
  const int lane = tid & 63, wv = tid >> 6;
  const float* xr = x + (size_t)t * Dn;
  float v[8];
  float s = 0.f;
#pragma unroll
  for (int c = 0; c < 8; ++c) { v[c] = xr[tid + c * 256]; s += v[c]; }
  s = waveSum(s);
  if (lane == 0) red[wv] = s;
  __syncthreads();
  const float mu = (red[0] + red[1] + red[2] + red[3]) * (1.f / (float)Dn);
  float q = 0.f;
#pragma unroll
  for (int c = 0; c < 8; ++c) { float d0 = v[c] - mu; q += d0 * d0; }
  q = waveSum(q);
  if (lane == 0) red[4 + wv] = q;
  __syncthreads();
  const float var = (red[4] + red[5] + red[6] + red[7]) * (1.f / (float)Dn);
  const float rstd = rsqrtf(var + 1e-5f);
#pragma unroll
  for (int c = 0; c < 8; ++c) {
    const int d = tid + c * 256;
    const float y = (v[c] - mu) * rstd * lw[d] + lb[d];
    xn[(size_t)t * Dn + d] = (__bf16)y;
    if (t == Tn - 1) xn_last[d] = y;
  }
}

// ---------------- token-shift mix ----------------

__global__ __launch_bounds__(256) void mix_kernel(
    const __bf16* __restrict__ xn, const float* __restrict__ state1,
    const float* __restrict__ cr, const float* __restrict__ cw,
    const float* __restrict__ ck, const float* __restrict__ cv,
    const float* __restrict__ ca, const float* __restrict__ cg,
    __bf16* __restrict__ br, __bf16* __restrict__ bw, __bf16* __restrict__ bk,
    __bf16* __restrict__ bv, __bf16* __restrict__ ba, __bf16* __restrict__ bg) {
  const size_t i4 = (size_t)blockIdx.x * 256 + threadIdx.x;
  const int t = (int)(i4 >> 9);
  const int d = (int)(i4 & 511) * 4;
  const bf16x4 cb = ((const bf16x4*)xn)[i4];
  f32x4 cur;
#pragma unroll
  for (int e = 0; e < 4; ++e) cur[e] = (float)cb[e];
  f32x4 prv;
  if (t == 0) {
    prv = *(const f32x4*)(state1 + d);
  } else {
    const bf16x4 pb = ((const bf16x4*)xn)[i4 - 512];
#pragma unroll
    for (int e = 0; e < 4; ++e) prv[e] = (float)pb[e];
  }
  const f32x4 sx = prv - cur;
  auto mix1 = [&](const float* c, __bf16* o) {
    const f32x4 cc = *(const f32x4*)(c + d);
    bf16x4 ob;
#pragma unroll
    for (int e = 0; e < 4; ++e) ob[e] = (__bf16)(cur[e] + sx[e] * cc[e]);
    ((bf16x4*)o)[i4] = ob;
  };
  mix1(cr, br); mix1(cw, bw); mix1(ck, bk);
  mix1(cv, bv); mix1(ca, ba); mix1(cg, bg);
}

// ---------------- MFMA GEMM tile core ----------------

__device__ __forceinline__ void gemm_tile(const __bf16* __restrict__ A,
                                          const __bf16* __restrict__ B,
                                          int K, int row0, int col0,
                                          f32x4 (&acc)[4][4]) {
  __shared__ __attribute__((aligned(16))) __bf16 As[4096];
  __shared__ __attribute__((aligned(16))) __bf16 Bs[4096];
  const int tid = threadIdx.x;
  const int lane = tid & 63, wid = tid >> 6;
  const int wm = (wid >> 1) * 64, wn = (wid & 1) * 64;
  const int lr = lane & 15, lk = (lane >> 4) * 8;
  for (int kt = 0; kt < K; kt += 32) {
#pragma unroll
    for (int it = 0; it < 2; ++it) {
      const int L = it * 256 + tid;
      const int rr = L >> 2, kc = (L & 3) * 8;
      const int lb = (it * 256 + wid * 64) * 8;
      gl_lds16(A + (size_t)(row0 + rr) * K + (kt + kc), &As[lb]);
      gl_lds16(B + (size_t)(col0 + rr) * K + (kt + kc), &Bs[lb]);
    }
    __syncthreads();
    bf16x8 af[4], bfv[4];
#pragma unroll
    for (int mf = 0; mf < 4; ++mf)
      af[mf] = *(const bf16x8*)&As[(wm + mf * 16 + lr) * 32 + lk];
#pragma unroll
    for (int nf = 0; nf < 4; ++nf)
      bfv[nf] = *(const bf16x8*)&Bs[(wn + nf * 16 + lr) * 32 + lk];
#pragma unroll
    for (int mf = 0; mf < 4; ++mf)
#pragma unroll
      for (int nf = 0; nf < 4; ++nf)
        acc[mf][nf] = __builtin_amdgcn_mfma_f32_16x16x32_bf16(
            af[mf], bfv[nf], acc[mf][nf], 0, 0, 0);
    __syncthreads();
  }
}

__global__ __launch_bounds__(256) void gemm3_kernel(
    const __bf16* __restrict__ A0, const __bf16* __restrict__ A1,
    const __bf16* __restrict__ A2, const __bf16* __restrict__ B0,
    const __bf16* __restrict__ B1, const __bf16* __restrict__ B2,
    __bf16* __restrict__ C0, __bf16* __restrict__ C1, __bf16* __restrict__ C2) {
  const int z = blockIdx.z;
  const __bf16* A = z == 0 ? A0 : (z == 1 ? A1 : A2);
  const __bf16* B = z == 0 ? B0 : (z == 1 ? B1 : B2);
  __bf16* C = z == 0 ? C0 : (z == 1 ? C1 : C2);
  const int row0 = blockIdx.x * 128, col0 = blockIdx.y * 128;
  f32x4 acc[4][4] = {};
  gemm_tile(A, B, Dn, row0, col0, acc);
  const int lane = threadIdx.x & 63, wid = threadIdx.x >> 6;
  const int wm = (wid >> 1) * 64, wn = (wid & 1) * 64;
#pragma unroll
  for (int mf = 0; mf < 4; ++mf) {
    const int r0 = row0 + wm + mf * 16 + ((lane >> 4) << 2);
#pragma unroll
    for (int nf = 0; nf < 4; ++nf) {
      const int c0 = col0 + wn + nf * 16 + (lane & 15);
#pragma unroll
      for (int rg = 0; rg < 4; ++rg)
        C[(size_t)(r0 + rg) * Dn + c0] = (__bf16)acc[mf][nf][rg];
    }
  }
}

// LoRA stage-1 as MFMA GEMM: Y[T][128] = X[T][D] @ U^T, epilogue per path
__global__ __launch_bounds__(256) void gemm_l1_kernel(
    const __bf16* __restrict__ Aw, const __bf16* __restrict__ Aa,
    const __bf16* __restrict__ Av, const __bf16* __restrict__ Ag,
    const __bf16* __restrict__ Bw, const __bf16* __restrict__ Ba,
    const __bf16* __restrict__ Bv, const __bf16* __restrict__ Bg,
    __bf16* __restrict__ Cw, __bf16* __restrict__ Ca,
    __bf16* __restrict__ Cv, __bf16* __restrict__ Cg) {
  const int z = blockIdx.z;
  const __bf16* A = z == 0 ? Aw : (z == 1 ? Aa : (z == 2 ? Av : Ag));
  const __bf16* B = z == 0 ? Bw : (z == 1 ? Ba : (z == 2 ? Bv : Bg));
  __bf16* C = z == 0 ? Cw : (z == 1 ? Ca : (z == 2 ? Cv : Cg));
  const int row0 = blockIdx.x * 128;
  f32x4 acc[4][4] = {};
  gemm_tile(A, B, Dn, row0, 0, acc);
  const int lane = threadIdx.x & 63, wid = threadIdx.x >> 6;
  const int wm = (wid >> 1) * 64, wn = (wid & 1) * 64;
#pragma unroll
  for (int mf = 0; mf < 4; ++mf) {
    const int r0 = row0 + wm + mf * 16 + ((lane >> 4) << 2);
#pragma unroll
    for (int nf = 0; nf < 4; ++nf) {
      const int c0 = wn + nf * 16 + (lane & 15);
#pragma unroll
      for (int rg = 0; rg < 4; ++rg) {
        float val = acc[mf][nf][rg];
        if (z == 0)      val = tanhf(val);
        else if (z == 3) val = sigm(val);
        C[(size_t)(r0 + rg) * 128 + c0] = (__bf16)val;
      }
    }
  }
}

// LoRA stage-2 fused, uniform K=128 (zero-padded), bf16 outputs
__global__ __launch_bounds__(256) void gemm_s2_kernel(
    const __bf16* __restrict__ Aw, const __bf16* __restrict__ Aa,
    const __bf16* __restrict__ Av, const __bf16* __restrict__ Ag,
    const __bf16* __restrict__ Bw, const __bf16* __restrict__ Ba,
    const __bf16* __restrict__ Bv, const __bf16* __restrict__ Bg,
    const float* __restrict__ w0, const float* __restrict__ a0,
    const float* __restrict__ v0, __bf16* __restrict__ Cw,
    __bf16* __restrict__ Ca, __bf16* __restrict__ Cv, __bf16* __restrict__ Cg) {
  const int z = blockIdx.z;
  const __bf16* A = z == 0 ? Aw : (z == 1 ? Aa : (z == 2 ? Av : Ag));
  const __bf16* B = z == 0 ? Bw : (z == 1 ? Ba : (z == 2 ? Bv : Bg));
  const float* bias = z == 0 ? w0 : (z == 1 ? a0 : (z == 2 ? v0 : (const float*)0));
  __bf16* C = z == 0 ? Cw : (z == 1 ? Ca : (z == 2 ? Cv : Cg));
  const int row0 = blockIdx.x * 128, col0 = blockIdx.y * 128;
  f32x4 acc[4][4] = {};
  gemm_tile(A, B, 128, row0, col0, acc);
  const int lane = threadIdx.x & 63, wid = threadIdx.x >> 6;
  const int wm = (wid >> 1) * 64, wn = (wid & 1) * 64;
#pragma unroll
  for (int mf = 0; mf < 4; ++mf) {
    const int r0 = row0 + wm + mf * 16 + ((lane >> 4) << 2);
#pragma unroll
    for (int nf = 0; nf < 4; ++nf) {
      const int c0 = col0 + wn + nf * 16 + (lane & 15);
#pragma unroll
      for (int rg = 0; rg < 4; ++rg) {
        float val = acc[mf][nf][rg];
        if (z == 0)      val = expf(-0.606531f * sigm(val + bias[c0]));
        else if (z < 3)  val = sigm(val + bias[c0]);
        C[(size_t)(r0 + rg) * Dn + c0] = (__bf16)val;
      }
    }
  }
}

__global__ __launch_bounds__(256) void gemm_wo_kernel(
    const __bf16* __restrict__ A, const __bf16* __restrict__ B,
    const float* __restrict__ xres, float* __restrict__ C) {
  const int row0 = blockIdx.x * 128, col0 = blockIdx.y * 128;
  f32x4 acc[4][4] = {};
  gemm_tile(A, B, Dn, row0, col0, acc);
  const int lane = threadIdx.x & 63, wid = threadIdx.x >> 6;
  const int wm = (wid >> 1) * 64, wn = (wid & 1) * 64;
#pragma unroll
  for (int mf = 0; mf < 4; ++mf) {
    const int r0 = row0 + wm + mf * 16 + ((lane >> 4) << 2);
#pragma unroll
    for (int nf = 0; nf < 4; ++nf) {
      const int c0 = col0 + wn + nf * 16 + (lane & 15);
#pragma unroll
      for (int rg = 0; rg < 4; ++rg)
        C[(size_t)(r0 + rg) * Dn + c0] =
            acc[mf][nf][rg] + xres[(size_t)(r0 + rg) * Dn + c0];
    }
  }
}

// ---------------- prep: v-blend, kk-norm, k-mod, ab, bonus dot ----------------

__global__ __launch_bounds__(256) void prep_kernel(
    const __bf16* __restrict__ r, __bf16* __restrict__ k, __bf16* __restrict__ v,
    const __bf16* __restrict__ a, const __bf16* __restrict__ vb,
    const float* __restrict__ v_first, const float* __restrict__ k_k,
    const float* __restrict__ k_a, const float* __restrict__ r_k,
    __bf16* __restrict__ kk_out, __bf16* __restrict__ ab_out,
    float* __restrict__ dot_out) {
  const int t = blockIdx.x;
  const int lane = threadIdx.x & 63, wv = threadIdx.x >> 6;
#pragma unroll 1
  for (int c = 0; c < 8; ++c) {
    const int d = c * 256 + wv * 64 + lane;
    const size_t idx = (size_t)t * Dn + d;
    const float kvv = (float)k[idx];
    const float kh = kvv * k_k[d];
    const float nrm = sqrtf(waveSum(kh * kh)) + 1e-6f;
    const float kkv = kh / nrm;
    const float av = (float)a[idx];
    float vv = (float)v[idx];
    vv = vv + (v_first[idx] - vv) * (float)vb[idx];
    const float kfv = kvv * (1.f + (av - 1.f) * k_a[d]);
    const float dt = waveSum((float)r[idx] * kfv * r_k[d]);
    kk_out[idx] = (__bf16)kkv;
    ab_out[idx] = (__bf16)(kkv * av);
    k[idx] = (__bf16)kfv;
    v[idx] = (__bf16)vv;
    if (lane == 0) dot_out[t * Hn + (d >> 6)] = dt;
  }
}

// ---------------- chunkA: per-chunk decay mats + triangular inverse ----------------

__global__ __launch_bounds__(256) void chunkA_kernel(
    const __bf16* __restrict__ wd, const __bf16* __restrict__ kk,
    const __bf16* __restrict__ ab, const __bf16* __restrict__ kf,
    const __bf16* __restrict__ r,
    __bf16* __restrict__ Atil, __bf16* __restrict__ Rtil,
    __bf16* __restrict__ Bhat, __bf16* __restrict__ Khat,
    __bf16* __restrict__ Pg, __bf16* __restrict__ PKg,
    __bf16* __restrict__ Gbg, __bf16* __restrict__ Gkg,
    float* __restrict__ WCg) {
  const int c = blockIdx.x, h = blockIdx.y;
  const int tid = threadIdx.x;
  __shared__ __bf16 A_l[32][72];
  __shared__ __bf16 B_l[32][72], K_l[32][72], R_l[32][72];
  __shared__ float W_l[33][64];
  __shared__ float Mba[32][36], Mka[32][36];
  __shared__ float P0[32][36], P1[32][36], T0[32][36], T1[32][36];

  const size_t rowbase = (size_t)(c * Cn) * Dn + (size_t)h * 64;
  const int tt = tid >> 3, j0 = (tid & 7) * 8;
  const size_t g = rowbase + (size_t)tt * Dn + j0;
  *(bf16x8*)&A_l[tt][j0] = *(const bf16x8*)(wd + g);
  __syncthreads();
  if (tid < 64) {
    const int j = tid;
    float cur = 1.f;
    W_l[0][j] = 1.f;
    for (int t = 0; t < Cn; ++t) {
      cur *= (float)A_l[t][j];
      W_l[t + 1][j] = cur;
    }
    WCg[((size_t)c * Hn + h) * 64 + j] = cur;
  }
  __syncthreads();
  {
    bf16x8 kkv = *(const bf16x8*)(kk + g);
    bf16x8 abv = *(const bf16x8*)(ab + g);
    bf16x8 kv  = *(const bf16x8*)(kf + g);
    bf16x8 rv  = *(const bf16x8*)(r + g);
    bf16x8 oa, ob, ok, orr, obh, okh;
#pragma unroll
    for (int e = 0; e < 8; ++e) {
      const int j = j0 + e;
      const float Wexc = W_l[tt][j], Winc = W_l[tt + 1][j], WC = W_l[32][j];
      const float inv = 1.f / Winc;
      const float at = -(float)kkv[e] * Wexc;
      const float bt = (float)abv[e] * inv;
      const float kt = (float)kv[e] * inv;
      const float rt = (float)rv[e] * Winc;
      oa[e] = (__bf16)at; ob[e] = (__bf16)bt; ok[e] = (__bf16)kt;
      orr[e] = (__bf16)rt;
      obh[e] = (__bf16)(bt * WC); okh[e] = (__bf16)(kt * WC);
    }
    *(bf16x8*)&A_l[tt][j0] = oa;
    *(bf16x8*)&B_l[tt][j0] = ob;
    *(bf16x8*)&K_l[tt][j0] = ok;
    *(bf16x8*)&R_l[tt][j0] = orr;
    *(bf16x8*)(Atil + g) = oa;
    *(bf16x8*)(Rtil + g) = orr;
    *(bf16x8*)(Bhat + g) = obh;
    *(bf16x8*)(Khat + g) = okh;
  }
  __syncthreads();
  const size_t matbase = ((size_t)c * Hn + h) * (Cn * Cn);
#pragma unroll 1
  for (int rep = 0; rep < 4; ++rep) {
    const int id = rep * 256 + tid;
    const int t = id >> 5, ta = id & 31;
    float d_ab = 0.f, d_ak = 0.f, d_rb = 0.f, d_rk = 0.f;
    for (int j8 = 0; j8 < 8; ++j8) {
      const bf16x8 av = *(const bf16x8*)&A_l[t][j8 * 8];
      const bf16x8 rv = *(const bf16x8*)&R_l[t][j8 * 8];
      const bf16x8 bv = *(const bf16x8*)&B_l[ta][j8 * 8];
      const bf16x8 kv = *(const bf16x8*)&K_l[ta][j8 * 8];
#pragma unroll
      for (int e = 0; e < 8; ++e) {
        const float af = (float)av[e], rf = (float)rv[e];
        const float bf2 = (float)bv[e], kf2 = (float)kv[e];
        d_ab += af * bf2; d_ak += af * kf2;
        d_rb += rf * bf2; d_rk += rf * kf2;
      }
    }
    Mba[t][ta] = (ta < t) ? d_ab : 0.f;
    Mka[t][ta] = (ta < t) ? d_ak : 0.f;
    Gbg[matbase + id] = (__bf16)((ta <= t) ? d_rb : 0.f);
    Gkg[matbase + id] = (__bf16)((ta <= t) ? d_rk : 0.f);
  }
  __syncthreads();
  for (int rep = 0; rep < 4; ++rep) {
    const int id = rep * 256 + tid;
    const int t = id >> 5, ta = id & 31;
    P0[t][ta] = Mba[t][ta] + (t == ta ? 1.f : 0.f);
  }
  __syncthreads();
  auto mm = [&](float (*D)[36], float (*Aa)[36], float (*Bb)[36]) {
    for (int rep = 0; rep < 4; ++rep) {
      const int id = rep * 256 + tid;
      const int t = id >> 5, ta = id & 31;
      float s = 0.f;
      for (int u = 0; u < 32; ++u) s += Aa[t][u] * Bb[u][ta];
      D[t][ta] = s;
    }
    __syncthreads();
  };
  auto mmadd = [&](float (*D)[36], float (*Pp)[36], float (*Tt)[36]) {
    for (int rep = 0; rep < 4; ++rep) {
      const int id = rep * 256 + tid;
      const int t = id >> 5, ta = id & 31;
      float s = Pp[t][ta];
      for (int u = 0; u < 32; ++u) s += Pp[t][u] * Tt[u][ta];
      D[t][ta] = s;
    }
    __syncthreads();
  };
  mm(T0, Mba, Mba);
  mmadd(P1, P0, T0);
  mm(T1, T0, T0);
  mmadd(P0, P1, T1);
  mm(T0, T1, T1);
  mmadd(P1, P0, T0);
  mm(T1, T0, T0);
  mmadd(P0, P1, T1);
  for (int rep = 0; rep < 4; ++rep) {
    const int id = rep * 256 + tid;
    const int t = id >> 5, ta = id & 31;
    Pg[matbase + id] = (__bf16)P0[t][ta];
    float s = 0.f;
    for (int u = 0; u < 32; ++u) s += P0[t][u] * Mka[u][ta];
    PKg[matbase + id] = (__bf16)s;
  }
}

// ---------------- chunkB: sequential over chunks, parallel (head, i-quad) ----------------

__global__ __launch_bounds__(256) void chunkB_kernel(
    const __bf16* __restrict__ Atil, const __bf16* __restrict__ Rtil,
    const __bf16* __restrict__ Bhat, const __bf16* __restrict__ Khat,
    const __bf16* __restrict__ Pg, const __bf16* __restrict__ PKg,
    const __bf16* __restrict__ Gbg, const __bf16* __restrict__ Gkg,
    const float* __restrict__ WCg, const __bf16* __restrict__ vbuf,
    const float* __restrict__ st_in, __bf16* __restrict__ xo,
    float* __restrict__ st_out) {
  const int h = blockIdx.x >> 2, iq = blockIdx.x & 3;
  const int ib = iq * 16;
  const int tid = threadIdx.x;
  __shared__ float S_l[16][68];
  __shared__ float P_l[32][36], PK_l[32][36], Gb_l[32][36], Gk_l[32][36];
  __shared__ __bf16 A_l[32][72], R_l[32][72], Bh_l[32][72], Kh_l[32][72];
  __shared__ float X_l[32][20], SA_l[32][20], V_l[32][20];
  __shared__ float WC_l[64];

  for (int rep = 0; rep < 4; ++rep) {
    const int id = rep * 256 + tid;
    const int i = id >> 6, j = id & 63;
    S_l[i][j] = st_in[(size_t)h * 4096 + (size_t)(ib + i) * 64 + j];
  }
  const int i16 = tid & 15, tq = tid >> 4;
  const int jl = tid & 63, wvi = tid >> 6;

#pragma unroll 1
  for (int c = 0; c < NCH; ++c) {
    __syncthreads();
    const size_t rowbase = (size_t)(c * Cn) * Dn + (size_t)h * 64;
    {
      const int tt = tid >> 3, j0 = (tid & 7) * 8;
      const size_t g = rowbase + (size_t)tt * Dn + j0;
      *(bf16x8*)&A_l[tt][j0]  = *(const bf16x8*)(Atil + g);
      *(bf16x8*)&R_l[tt][j0]  = *(const bf16x8*)(Rtil + g);
      *(bf16x8*)&Bh_l[tt][j0] = *(const bf16x8*)(Bhat + g);
      *(bf16x8*)&Kh_l[tt][j0] = *(const bf16x8*)(Khat + g);
    }
    const size_t matbase = ((size_t)c * Hn + h) * (Cn * Cn);
    for (int rep = 0; rep < 4; ++rep) {
      const int id = rep * 256 + tid;
      const int t = id >> 5, ta = id & 31;
      P_l[t][ta]  = (float)Pg[matbase + id];
      PK_l[t][ta] = (float)PKg[matbase + id];
      Gb_l[t][ta] = (float)Gbg[matbase + id];
      Gk_l[t][ta] = (float)Gkg[matbase + id];
    }
    for (int rep = 0; rep < 2; ++rep) {
      const int id = rep * 256 + tid;
      const int tt = id >> 4, i = id & 15;
      V_l[tt][i] = (float)vbuf[rowbase + (size_t)tt * Dn + ib + i];
    }
    if (tid < 64) WC_l[tid] = WCg[((size_t)c * Hn + h) * 64 + tid];
    __syncthreads();
    // X = Atil * S^T
    {
      float a0 = 0.f, a1 = 0.f;
      for (int j4 = 0; j4 < 16; ++j4) {
        const f32x4 s = *(const f32x4*)&S_l[i16][j4 * 4];
#pragma unroll
        for (int e = 0; e < 4; ++e) {
          const int j = j4 * 4 + e;
          a0 += s[e] * (float)A_l[tq][j];
          a1 += s[e] * (float)A_l[tq + 16][j];
        }
      }
      X_l[tq][i16] = a0; X_l[tq + 16][i16] = a1;
    }
    __syncthreads();
    // SA = P*X + PK*V
    {
      float a0 = 0.f, a1 = 0.f;
      for (int u = 0; u < 32; ++u) {
        const float xv = X_l[u][i16], vv2 = V_l[u][i16];
        a0 += P_l[tq][u] * xv + PK_l[tq][u] * vv2;
        a1 += P_l[tq + 16][u] * xv + PK_l[tq + 16][u] * vv2;
      }
      SA_l[tq][i16] = a0; SA_l[tq + 16][i16] = a1;
    }
    __syncthreads();
    // O = Gb*SA + Gk*V + Rtil*S^T
    {
      float a0 = 0.f, a1 = 0.f;
      for (int u = 0; u < 32; ++u) {
        const float sv = SA_l[u][i16], vv2 = V_l[u][i16];
        a0 += Gb_l[tq][u] * sv + Gk_l[tq][u] * vv2;
        a1 += Gb_l[tq + 16][u] * sv + Gk_l[tq + 16][u] * vv2;
      }
      for (int j4 = 0; j4 < 16; ++j4) {
        const f32x4 s = *(const f32x4*)&S_l[i16][j4 * 4];
#pragma unroll
        for (int e = 0; e < 4; ++e) {
          const int j = j4 * 4 + e;
          a0 += s[e] * (float)R_l[tq][j];
          a1 += s[e] * (float)R_l[tq + 16][j];
        }
      }
      xo[(size_t)(c * Cn + tq) * Dn + h * 64 + ib + i16] = (__bf16)a0;
      xo[(size_t)(c * Cn + tq + 16) * Dn + h * 64 + ib + i16] = (__bf16)a1;
    }
    __syncthreads();
    // S = S .* WC + SA^T * Bhat + V^T * Khat
    {
      const float wc = WC_l[jl];
      float acc[4];
#pragma unroll
      for (int ii = 0; ii < 4; ++ii) acc[ii] = S_l[wvi * 4 + ii][jl] * wc;
      for (int u = 0; u < 32; ++u) {
        const float bh = (float)Bh_l[u][jl], kh = (float)Kh_l[u][jl];
        const f32x4 sa4 = *(const f32x4*)&SA_l[u][wvi * 4];
        const f32x4 vv4 = *(const f32x4*)&V_l[u][wvi * 4];
#pragma unroll
        for (int ii = 0; ii < 4; ++ii)
          acc[ii] += sa4[ii] * bh + vv4[ii] * kh;
      }
#pragma unroll
      for (int ii = 0; ii < 4; ++ii) S_l[wvi * 4 + ii][jl] = acc[ii];
    }
  }
  __syncthreads();
  for (int rep = 0; rep < 4; ++rep) {
    const int id = rep * 256 + tid;
    const int i = id >> 6, j = id & 63;
    st_out[(size_t)h * 4096 + (size_t)(ib + i) * 64 + j] = S_l[i][j];
  }
}

// ---------------- post: per-head LN + bonus + gate -> bf16 ----------------

__global__ __launch_bounds__(256) void post_kernel(
    const __bf16* __restrict__ xo, const __bf16* __restrict__ v,
    const __bf16* __restrict__ g, const float* __restrict__ dot,
    const float* __restrict__ lnw, const float* __restrict__ lnb,
    __bf16* __restrict__ out) {
  const int t = blockIdx.x;
  const int lane = threadIdx.x & 63, wv = threadIdx.x >> 6;
#pragma unroll 1
  for (int c = 0; c < 8; ++c) {
    const int d = c * 256 + wv * 64 + lane;
    const size_t idx = (size_t)t * Dn + d;
    const float val = (float)xo[idx];
    const float mu = waveSum(val) * (1.f / 64.f);
    const float ctr = val - mu;
    const float var = waveSum(ctr * ctr) * (1.f / 64.f);
    float y = ctr * rsqrtf(var + 0.00064f);
    y = y * lnw[d] + lnb[d];
    const float res = (y + dot[t * Hn + (d >> 6)] * (float)v[idx]) * (float)g[idx];
    out[idx] = (__bf16)res;
  }
}

// ---------------- launcher ----------------

extern "C" void kernel_launch(void* const* d_in, const int* in_sizes, int n_in,
                              void* d_out, int out_size, void* d_ws, size_t ws_size,
                              hipStream_t stream) {
  (void)in_sizes; (void)n_in; (void)out_size; (void)ws_size;
  const float* x       = (const float*)d_in[0];
  const float* state1  = (const float*)d_in[1];
  const float* state2  = (const float*)d_in[2];
  const float* v_first = (const float*)d_in[3];
  const float* ln1_w   = (const float*)d_in[4];
  const float* ln1_b   = (const float*)d_in[5];
  const float* x_r     = (const float*)d_in[6];
  const float* x_w     = (const float*)d_in[7];
  const float* x_k     = (const float*)d_in[8];
  const float* x_v     = (const float*)d_in[9];
  const float* x_a     = (const float*)d_in[10];
  const float* x_g     = (const float*)d_in[11];
  const float* W_r     = (const float*)d_in[12];
  const float* W_k     = (const float*)d_in[13];
  const float* W_v     = (const float*)d_in[14];
  const float* W_o     = (const float*)d_in[15];
  const float* w1      = (const float*)d_in[16];
  const float* w2      = (const float*)d_in[17];
  const float* w0      = (const float*)d_in[18];
  const float* a1      = (const float*)d_in[19];
  const float* a2      = (const float*)d_in[20];
  const float* a0      = (const float*)d_in[21];
  const float* v1      = (const float*)d_in[22];
  const float* v2      = (const float*)d_in[23];
  const float* v0      = (const float*)d_in[24];
  const float* g1      = (const float*)d_in[25];
  const float* g2      = (const float*)d_in[26];
  const float* k_k     = (const float*)d_in[27];
  const float* k_a     = (const float*)d_in[28];
  const float* r_k     = (const float*)d_in[29];
  const float* lnx_w   = (const float*)d_in[30];
  const float* lnx_b   = (const float*)d_in[31];

  char* p = (char*)d_ws;
  const size_t MB = 1ull << 20;
  // 14 slots x 8 MB + smalls(~6.9MB) = ~119 MB. Lifetimes as round 7, plus
  // padded LoRA buffers in the smalls region.
  __bf16* xn    = (__bf16*)(p + 0 * MB);
  __bf16* Atil  = (__bf16*)(p + 0 * MB);
  __bf16* xr_b  = (__bf16*)(p + 8 * MB);
  __bf16* Wo_b  = (__bf16*)(p + 8 * MB);
  __bf16* xw_b  = (__bf16*)(p + 16 * MB);
  __bf16* wdec  = (__bf16*)(p + 16 * MB);
  __bf16* xo_b  = (__bf16*)(p + 16 * MB);
  __bf16* xk_b  = (__bf16*)(p + 24 * MB);
  __bf16* abuf  = (__bf16*)(p + 24 * MB);
  __bf16* Rtil  = (__bf16*)(p + 24 * MB);
  __bf16* xv_b  = (__bf16*)(p + 32 * MB);
  __bf16* vbl   = (__bf16*)(p + 32 * MB);
  __bf16* Bhat  = (__bf16*)(p + 32 * MB);
  __bf16* xa_b  = (__bf16*)(p + 40 * MB);
  __bf16* gbuf  = (__bf16*)(p + 40 * MB);
  __bf16* xg_b  = (__bf16*)(p + 48 * MB);
  __bf16* kkbuf = (__bf16*)(p + 48 * MB);
  __bf16* xobuf = (__bf16*)(p + 48 * MB);
  __bf16* Wr_b  = (__bf16*)(p + 56 * MB);
  __bf16* abbuf = (__bf16*)(p + 56 * MB);
  __bf16* Wk_b  = (__bf16*)(p + 64 * MB);
  __bf16* Khat  = (__bf16*)(p + 64 * MB);
  __bf16* Wv_b  = (__bf16*)(p + 72 * MB);
  __bf16* Pg    = (__bf16*)(p + 72 * MB);
  __bf16* PKg   = (__bf16*)(p + 76 * MB);
  __bf16* rbuf  = (__bf16*)(p + 80 * MB);
  __bf16* kbuf  = (__bf16*)(p + 88 * MB);
  __bf16* vbuf  = (__bf16*)(p + 96 * MB);
  __bf16* Gbg   = (__bf16*)(p + 104 * MB);
  __bf16* Gkg   = (__bf16*)(p + 108 * MB);
  char* q = p + 112 * MB;
  __bf16* yw  = (__bf16*)q; q += (size_t)Tn * 128 * 2;   // padded [T][128]
  __bf16* ya  = (__bf16*)q; q += (size_t)Tn * 128 * 2;
  __bf16* yv  = (__bf16*)q; q += (size_t)Tn * 128 * 2;
  __bf16* yg  = (__bf16*)q; q += (size_t)Tn * 128 * 2;
  __bf16* uwT = (__bf16*)q; q += (size_t)128 * Dn * 2;   // [128][D] padded
  __bf16* uaT = (__bf16*)q; q += (size_t)128 * Dn * 2;
  __bf16* uvT = (__bf16*)q; q += (size_t)128 * Dn * 2;
  __bf16* ugT = (__bf16*)q; q += (size_t)128 * Dn * 2;
  __bf16* w2T = (__bf16*)q; q += (size_t)Dn * 128 * 2;   // [D][128] padded
  __bf16* a2T = (__bf16*)q; q += (size_t)Dn * 128 * 2;
  __bf16* v2T = (__bf16*)q; q += (size_t)Dn * 128 * 2;
  __bf16* g2T = (__bf16*)q; q += (size_t)Dn * 128 * 2;
  float*  dot = (float*)q;  q += (size_t)Tn * Hn * 4;
  float*  WCg = (float*)q;  q += (size_t)NCH * Hn * 64 * 4;

  float* out     = (float*)d_out;
  float* out_xnl = out + (size_t)Tn * Dn;
  float* out_st  = out_xnl + Dn;

  castw3_kernel<<<dim3(4096, 3), 256, 0, stream>>>(W_r, W_k, W_v, Wr_b, Wk_b, Wv_b);
  castT_kernel<<<2048, 256, 0, stream>>>(w2, a2, v2, g2, w2T, a2T, v2T, g2T);
  castU_kernel<<<dim3(2048, 4), 256, 0, stream>>>(w1, a1, v1, g1, uwT, uaT, uvT, ugT);
  ln_kernel<<<2048, 256, 0, stream>>>(x, ln1_w, ln1_b, xn, out_xnl);
  mix_kernel<<<4096, 256, 0, stream>>>(xn, state1, x_r, x_w, x_k, x_v, x_a, x_g,
                                       xr_b, xw_b, xk_b, xv_b, xa_b, xg_b);
  gemm3_kernel<<<dim3(16, 16, 3), 256, 0, stream>>>(
      xr_b, xk_b, xv_b, Wr_b, Wk_b, Wv_b, rbuf, kbuf, vbuf);
  cast1_kernel<<<4096, 256, 0, stream>>>(W_o, Wo_b);
  gemm_l1_kernel<<<dim3(16, 1, 4), 256, 0, stream>>>(
      xw_b, xa_b, xv_b, xg_b, uwT, uaT, uvT, ugT, yw, ya, yv, yg);
  gemm_s2_kernel<<<dim3(16, 16, 4), 256, 0, stream>>>(
      yw, ya, yv, yg, w2T, a2T, v2T, g2T, w0, a0, v0, wdec, abuf, vbl, gbuf);
  prep_kernel<<<2048, 256, 0, stream>>>(rbuf, kbuf, vbuf, abuf, vbl, v_first,
                                        k_k, k_a, r_k, kkbuf, abbuf, dot);
  chunkA_kernel<<<dim3(NCH, Hn), 256, 0, stream>>>(
      wdec, kkbuf, abbuf, kbuf, rbuf,
      Atil, Rtil, Bhat, Khat, Pg, PKg, Gbg, Gkg, WCg);
  chunkB_kernel<<<128, 256, 0, stream>>>(
      Atil, Rtil, Bhat, Khat, Pg, PKg, Gbg, Gkg, WCg, vbuf,
      state2, xobuf, out_st);
  post_kernel<<<2048, 256, 0, stream>>>(xobuf, vbuf, gbuf, dot, lnx_w, lnx_b, xo_b);
  gemm_wo_kernel<<<dim3(16, 16), 256, 0, stream>>>(xo_b, Wo_b, x, out);
}

// Round 9
// 613.771 us; speedup vs baseline: 1.9874x; 1.1798x over previous
//
#include <hip/hip_runtime.h>

#define Tn 2048
#define Dn 2048
#define Hn 32
#define Cn 32
#define NCH (Tn / Cn)

typedef float f32x4 __attribute__((ext_vector_type(4)));
typedef __bf16 bf16x8 __attribute__((ext_vector_type(8)));
typedef __bf16 bf16x4 __attribute__((ext_vector_type(4)));

// ---- fast wave-64 sum: DPP row reductions (VALU) + readlane ----
template <int CTRL>
__device__ __forceinline__ float dpp_add(float x) {
  int xi = __builtin_bit_cast(int, x);
  int sh = __builtin_amdgcn_update_dpp(0, xi, CTRL, 0xf, 0xf, true);
  return x + __builtin_bit_cast(float, sh);
}
__device__ __forceinline__ float rdlane(float x, int l) {
  int xi = __builtin_bit_cast(int, x);
  return __builtin_bit_cast(float, __builtin_amdgcn_readlane(xi, l));
}
__device__ __forceinline__ float waveSum(float v) {
  v = dpp_add<0x111>(v);
  v = dpp_add<0x112>(v);
  v = dpp_add<0x114>(v);
  v = dpp_add<0x118>(v);
  return (rdlane(v, 15) + rdlane(v, 31)) + (rdlane(v, 47) + rdlane(v, 63));
}

__device__ __forceinline__ float sigm(float x) { return 1.f / (1.f + expf(-x)); }

__device__ __forceinline__ void gl_lds16(const void* g, void* l) {
  __builtin_amdgcn_global_load_lds(
      (__attribute__((address_space(1))) void*)(g),
      (__attribute__((address_space(3))) void*)(l), 16, 0, 0);
}

// ---------------- weight casts ----------------

__global__ __launch_bounds__(256) void castw3_kernel(
    const float* __restrict__ A, const float* __restrict__ B,
    const float* __restrict__ C, __bf16* __restrict__ o0,
    __bf16* __restrict__ o1, __bf16* __restrict__ o2) {
  const int z = blockIdx.y;
  const float* src = z == 0 ? A : (z == 1 ? B : C);
  __bf16* dst = z == 0 ? o0 : (z == 1 ? o1 : o2);
  const size_t i4 = (size_t)blockIdx.x * 256 + threadIdx.x;
  f32x4 v = *(const f32x4*)(src + i4 * 4);
  bf16x4 o;
  o[0] = (__bf16)v[0]; o[1] = (__bf16)v[1]; o[2] = (__bf16)v[2]; o[3] = (__bf16)v[3];
  ((bf16x4*)dst)[i4] = o;
}

__global__ __launch_bounds__(256) void cast1_kernel(
    const float* __restrict__ src, __bf16* __restrict__ dst) {
  const size_t i4 = (size_t)blockIdx.x * 256 + threadIdx.x;
  f32x4 v = *(const f32x4*)(src + i4 * 4);
  bf16x4 o;
  o[0] = (__bf16)v[0]; o[1] = (__bf16)v[1]; o[2] = (__bf16)v[2]; o[3] = (__bf16)v[3];
  ((bf16x4*)dst)[i4] = o;
}

// stage-2 weights: transpose-cast to [D][128] bf16, zero-padded beyond R
__global__ __launch_bounds__(256) void castT_kernel(
    const float* __restrict__ w2, const float* __restrict__ a2,
    const float* __restrict__ v2, const float* __restrict__ g2,
    __bf16* __restrict__ w2T, __bf16* __restrict__ a2T,
    __bf16* __restrict__ v2T, __bf16* __restrict__ g2T) {
  const int i = blockIdx.x;   // D index
  const int k = threadIdx.x;
  if (k < 128) {
    w2T[(size_t)i * 128 + k] = (k < 64) ? (__bf16)w2[(size_t)k * Dn + i] : (__bf16)0.f;
    a2T[(size_t)i * 128 + k] = (k < 64) ? (__bf16)a2[(size_t)k * Dn + i] : (__bf16)0.f;
    v2T[(size_t)i * 128 + k] = (k < 32) ? (__bf16)v2[(size_t)k * Dn + i] : (__bf16)0.f;
    g2T[(size_t)i * 128 + k] = (__bf16)g2[(size_t)k * Dn + i];
  }
}

// stage-1 (LoRA down) weights: [D][R] f32 -> [128][D] bf16, zero-padded rows
__global__ __launch_bounds__(256) void castU_kernel(
    const float* __restrict__ w1, const float* __restrict__ a1,
    const float* __restrict__ v1, const float* __restrict__ g1,
    __bf16* __restrict__ uwT, __bf16* __restrict__ uaT,
    __bf16* __restrict__ uvT, __bf16* __restrict__ ugT) {
  const int z = blockIdx.y;
  const float* src = z == 0 ? w1 : (z == 1 ? a1 : (z == 2 ? v1 : g1));
  __bf16* dst = z == 0 ? uwT : (z == 1 ? uaT : (z == 2 ? uvT : ugT));
  const int R = z == 0 ? 64 : (z == 1 ? 64 : (z == 2 ? 32 : 128));
  const int d = blockIdx.x;
  const int k = threadIdx.x;
  if (k < 128)
    dst[(size_t)k * Dn + d] = (k < R) ? (__bf16)src[(size_t)d * R + k] : (__bf16)0.f;
}

// ---------------- layernorm (ln1) ----------------

__global__ __launch_bounds__(256) void ln_kernel(
    const float* __restrict__ x, const float* __restrict__ lw,
    const float* __restrict__ lb, __bf16* __restrict__ xn,
    float* __restrict__ xn_last) {
  __shared__ float red[8];
  const int t = blockIdx.x, tid = threadIdx.x;
  const int lane = tid & 63, wv = tid >> 6;
  const float* xr = x + (size_t)t * Dn;
  float v[8];
  float s = 0.f;
#pragma unroll
  for (int c = 0; c < 8; ++c) { v[c] = xr[tid + c * 256]; s += v[c]; }
  s = waveSum(s);
  if (lane == 0) red[wv] = s;
  __syncthreads();
  const float mu = (red[0] + red[1] + red[2] + red[3]) * (1.f / (float)Dn);
  float q = 0.f;
#pragma unroll
  for (int c = 0; c < 8; ++c) { float d0 = v[c] - mu; q += d0 * d0; }
  q = waveSum(q);
  if (lane == 0) red[4 + wv] = q;
  __syncthreads();
  const float var = (red[4] + red[5] + red[6] + red[7]) * (1.f / (float)Dn);
  const float rstd = rsqrtf(var + 1e-5f);
#pragma unroll
  for (int c = 0; c < 8; ++c) {
    const int d = tid + c * 256;
    const float y = (v[c] - mu) * rstd * lw[d] + lb[d];
    xn[(size_t)t * Dn + d] = (__bf16)y;
    if (t == Tn - 1) xn_last[d] = y;
  }
}

// ---------------- token-shift mix ----------------

__global__ __launch_bounds__(256) void mix_kernel(
    const __bf16* __restrict__ xn, const float* __restrict__ state1,
    const float* __restrict__ cr, const float* __restrict__ cw,
    const float* __restrict__ ck, const float* __restrict__ cv,
    const float* __restrict__ ca, const float* __restrict__ cg,
    __bf16* __restrict__ br, __bf16* __restrict__ bw, __bf16* __restrict__ bk,
    __bf16* __restrict__ bv, __bf16* __restrict__ ba, __bf16* __restrict__ bg) {
  const size_t i4 = (size_t)blockIdx.x * 256 + threadIdx.x;
  const int t = (int)(i4 >> 9);
  const int d = (int)(i4 & 511) * 4;
  const bf16x4 cb = ((const bf16x4*)xn)[i4];
  f32x4 cur;
#pragma unroll
  for (int e = 0; e < 4; ++e) cur[e] = (float)cb[e];
  f32x4 prv;
  if (t == 0) {
    prv = *(const f32x4*)(state1 + d);
  } else {
    const bf16x4 pb = ((const bf16x4*)xn)[i4 - 512];
#pragma unroll
    for (int e = 0; e < 4; ++e) prv[e] = (float)pb[e];
  }
  const f32x4 sx = prv - cur;
  auto mix1 = [&](const float* c, __bf16* o) {
    const f32x4 cc = *(const f32x4*)(c + d);
    bf16x4 ob;
#pragma unroll
    for (int e = 0; e < 4; ++e) ob[e] = (__bf16)(cur[e] + sx[e] * cc[e]);
    ((bf16x4*)o)[i4] = ob;
  };
  mix1(cr, br); mix1(cw, bw); mix1(ck, bk);
  mix1(cv, bv); mix1(ca, ba); mix1(cg, bg);
}

// ---------------- MFMA GEMM tile core ----------------

__device__ __forceinline__ void gemm_tile(const __bf16* __restrict__ A,
                                          const __bf16* __restrict__ B,
                                          int K, int row0, int col0,
                                          f32x4 (&acc)[4][4]) {
  __shared__ __attribute__((aligned(16))) __bf16 As[4096];
  __shared__ __attribute__((aligned(16))) __bf16 Bs[4096];
  const int tid = threadIdx.x;
  const int lane = tid & 63, wid = tid >> 6;
  const int wm = (wid >> 1) * 64, wn = (wid & 1) * 64;
  const int lr = lane & 15, lk = (lane >> 4) * 8;
  for (int kt = 0; kt < K; kt += 32) {
#pragma unroll
    for (int it = 0; it < 2; ++it) {
      const int L = it * 256 + tid;
      const int rr = L >> 2, kc = (L & 3) * 8;
      const int lb = (it * 256 + wid * 64) * 8;
      gl_lds16(A + (size_t)(row0 + rr) * K + (kt + kc), &As[lb]);
      gl_lds16(B + (size_t)(col0 + rr) * K + (kt + kc), &Bs[lb]);
    }
    __syncthreads();
    bf16x8 af[4], bfv[4];
#pragma unroll
    for (int mf = 0; mf < 4; ++mf)
      af[mf] = *(const bf16x8*)&As[(wm + mf * 16 + lr) * 32 + lk];
#pragma unroll
    for (int nf = 0; nf < 4; ++nf)
      bfv[nf] = *(const bf16x8*)&Bs[(wn + nf * 16 + lr) * 32 + lk];
#pragma unroll
    for (int mf = 0; mf < 4; ++mf)
#pragma unroll
      for (int nf = 0; nf < 4; ++nf)
        acc[mf][nf] = __builtin_amdgcn_mfma_f32_16x16x32_bf16(
            af[mf], bfv[nf], acc[mf][nf], 0, 0, 0);
    __syncthreads();
  }
}

__global__ __launch_bounds__(256) void gemm3_kernel(
    const __bf16* __restrict__ A0, const __bf16* __restrict__ A1,
    const __bf16* __restrict__ A2, const __bf16* __restrict__ B0,
    const __bf16* __restrict__ B1, const __bf16* __restrict__ B2,
    __bf16* __restrict__ C0, __bf16* __restrict__ C1, __bf16* __restrict__ C2) {
  const int z = blockIdx.z;
  const __bf16* A = z == 0 ? A0 : (z == 1 ? A1 : A2);
  const __bf16* B = z == 0 ? B0 : (z == 1 ? B1 : B2);
  __bf16* C = z == 0 ? C0 : (z == 1 ? C1 : C2);
  const int row0 = blockIdx.x * 128, col0 = blockIdx.y * 128;
  f32x4 acc[4][4] = {};
  gemm_tile(A, B, Dn, row0, col0, acc);
  const int lane = threadIdx.x & 63, wid = threadIdx.x >> 6;
  const int wm = (wid >> 1) * 64, wn = (wid & 1) * 64;
#pragma unroll
  for (int mf = 0; mf < 4; ++mf) {
    const int r0 = row0 + wm + mf * 16 + ((lane >> 4) << 2);
#pragma unroll
    for (int nf = 0; nf < 4; ++nf) {
      const int c0 = col0 + wn + nf * 16 + (lane & 15);
#pragma unroll
      for (int rg = 0; rg < 4; ++rg)
        C[(size_t)(r0 + rg) * Dn + c0] = (__bf16)acc[mf][nf][rg];
    }
  }
}

// LoRA stage-1 as MFMA GEMM: Y[T][128] = X[T][D] @ U^T, epilogue per path
__global__ __launch_bounds__(256) void gemm_l1_kernel(
    const __bf16* __restrict__ Aw, const __bf16* __restrict__ Aa,
    const __bf16* __restrict__ Av, const __bf16* __restrict__ Ag,
    const __bf16* __restrict__ Bw, const __bf16* __restrict__ Ba,
    const __bf16* __restrict__ Bv, const __bf16* __restrict__ Bg,
    __bf16* __restrict__ Cw, __bf16* __restrict__ Ca,
    __bf16* __restrict__ Cv, __bf16* __restrict__ Cg) {
  const int z = blockIdx.z;
  const __bf16* A = z == 0 ? Aw : (z == 1 ? Aa : (z == 2 ? Av : Ag));
  const __bf16* B = z == 0 ? Bw : (z == 1 ? Ba : (z == 2 ? Bv : Bg));
  __bf16* C = z == 0 ? Cw : (z == 1 ? Ca : (z == 2 ? Cv : Cg));
  const int row0 = blockIdx.x * 128;
  f32x4 acc[4][4] = {};
  gemm_tile(A, B, Dn, row0, 0, acc);
  const int lane = threadIdx.x & 63, wid = threadIdx.x >> 6;
  const int wm = (wid >> 1) * 64, wn = (wid & 1) * 64;
#pragma unroll
  for (int mf = 0; mf < 4; ++mf) {
    const int r0 = row0 + wm + mf * 16 + ((lane >> 4) << 2);
#pragma unroll
    for (int nf = 0; nf < 4; ++nf) {
      const int c0 = wn + nf * 16 + (lane & 15);
#pragma unroll
      for (int rg = 0; rg < 4; ++rg) {
        float val = acc[mf][nf][rg];
        if (z == 0)      val = tanhf(val);
        else if (z == 3) val = sigm(val);
        C[(size_t)(r0 + rg) * 128 + c0] = (__bf16)val;
      }
    }
  }
}

// LoRA stage-2 fused, uniform K=128 (zero-padded), bf16 outputs
__global__ __launch_bounds__(256) void gemm_s2_kernel(
    const __bf16* __restrict__ Aw, const __bf16* __restrict__ Aa,
    const __bf16* __restrict__ Av, const __bf16* __restrict__ Ag,
    const __bf16* __restrict__ Bw, const __bf16* __restrict__ Ba,
    const __bf16* __restrict__ Bv, const __bf16* __restrict__ Bg,
    const float* __restrict__ w0, const float* __restrict__ a0,
    const float* __restrict__ v0, __bf16* __restrict__ Cw,
    __bf16* __restrict__ Ca, __bf16* __restrict__ Cv, __bf16* __restrict__ Cg) {
  const int z = blockIdx.z;
  const __bf16* A = z == 0 ? Aw : (z == 1 ? Aa : (z == 2 ? Av : Ag));
  const __bf16* B = z == 0 ? Bw : (z == 1 ? Ba : (z == 2 ? Bv : Bg));
  const float* bias = z == 0 ? w0 : (z == 1 ? a0 : (z == 2 ? v0 : (const float*)0));
  __bf16* C = z == 0 ? Cw : (z == 1 ? Ca : (z == 2 ? Cv : Cg));
  const int row0 = blockIdx.x * 128, col0 = blockIdx.y * 128;
  f32x4 acc[4][4] = {};
  gemm_tile(A, B, 128, row0, col0, acc);
  const int lane = threadIdx.x & 63, wid = threadIdx.x >> 6;
  const int wm = (wid >> 1) * 64, wn = (wid & 1) * 64;
#pragma unroll
  for (int mf = 0; mf < 4; ++mf) {
    const int r0 = row0 + wm + mf * 16 + ((lane >> 4) << 2);
#pragma unroll
    for (int nf = 0; nf < 4; ++nf) {
      const int c0 = col0 + wn + nf * 16 + (lane & 15);
#pragma unroll
      for (int rg = 0; rg < 4; ++rg) {
        float val = acc[mf][nf][rg];
        if (z == 0)      val = expf(-0.606531f * sigm(val + bias[c0]));
        else if (z < 3)  val = sigm(val + bias[c0]);
        C[(size_t)(r0 + rg) * Dn + c0] = (__bf16)val;
      }
    }
  }
}

__global__ __launch_bounds__(256) void gemm_wo_kernel(
    const __bf16* __restrict__ A, const __bf16* __restrict__ B,
    const float* __restrict__ xres, float* __restrict__ C) {
  const int row0 = blockIdx.x * 128, col0 = blockIdx.y * 128;
  f32x4 acc[4][4] = {};
  gemm_tile(A, B, Dn, row0, col0, acc);
  const int lane = threadIdx.x & 63, wid = threadIdx.x >> 6;
  const int wm = (wid >> 1) * 64, wn = (wid & 1) * 64;
#pragma unroll
  for (int mf = 0; mf < 4; ++mf) {
    const int r0 = row0 + wm + mf * 16 + ((lane >> 4) << 2);
#pragma unroll
    for (int nf = 0; nf < 4; ++nf) {
      const int c0 = col0 + wn + nf * 16 + (lane & 15);
#pragma unroll
      for (int rg = 0; rg < 4; ++rg)
        C[(size_t)(r0 + rg) * Dn + c0] =
            acc[mf][nf][rg] + xres[(size_t)(r0 + rg) * Dn + c0];
    }
  }
}

// ---------------- prep: v-blend, kk-norm, k-mod, ab, bonus dot ----------------

__global__ __launch_bounds__(256) void prep_kernel(
    const __bf16* __restrict__ r, __bf16* __restrict__ k, __bf16* __restrict__ v,
    const __bf16* __restrict__ a, const __bf16* __restrict__ vb,
    const float* __restrict__ v_first, const float* __restrict__ k_k,
    const float* __restrict__ k_a, const float* __restrict__ r_k,
    __bf16* __restrict__ kk_out, __bf16* __restrict__ ab_out,
    float* __restrict__ dot_out) {
  const int t = blockIdx.x;
  const int lane = threadIdx.x & 63, wv = threadIdx.x >> 6;
#pragma unroll 1
  for (int c = 0; c < 8; ++c) {
    const int d = c * 256 + wv * 64 + lane;
    const size_t idx = (size_t)t * Dn + d;
    const float kvv = (float)k[idx];
    const float kh = kvv * k_k[d];
    const float nrm = sqrtf(waveSum(kh * kh)) + 1e-6f;
    const float kkv = kh / nrm;
    const float av = (float)a[idx];
    float vv = (float)v[idx];
    vv = vv + (v_first[idx] - vv) * (float)vb[idx];
    const float kfv = kvv * (1.f + (av - 1.f) * k_a[d]);
    const float dt = waveSum((float)r[idx] * kfv * r_k[d]);
    kk_out[idx] = (__bf16)kkv;
    ab_out[idx] = (__bf16)(kkv * av);
    k[idx] = (__bf16)kfv;
    v[idx] = (__bf16)vv;
    if (lane == 0) dot_out[t * Hn + (d >> 6)] = dt;
  }
}

// ---------------- chunkA: per-chunk decay mats + triangular inverse ----------------

__global__ __launch_bounds__(256) void chunkA_kernel(
    const __bf16* __restrict__ wd, const __bf16* __restrict__ kk,
    const __bf16* __restrict__ ab, const __bf16* __restrict__ kf,
    const __bf16* __restrict__ r,
    __bf16* __restrict__ Atil, __bf16* __restrict__ Rtil,
    __bf16* __restrict__ Bhat, __bf16* __restrict__ Khat,
    __bf16* __restrict__ Pg, __bf16* __restrict__ PKg,
    __bf16* __restrict__ Gbg, __bf16* __restrict__ Gkg,
    float* __restrict__ WCg) {
  const int c = blockIdx.x, h = blockIdx.y;
  const int tid = threadIdx.x;
  __shared__ __bf16 A_l[32][72];
  __shared__ __bf16 B_l[32][72], K_l[32][72], R_l[32][72];
  __shared__ float W_l[33][64];
  __shared__ float Mba[32][36], Mka[32][36];
  __shared__ float P0[32][36], P1[32][36], T0[32][36], T1[32][36];

  const size_t rowbase = (size_t)(c * Cn) * Dn + (size_t)h * 64;
  const int tt = tid >> 3, j0 = (tid & 7) * 8;
  const size_t g = rowbase + (size_t)tt * Dn + j0;
  *(bf16x8*)&A_l[tt][j0] = *(const bf16x8*)(wd + g);
  __syncthreads();
  if (tid < 64) {
    const int j = tid;
    float cur = 1.f;
    W_l[0][j] = 1.f;
    for (int t = 0; t < Cn; ++t) {
      cur *= (float)A_l[t][j];
      W_l[t + 1][j] = cur;
    }
    WCg[((size_t)c * Hn + h) * 64 + j] = cur;
  }
  __syncthreads();
  {
    bf16x8 kkv = *(const bf16x8*)(kk + g);
    bf16x8 abv = *(const bf16x8*)(ab + g);
    bf16x8 kv  = *(const bf16x8*)(kf + g);
    bf16x8 rv  = *(const bf16x8*)(r + g);
    bf16x8 oa, ob, ok, orr, obh, okh;
#pragma unroll
    for (int e = 0; e < 8; ++e) {
      const int j = j0 + e;
      const float Wexc = W_l[tt][j], Winc = W_l[tt + 1][j], WC = W_l[32][j];
      const float inv = 1.f / Winc;
      const float at = -(float)kkv[e] * Wexc;
      const float bt = (float)abv[e] * inv;
      const float kt = (float)kv[e] * inv;
      const float rt = (float)rv[e] * Winc;
      oa[e] = (__bf16)at; ob[e] = (__bf16)bt; ok[e] = (__bf16)kt;
      orr[e] = (__bf16)rt;
      obh[e] = (__bf16)(bt * WC); okh[e] = (__bf16)(kt * WC);
    }
    *(bf16x8*)&A_l[tt][j0] = oa;
    *(bf16x8*)&B_l[tt][j0] = ob;
    *(bf16x8*)&K_l[tt][j0] = ok;
    *(bf16x8*)&R_l[tt][j0] = orr;
    *(bf16x8*)(Atil + g) = oa;
    *(bf16x8*)(Rtil + g) = orr;
    *(bf16x8*)(Bhat + g) = obh;
    *(bf16x8*)(Khat + g) = okh;
  }
  __syncthreads();
  const size_t matbase = ((size_t)c * Hn + h) * (Cn * Cn);
#pragma unroll 1
  for (int rep = 0; rep < 4; ++rep) {
    const int id = rep * 256 + tid;
    const int t = id >> 5, ta = id & 31;
    float d_ab = 0.f, d_ak = 0.f, d_rb = 0.f, d_rk = 0.f;
    for (int j8 = 0; j8 < 8; ++j8) {
      const bf16x8 av = *(const bf16x8*)&A_l[t][j8 * 8];
      const bf16x8 rv = *(const bf16x8*)&R_l[t][j8 * 8];
      const bf16x8 bv = *(const bf16x8*)&B_l[ta][j8 * 8];
      const bf16x8 kv = *(const bf16x8*)&K_l[ta][j8 * 8];
#pragma unroll
      for (int e = 0; e < 8; ++e) {
        const float af = (float)av[e], rf = (float)rv[e];
        const float bf2 = (float)bv[e], kf2 = (float)kv[e];
        d_ab += af * bf2; d_ak += af * kf2;
        d_rb += rf * bf2; d_rk += rf * kf2;
      }
    }
    Mba[t][ta] = (ta < t) ? d_ab : 0.f;
    Mka[t][ta] = (ta < t) ? d_ak : 0.f;
    Gbg[matbase + id] = (__bf16)((ta <= t) ? d_rb : 0.f);
    Gkg[matbase + id] = (__bf16)((ta <= t) ? d_rk : 0.f);
  }
  __syncthreads();
  for (int rep = 0; rep < 4; ++rep) {
    const int id = rep * 256 + tid;
    const int t = id >> 5, ta = id & 31;
    P0[t][ta] = Mba[t][ta] + (t == ta ? 1.f : 0.f);
  }
  __syncthreads();
  auto mm = [&](float (*D)[36], float (*Aa)[36], float (*Bb)[36]) {
    for (int rep = 0; rep < 4; ++rep) {
      const int id = rep * 256 + tid;
      const int t = id >> 5, ta = id & 31;
      float s = 0.f;
      for (int u = 0; u < 32; ++u) s += Aa[t][u] * Bb[u][ta];
      D[t][ta] = s;
    }
    __syncthreads();
  };
  auto mmadd = [&](float (*D)[36], float (*Pp)[36], float (*Tt)[36]) {
    for (int rep = 0; rep < 4; ++rep) {
      const int id = rep * 256 + tid;
      const int t = id >> 5, ta = id & 31;
      float s = Pp[t][ta];
      for (int u = 0; u < 32; ++u) s += Pp[t][u] * Tt[u][ta];
      D[t][ta] = s;
    }
    __syncthreads();
  };
  mm(T0, Mba, Mba);
  mmadd(P1, P0, T0);
  mm(T1, T0, T0);
  mmadd(P0, P1, T1);
  mm(T0, T1, T1);
  mmadd(P1, P0, T0);
  mm(T1, T0, T0);
  mmadd(P0, P1, T1);
  for (int rep = 0; rep < 4; ++rep) {
    const int id = rep * 256 + tid;
    const int t = id >> 5, ta = id & 31;
    Pg[matbase + id] = (__bf16)P0[t][ta];
    float s = 0.f;
    for (int u = 0; u < 32; ++u) s += P0[t][u] * Mka[u][ta];
    PKg[matbase + id] = (__bf16)s;
  }
}

// ---------------- chunkB: sequential over chunks, 256 blocks (h x 8 i-cols) ----------------
// Register-prefetch of next chunk's data hides global latency under compute.

__global__ __launch_bounds__(256) void chunkB_kernel(
    const __bf16* __restrict__ Atil, const __bf16* __restrict__ Rtil,
    const __bf16* __restrict__ Bhat, const __bf16* __restrict__ Khat,
    const __bf16* __restrict__ Pg, const __bf16* __restrict__ PKg,
    const __bf16* __restrict__ Gbg, const __bf16* __restrict__ Gkg,
    const float* __restrict__ WCg, const __bf16* __restrict__ vbuf,
    const float* __restrict__ st_in, __bf16* __restrict__ xo,
    float* __restrict__ st_out) {
  const int h = blockIdx.x >> 3, io = (blockIdx.x & 7) * 8;
  const int tid = threadIdx.x;
  __shared__ __attribute__((aligned(16))) float S_l[8][68];
  __shared__ __attribute__((aligned(16))) float P_l[32][36], PK_l[32][36];
  __shared__ __attribute__((aligned(16))) float Gb_l[32][36], Gk_l[32][36];
  __shared__ __attribute__((aligned(16))) __bf16 A_l[32][72], R_l[32][72];
  __shared__ __attribute__((aligned(16))) __bf16 Bh_l[32][72], Kh_l[32][72];
  __shared__ __attribute__((aligned(16))) float X_l[32][12], SA_l[32][12], V_l[32][12];
  __shared__ float WC_l[64];

  // initial S rows [io..io+8)
  for (int rep = 0; rep < 2; ++rep) {
    const int id = rep * 256 + tid;
    const int i = id >> 6, j = id & 63;
    S_l[i][j] = st_in[(size_t)h * 4096 + (size_t)(io + i) * 64 + j];
  }
  const int t32 = tid >> 3, i8 = tid & 7;     // compute + row-load mapping
  const int j0 = i8 * 8;                       // row-load col base
  const int jl = tid & 63, i4 = tid >> 6;      // S-update mapping

  bf16x8 rA, rR, rB, rK;
  bf16x4 rP, rPK, rGb, rGk;
  __bf16 rV;
  float rWC = 0.f;

  auto load_regs = [&](int c) {
    const size_t rowbase = (size_t)(c * Cn) * Dn + (size_t)h * 64;
    const size_t g = rowbase + (size_t)t32 * Dn + j0;
    rA = *(const bf16x8*)(Atil + g);
    rR = *(const bf16x8*)(Rtil + g);
    rB = *(const bf16x8*)(Bhat + g);
    rK = *(const bf16x8*)(Khat + g);
    const size_t matbase = ((size_t)c * Hn + h) * (Cn * Cn) + (size_t)tid * 4;
    rP  = *(const bf16x4*)(Pg + matbase);
    rPK = *(const bf16x4*)(PKg + matbase);
    rGb = *(const bf16x4*)(Gbg + matbase);
    rGk = *(const bf16x4*)(Gkg + matbase);
    rV = vbuf[rowbase + (size_t)t32 * Dn + io + i8];
    if (tid < 64) rWC = WCg[((size_t)c * Hn + h) * 64 + tid];
  };
  auto store_lds = [&]() {
    *(bf16x8*)&A_l[t32][j0]  = rA;
    *(bf16x8*)&R_l[t32][j0]  = rR;
    *(bf16x8*)&Bh_l[t32][j0] = rB;
    *(bf16x8*)&Kh_l[t32][j0] = rK;
    const int mc = i8 * 4;
#pragma unroll
    for (int e = 0; e < 4; ++e) {
      P_l[t32][mc + e]  = (float)rP[e];
      PK_l[t32][mc + e] = (float)rPK[e];
      Gb_l[t32][mc + e] = (float)rGb[e];
      Gk_l[t32][mc + e] = (float)rGk[e];
    }
    V_l[t32][i8] = (float)rV;
    if (tid < 64) WC_l[tid] = rWC;
  };

  load_regs(0);
  store_lds();
  __syncthreads();

#pragma unroll 1
  for (int c = 0; c < NCH; ++c) {
    load_regs(c + 1 < NCH ? c + 1 : c);   // prefetch (in flight during compute)
    // X[t][i] = sum_j Atil[t][j] * S[i][j]
    {
      float alo = 0.f, ahi = 0.f;
#pragma unroll
      for (int q = 0; q < 8; ++q) {
        const f32x4 slo = *(const f32x4*)&S_l[i8][q * 4];
        const f32x4 shi = *(const f32x4*)&S_l[i8][q * 4 + 32];
        const bf16x4 alo4 = *(const bf16x4*)&A_l[t32][q * 4];
        const bf16x4 ahi4 = *(const bf16x4*)&A_l[t32][q * 4 + 32];
#pragma unroll
        for (int e = 0; e < 4; ++e) {
          alo += slo[e] * (float)alo4[e];
          ahi += shi[e] * (float)ahi4[e];
        }
      }
      X_l[t32][i8] = alo + ahi;
    }
    __syncthreads();
    // SA = P*X + PK*V
    {
      float alo = 0.f, ahi = 0.f;
#pragma unroll
      for (int u = 0; u < 16; ++u) {
        alo += P_l[t32][u] * X_l[u][i8] + PK_l[t32][u] * V_l[u][i8];
        ahi += P_l[t32][u + 16] * X_l[u + 16][i8] + PK_l[t32][u + 16] * V_l[u + 16][i8];
      }
      SA_l[t32][i8] = alo + ahi;
    }
    __syncthreads();
    // O = Gb*SA + Gk*V + Rtil*S^T
    {
      float alo = 0.f, ahi = 0.f;
#pragma unroll
      for (int u = 0; u < 16; ++u) {
        alo += Gb_l[t32][u] * SA_l[u][i8] + Gk_l[t32][u] * V_l[u][i8];
        ahi += Gb_l[t32][u + 16] * SA_l[u + 16][i8] + Gk_l[t32][u + 16] * V_l[u + 16][i8];
      }
#pragma unroll
      for (int q = 0; q < 8; ++q) {
        const f32x4 slo = *(const f32x4*)&S_l[i8][q * 4];
        const f32x4 shi = *(const f32x4*)&S_l[i8][q * 4 + 32];
        const bf16x4 rlo4 = *(const bf16x4*)&R_l[t32][q * 4];
        const bf16x4 rhi4 = *(const bf16x4*)&R_l[t32][q * 4 + 32];
#pragma unroll
        for (int e = 0; e < 4; ++e) {
          alo += slo[e] * (float)rlo4[e];
          ahi += shi[e] * (float)rhi4[e];
        }
      }
      xo[(size_t)(c * Cn + t32) * Dn + h * 64 + io + i8] = (__bf16)(alo + ahi);
    }
    __syncthreads();
    // S update: rows i4 and i4+4, col jl (each thread RMWs its own elements)
    {
      const float wc = WC_l[jl];
      float a0 = S_l[i4][jl] * wc;
      float a1 = S_l[i4 + 4][jl] * wc;
#pragma unroll
      for (int u = 0; u < 32; ++u) {
        const float bh = (float)Bh_l[u][jl], kh = (float)Kh_l[u][jl];
        a0 += SA_l[u][i4] * bh + V_l[u][i4] * kh;
        a1 += SA_l[u][i4 + 4] * bh + V_l[u][i4 + 4] * kh;
      }
      S_l[i4][jl] = a0;
      S_l[i4 + 4][jl] = a1;
    }
    __syncthreads();   // update done + all reads of chunk-c arrays done
    store_lds();       // write prefetched chunk c+1 into LDS
    __syncthreads();
  }
  for (int rep = 0; rep < 2; ++rep) {
    const int id = rep * 256 + tid;
    const int i = id >> 6, j = id & 63;
    st_out[(size_t)h * 4096 + (size_t)(io + i) * 64 + j] = S_l[i][j];
  }
}

// ---------------- post: per-head LN + bonus + gate -> bf16 ----------------

__global__ __launch_bounds__(256) void post_kernel(
    const __bf16* __restrict__ xo, const __bf16* __restrict__ v,
    const __bf16* __restrict__ g, const float* __restrict__ dot,
    const float* __restrict__ lnw, const float* __restrict__ lnb,
    __bf16* __restrict__ out) {
  const int t = blockIdx.x;
  const int lane = threadIdx.x & 63, wv = threadIdx.x >> 6;
#pragma unroll 1
  for (int c = 0; c < 8; ++c) {
    const int d = c * 256 + wv * 64 + lane;
    const size_t idx = (size_t)t * Dn + d;
    const float val = (float)xo[idx];
    const float mu = waveSum(val) * (1.f / 64.f);
    const float ctr = val - mu;
    const float var = waveSum(ctr * ctr) * (1.f / 64.f);
    float y = ctr * rsqrtf(var + 0.00064f);
    y = y * lnw[d] + lnb[d];
    const float res = (y + dot[t * Hn + (d >> 6)] * (float)v[idx]) * (float)g[idx];
    out[idx] = (__bf16)res;
  }
}

// ---------------- launcher ----------------

extern "C" void kernel_launch(void* const* d_in, const int* in_sizes, int n_in,
                              void* d_out, int out_size, void* d_ws, size_t ws_size,
                              hipStream_t stream) {
  (void)in_sizes; (void)n_in; (void)out_size; (void)ws_size;
  const float* x       = (const float*)d_in[0];
  const float* state1  = (const float*)d_in[1];
  const float* state2  = (const float*)d_in[2];
  const float* v_first = (const float*)d_in[3];
  const float* ln1_w   = (const float*)d_in[4];
  const float* ln1_b   = (const float*)d_in[5];
  const float* x_r     = (const float*)d_in[6];
  const float* x_w     = (const float*)d_in[7];
  const float* x_k     = (const float*)d_in[8];
  const float* x_v     = (const float*)d_in[9];
  const float* x_a     = (const float*)d_in[10];
  const float* x_g     = (const float*)d_in[11];
  const float* W_r     = (const float*)d_in[12];
  const float* W_k     = (const float*)d_in[13];
  const float* W_v     = (const float*)d_in[14];
  const float* W_o     = (const float*)d_in[15];
  const float* w1      = (const float*)d_in[16];
  const float* w2      = (const float*)d_in[17];
  const float* w0      = (const float*)d_in[18];
  const float* a1      = (const float*)d_in[19];
  const float* a2      = (const float*)d_in[20];
  const float* a0      = (const float*)d_in[21];
  const float* v1      = (const float*)d_in[22];
  const float* v2      = (const float*)d_in[23];
  const float* v0      = (const float*)d_in[24];
  const float* g1      = (const float*)d_in[25];
  const float* g2      = (const float*)d_in[26];
  const float* k_k     = (const float*)d_in[27];
  const float* k_a     = (const float*)d_in[28];
  const float* r_k     = (const float*)d_in[29];
  const float* lnx_w   = (const float*)d_in[30];
  const float* lnx_b   = (const float*)d_in[31];

  char* p = (char*)d_ws;
  const size_t MB = 1ull << 20;
  __bf16* xn    = (__bf16*)(p + 0 * MB);
  __bf16* Atil  = (__bf16*)(p + 0 * MB);
  __bf16* xr_b  = (__bf16*)(p + 8 * MB);
  __bf16* Wo_b  = (__bf16*)(p + 8 * MB);
  __bf16* xw_b  = (__bf16*)(p + 16 * MB);
  __bf16* wdec  = (__bf16*)(p + 16 * MB);
  __bf16* xo_b  = (__bf16*)(p + 16 * MB);
  __bf16* xk_b  = (__bf16*)(p + 24 * MB);
  __bf16* abuf  = (__bf16*)(p + 24 * MB);
  __bf16* Rtil  = (__bf16*)(p + 24 * MB);
  __bf16* xv_b  = (__bf16*)(p + 32 * MB);
  __bf16* vbl   = (__bf16*)(p + 32 * MB);
  __bf16* Bhat  = (__bf16*)(p + 32 * MB);
  __bf16* xa_b  = (__bf16*)(p + 40 * MB);
  __bf16* gbuf  = (__bf16*)(p + 40 * MB);
  __bf16* xg_b  = (__bf16*)(p + 48 * MB);
  __bf16* kkbuf = (__bf16*)(p + 48 * MB);
  __bf16* xobuf = (__bf16*)(p + 48 * MB);
  __bf16* Wr_b  = (__bf16*)(p + 56 * MB);
  __bf16* abbuf = (__bf16*)(p + 56 * MB);
  __bf16* Wk_b  = (__bf16*)(p + 64 * MB);
  __bf16* Khat  = (__bf16*)(p + 64 * MB);
  __bf16* Wv_b  = (__bf16*)(p + 72 * MB);
  __bf16* Pg    = (__bf16*)(p + 72 * MB);
  __bf16* PKg   = (__bf16*)(p + 76 * MB);
  __bf16* rbuf  = (__bf16*)(p + 80 * MB);
  __bf16* kbuf  = (__bf16*)(p + 88 * MB);
  __bf16* vbuf  = (__bf16*)(p + 96 * MB);
  __bf16* Gbg   = (__bf16*)(p + 104 * MB);
  __bf16* Gkg   = (__bf16*)(p + 108 * MB);
  char* q = p + 112 * MB;
  __bf16* yw  = (__bf16*)q; q += (size_t)Tn * 128 * 2;   // padded [T][128]
  __bf16* ya  = (__bf16*)q; q += (size_t)Tn * 128 * 2;
  __bf16* yv  = (__bf16*)q; q += (size_t)Tn * 128 * 2;
  __bf16* yg  = (__bf16*)q; q += (size_t)Tn * 128 * 2;
  __bf16* uwT = (__bf16*)q; q += (size_t)128 * Dn * 2;   // [128][D] padded
  __bf16* uaT = (__bf16*)q; q += (size_t)128 * Dn * 2;
  __bf16* uvT = (__bf16*)q; q += (size_t)128 * Dn * 2;
  __bf16* ugT = (__bf16*)q; q += (size_t)128 * Dn * 2;
  __bf16* w2T = (__bf16*)q; q += (size_t)Dn * 128 * 2;   // [D][128] padded
  __bf16* a2T = (__bf16*)q; q += (size_t)Dn * 128 * 2;
  __bf16* v2T = (__bf16*)q; q += (size_t)Dn * 128 * 2;
  __bf16* g2T = (__bf16*)q; q += (size_t)Dn * 128 * 2;
  float*  dot = (float*)q;  q += (size_t)Tn * Hn * 4;
  float*  WCg = (float*)q;  q += (size_t)NCH * Hn * 64 * 4;

  float* out     = (float*)d_out;
  float* out_xnl = out + (size_t)Tn * Dn;
  float* out_st  = out_xnl + Dn;

  castw3_kernel<<<dim3(4096, 3), 256, 0, stream>>>(W_r, W_k, W_v, Wr_b, Wk_b, Wv_b);
  castT_kernel<<<2048, 256, 0, stream>>>(w2, a2, v2, g2, w2T, a2T, v2T, g2T);
  castU_kernel<<<dim3(2048, 4), 256, 0, stream>>>(w1, a1, v1, g1, uwT, uaT, uvT, ugT);
  ln_kernel<<<2048, 256, 0, stream>>>(x, ln1_w, ln1_b, xn, out_xnl);
  mix_kernel<<<4096, 256, 0, stream>>>(xn, state1, x_r, x_w, x_k, x_v, x_a, x_g,
                                       xr_b, xw_b, xk_b, xv_b, xa_b, xg_b);
  gemm3_kernel<<<dim3(16, 16, 3), 256, 0, stream>>>(
      xr_b, xk_b, xv_b, Wr_b, Wk_b, Wv_b, rbuf, kbuf, vbuf);
  cast1_kernel<<<4096, 256, 0, stream>>>(W_o, Wo_b);
  gemm_l1_kernel<<<dim3(16, 1, 4), 256, 0, stream>>>(
      xw_b, xa_b, xv_b, xg_b, uwT, uaT, uvT, ugT, yw, ya, yv, yg);
  gemm_s2_kernel<<<dim3(16, 16, 4), 256, 0, stream>>>(
      yw, ya, yv, yg, w2T, a2T, v2T, g2T, w0, a0, v0, wdec, abuf, vbl, gbuf);
  prep_kernel<<<2048, 256, 0, stream>>>(rbuf, kbuf, vbuf, abuf, vbl, v_first,
                                        k_k, k_a, r_k, kkbuf, abbuf, dot);
  chunkA_kernel<<<dim3(NCH, Hn), 256, 0, stream>>>(
      wdec, kkbuf, abbuf, kbuf, rbuf,
      Atil, Rtil, Bhat, Khat, Pg, PKg, Gbg, Gkg, WCg);
  chunkB_kernel<<<256, 256, 0, stream>>>(
      Atil, Rtil, Bhat, Khat, Pg, PKg, Gbg, Gkg, WCg, vbuf,
      state2, xobuf, out_st);
  post_kernel<<<2048, 256, 0, stream>>>(xobuf, vbuf, gbuf, dot, lnx_w, lnx_b, xo_b);
  gemm_wo_kernel<<<dim3(16, 16), 256, 0, stream>>>(xo_b, Wo_b, x, out);
}

// Round 10
// 610.389 us; speedup vs baseline: 1.9984x; 1.0055x over previous
//
#include <hip/hip_runtime.h>

#define Tn 2048
#define Dn 2048
#define Hn 32
#define Cn 32
#define NCH (Tn / Cn)

typedef float f32x4 __attribute__((ext_vector_type(4)));
typedef __bf16 bf16x8 __attribute__((ext_vector_type(8)));
typedef __bf16 bf16x4 __attribute__((ext_vector_type(4)));

// ---- fast wave-64 sum: DPP row reductions (VALU) + readlane ----
template <int CTRL>
__device__ __forceinline__ float dpp_add(float x) {
  int xi = __builtin_bit_cast(int, x);
  int sh = __builtin_amdgcn_update_dpp(0, xi, CTRL, 0xf, 0xf, true);
  return x + __builtin_bit_cast(float, sh);
}
__device__ __forceinline__ float rdlane(float x, int l) {
  int xi = __builtin_bit_cast(int, x);
  return __builtin_bit_cast(float, __builtin_amdgcn_readlane(xi, l));
}
__device__ __forceinline__ float waveSum(float v) {
  v = dpp_add<0x111>(v);
  v = dpp_add<0x112>(v);
  v = dpp_add<0x114>(v);
  v = dpp_add<0x118>(v);
  return (rdlane(v, 15) + rdlane(v, 31)) + (rdlane(v, 47) + rdlane(v, 63));
}

__device__ __forceinline__ float sigm(float x) { return 1.f / (1.f + expf(-x)); }

__device__ __forceinline__ void gl_lds16(const void* g, void* l) {
  __builtin_amdgcn_global_load_lds(
      (__attribute__((address_space(1))) void*)(g),
      (__attribute__((address_space(3))) void*)(l), 16, 0, 0);
}

// barrier that drains only LDS (lgkmcnt), leaving global loads in flight
__device__ __forceinline__ void bar_lgkm() {
  asm volatile("s_waitcnt lgkmcnt(0)" ::: "memory");
  __builtin_amdgcn_s_barrier();
}

// ---------------- weight casts ----------------

__global__ __launch_bounds__(256) void castw3_kernel(
    const float* __restrict__ A, const float* __restrict__ B,
    const float* __restrict__ C, __bf16* __restrict__ o0,
    __bf16* __restrict__ o1, __bf16* __restrict__ o2) {
  const int z = blockIdx.y;
  const float* src = z == 0 ? A : (z == 1 ? B : C);
  __bf16* dst = z == 0 ? o0 : (z == 1 ? o1 : o2);
  const size_t i4 = (size_t)blockIdx.x * 256 + threadIdx.x;
  f32x4 v = *(const f32x4*)(src + i4 * 4);
  bf16x4 o;
  o[0] = (__bf16)v[0]; o[1] = (__bf16)v[1]; o[2] = (__bf16)v[2]; o[3] = (__bf16)v[3];
  ((bf16x4*)dst)[i4] = o;
}

__global__ __launch_bounds__(256) void cast1_kernel(
    const float* __restrict__ src, __bf16* __restrict__ dst) {
  const size_t i4 = (size_t)blockIdx.x * 256 + threadIdx.x;
  f32x4 v = *(const f32x4*)(src + i4 * 4);
  bf16x4 o;
  o[0] = (__bf16)v[0]; o[1] = (__bf16)v[1]; o[2] = (__bf16)v[2]; o[3] = (__bf16)v[3];
  ((bf16x4*)dst)[i4] = o;
}

// stage-2 weights: transpose-cast to [D][128] bf16, zero-padded beyond R
__global__ __launch_bounds__(256) void castT_kernel(
    const float* __restrict__ w2, const float* __restrict__ a2,
    const float* __restrict__ v2, const float* __restrict__ g2,
    __bf16* __restrict__ w2T, __bf16* __restrict__ a2T,
    __bf16* __restrict__ v2T, __bf16* __restrict__ g2T) {
  const int i = blockIdx.x;   // D index
  const int k = threadIdx.x;
  if (k < 128) {
    w2T[(size_t)i * 128 + k] = (k < 64) ? (__bf16)w2[(size_t)k * Dn + i] : (__bf16)0.f;
    a2T[(size_t)i * 128 + k] = (k < 64) ? (__bf16)a2[(size_t)k * Dn + i] : (__bf16)0.f;
    v2T[(size_t)i * 128 + k] = (k < 32) ? (__bf16)v2[(size_t)k * Dn + i] : (__bf16)0.f;
    g2T[(size_t)i * 128 + k] = (__bf16)g2[(size_t)k * Dn + i];
  }
}

// stage-1 (LoRA down) weights: [D][R] f32 -> [128][D] bf16, zero-padded rows
__global__ __launch_bounds__(256) void castU_kernel(
    const float* __restrict__ w1, const float* __restrict__ a1,
    const float* __restrict__ v1, const float* __restrict__ g1,
    __bf16* __restrict__ uwT, __bf16* __restrict__ uaT,
    __bf16* __restrict__ uvT, __bf16* __restrict__ ugT) {
  const int z = blockIdx.y;
  const float* src = z == 0 ? w1 : (z == 1 ? a1 : (z == 2 ? v1 : g1));
  __bf16* dst = z == 0 ? uwT : (z == 1 ? uaT : (z == 2 ? uvT : ugT));
  const int R = z == 0 ? 64 : (z == 1 ? 64 : (z == 2 ? 32 : 128));
  const int d = blockIdx.x;
  const int k = threadIdx.x;
  if (k < 128)
    dst[(size_t)k * Dn + d] = (k < R) ? (__bf16)src[(size_t)d * R + k] : (__bf16)0.f;
}

// ---------------- layernorm (ln1) ----------------

__global__ __launch_bounds__(256) void ln_kernel(
    const float* __restrict__ x, const float* __restrict__ lw,
    const float* __restrict__ lb, __bf16* __restrict__ xn,
    float* __restrict__ xn_last) {
  __shared__ float red[8];
  const int t = blockIdx.x, tid = threadIdx.x;
  const int lane = tid & 63, wv = tid >> 6;
  const float* xr = x + (size_t)t * Dn;
  float v[8];
  float s = 0.f;
#pragma unroll
  for (int c = 0; c < 8; ++c) { v[c] = xr[tid + c * 256]; s += v[c]; }
  s = waveSum(s);
  if (lane == 0) red[wv] = s;
  __syncthreads();
  const float mu = (red[0] + red[1] + red[2] + red[3]) * (1.f / (float)Dn);
  float q = 0.f;
#pragma unroll
  for (int c = 0; c < 8; ++c) { float d0 = v[c] - mu; q += d0 * d0; }
  q = waveSum(q);
  if (lane == 0) red[4 + wv] = q;
  __syncthreads();
  const float var = (red[4] + red[5] + red[6] + red[7]) * (1.f / (float)Dn);
  const float rstd = rsqrtf(var + 1e-5f);
#pragma unroll
  for (int c = 0; c < 8; ++c) {
    const int d = tid + c * 256;
    const float y = (v[c] - mu) * rstd * lw[d] + lb[d];
    xn[(size_t)t * Dn + d] = (__bf16)y;
    if (t == Tn - 1) xn_last[d] = y;
  }
}

// ---------------- token-shift mix ----------------

__global__ __launch_bounds__(256) void mix_kernel(
    const __bf16* __restrict__ xn, const float* __restrict__ state1,
    const float* __restrict__ cr, const float* __restrict__ cw,
    const float* __restrict__ ck, const float* __restrict__ cv,
    const float* __restrict__ ca, const float* __restrict__ cg,
    __bf16* __restrict__ br, __bf16* __restrict__ bw, __bf16* __restrict__ bk,
    __bf16* __restrict__ bv, __bf16* __restrict__ ba, __bf16* __restrict__ bg) {
  const size_t i4 = (size_t)blockIdx.x * 256 + threadIdx.x;
  const int t = (int)(i4 >> 9);
  const int d = (int)(i4 & 511) * 4;
  const bf16x4 cb = ((const bf16x4*)xn)[i4];
  f32x4 cur;
#pragma unroll
  for (int e = 0; e < 4; ++e) cur[e] = (float)cb[e];
  f32x4 prv;
  if (t == 0) {
    prv = *(const f32x4*)(state1 + d);
  } else {
    const bf16x4 pb = ((const bf16x4*)xn)[i4 - 512];
#pragma unroll
    for (int e = 0; e < 4; ++e) prv[e] = (float)pb[e];
  }
  const f32x4 sx = prv - cur;
  auto mix1 = [&](const float* c, __bf16* o) {
    const f32x4 cc = *(const f32x4*)(c + d);
    bf16x4 ob;
#pragma unroll
    for (int e = 0; e < 4; ++e) ob[e] = (__bf16)(cur[e] + sx[e] * cc[e]);
    ((bf16x4*)o)[i4] = ob;
  };
  mix1(cr, br); mix1(cw, bw); mix1(ck, bk);
  mix1(cv, bv); mix1(ca, ba); mix1(cg, bg);
}

// ---------------- MFMA GEMM tile core ----------------

__device__ __forceinline__ void gemm_tile(const __bf16* __restrict__ A,
                                          const __bf16* __restrict__ B,
                                          int K, int row0, int col0,
                                          f32x4 (&acc)[4][4]) {
  __shared__ __attribute__((aligned(16))) __bf16 As[4096];
  __shared__ __attribute__((aligned(16))) __bf16 Bs[4096];
  const int tid = threadIdx.x;
  const int lane = tid & 63, wid = tid >> 6;
  const int wm = (wid >> 1) * 64, wn = (wid & 1) * 64;
  const int lr = lane & 15, lk = (lane >> 4) * 8;
  for (int kt = 0; kt < K; kt += 32) {
#pragma unroll
    for (int it = 0; it < 2; ++it) {
      const int L = it * 256 + tid;
      const int rr = L >> 2, kc = (L & 3) * 8;
      const int lb = (it * 256 + wid * 64) * 8;
      gl_lds16(A + (size_t)(row0 + rr) * K + (kt + kc), &As[lb]);
      gl_lds16(B + (size_t)(col0 + rr) * K + (kt + kc), &Bs[lb]);
    }
    __syncthreads();
    bf16x8 af[4], bfv[4];
#pragma unroll
    for (int mf = 0; mf < 4; ++mf)
      af[mf] = *(const bf16x8*)&As[(wm + mf * 16 + lr) * 32 + lk];
#pragma unroll
    for (int nf = 0; nf < 4; ++nf)
      bfv[nf] = *(const bf16x8*)&Bs[(wn + nf * 16 + lr) * 32 + lk];
#pragma unroll
    for (int mf = 0; mf < 4; ++mf)
#pragma unroll
      for (int nf = 0; nf < 4; ++nf)
        acc[mf][nf] = __builtin_amdgcn_mfma_f32_16x16x32_bf16(
            af[mf], bfv[nf], acc[mf][nf], 0, 0, 0);
    __syncthreads();
  }
}

__global__ __launch_bounds__(256) void gemm3_kernel(
    const __bf16* __restrict__ A0, const __bf16* __restrict__ A1,
    const __bf16* __restrict__ A2, const __bf16* __restrict__ B0,
    const __bf16* __restrict__ B1, const __bf16* __restrict__ B2,
    __bf16* __restrict__ C0, __bf16* __restrict__ C1, __bf16* __restrict__ C2) {
  const int z = blockIdx.z;
  const __bf16* A = z == 0 ? A0 : (z == 1 ? A1 : A2);
  const __bf16* B = z == 0 ? B0 : (z == 1 ? B1 : B2);
  __bf16* C = z == 0 ? C0 : (z == 1 ? C1 : C2);
  const int row0 = blockIdx.x * 128, col0 = blockIdx.y * 128;
  f32x4 acc[4][4] = {};
  gemm_tile(A, B, Dn, row0, col0, acc);
  const int lane = threadIdx.x & 63, wid = threadIdx.x >> 6;
  const int wm = (wid >> 1) * 64, wn = (wid & 1) * 64;
#pragma unroll
  for (int mf = 0; mf < 4; ++mf) {
    const int r0 = row0 + wm + mf * 16 + ((lane >> 4) << 2);
#pragma unroll
    for (int nf = 0; nf < 4; ++nf) {
      const int c0 = col0 + wn + nf * 16 + (lane & 15);
#pragma unroll
      for (int rg = 0; rg < 4; ++rg)
        C[(size_t)(r0 + rg) * Dn + c0] = (__bf16)acc[mf][nf][rg];
    }
  }
}

// LoRA stage-1 as MFMA GEMM: Y[T][128] = X[T][D] @ U^T, epilogue per path
__global__ __launch_bounds__(256) void gemm_l1_kernel(
    const __bf16* __restrict__ Aw, const __bf16* __restrict__ Aa,
    const __bf16* __restrict__ Av, const __bf16* __restrict__ Ag,
    const __bf16* __restrict__ Bw, const __bf16* __restrict__ Ba,
    const __bf16* __restrict__ Bv, const __bf16* __restrict__ Bg,
    __bf16* __restrict__ Cw, __bf16* __restrict__ Ca,
    __bf16* __restrict__ Cv, __bf16* __restrict__ Cg) {
  const int z = blockIdx.z;
  const __bf16* A = z == 0 ? Aw : (z == 1 ? Aa : (z == 2 ? Av : Ag));
  const __bf16* B = z == 0 ? Bw : (z == 1 ? Ba : (z == 2 ? Bv : Bg));
  __bf16* C = z == 0 ? Cw : (z == 1 ? Ca : (z == 2 ? Cv : Cg));
  const int row0 = blockIdx.x * 128;
  f32x4 acc[4][4] = {};
  gemm_tile(A, B, Dn, row0, 0, acc);
  const int lane = threadIdx.x & 63, wid = threadIdx.x >> 6;
  const int wm = (wid >> 1) * 64, wn = (wid & 1) * 64;
#pragma unroll
  for (int mf = 0; mf < 4; ++mf) {
    const int r0 = row0 + wm + mf * 16 + ((lane >> 4) << 2);
#pragma unroll
    for (int nf = 0; nf < 4; ++nf) {
      const int c0 = wn + nf * 16 + (lane & 15);
#pragma unroll
      for (int rg = 0; rg < 4; ++rg) {
        float val = acc[mf][nf][rg];
        if (z == 0)      val = tanhf(val);
        else if (z == 3) val = sigm(val);
        C[(size_t)(r0 + rg) * 128 + c0] = (__bf16)val;
      }
    }
  }
}

// LoRA stage-2 fused, uniform K=128 (zero-padded), bf16 outputs
__global__ __launch_bounds__(256) void gemm_s2_kernel(
    const __bf16* __restrict__ Aw, const __bf16* __restrict__ Aa,
    const __bf16* __restrict__ Av, const __bf16* __restrict__ Ag,
    const __bf16* __restrict__ Bw, const __bf16* __restrict__ Ba,
    const __bf16* __restrict__ Bv, const __bf16* __restrict__ Bg,
    const float* __restrict__ w0, const float* __restrict__ a0,
    const float* __restrict__ v0, __bf16* __restrict__ Cw,
    __bf16* __restrict__ Ca, __bf16* __restrict__ Cv, __bf16* __restrict__ Cg) {
  const int z = blockIdx.z;
  const __bf16* A = z == 0 ? Aw : (z == 1 ? Aa : (z == 2 ? Av : Ag));
  const __bf16* B = z == 0 ? Bw : (z == 1 ? Ba : (z == 2 ? Bv : Bg));
  const float* bias = z == 0 ? w0 : (z == 1 ? a0 : (z == 2 ? v0 : (const float*)0));
  __bf16* C = z == 0 ? Cw : (z == 1 ? Ca : (z == 2 ? Cv : Cg));
  const int row0 = blockIdx.x * 128, col0 = blockIdx.y * 128;
  f32x4 acc[4][4] = {};
  gemm_tile(A, B, 128, row0, col0, acc);
  const int lane = threadIdx.x & 63, wid = threadIdx.x >> 6;
  const int wm = (wid >> 1) * 64, wn = (wid & 1) * 64;
#pragma unroll
  for (int mf = 0; mf < 4; ++mf) {
    const int r0 = row0 + wm + mf * 16 + ((lane >> 4) << 2);
#pragma unroll
    for (int nf = 0; nf < 4; ++nf) {
      const int c0 = col0 + wn + nf * 16 + (lane & 15);
#pragma unroll
      for (int rg = 0; rg < 4; ++rg) {
        float val = acc[mf][nf][rg];
        if (z == 0)      val = expf(-0.606531f * sigm(val + bias[c0]));
        else if (z < 3)  val = sigm(val + bias[c0]);
        C[(size_t)(r0 + rg) * Dn + c0] = (__bf16)val;
      }
    }
  }
}

__global__ __launch_bounds__(256) void gemm_wo_kernel(
    const __bf16* __restrict__ A, const __bf16* __restrict__ B,
    const float* __restrict__ xres, float* __restrict__ C) {
  const int row0 = blockIdx.x * 128, col0 = blockIdx.y * 128;
  f32x4 acc[4][4] = {};
  gemm_tile(A, B, Dn, row0, col0, acc);
  const int lane = threadIdx.x & 63, wid = threadIdx.x >> 6;
  const int wm = (wid >> 1) * 64, wn = (wid & 1) * 64;
#pragma unroll
  for (int mf = 0; mf < 4; ++mf) {
    const int r0 = row0 + wm + mf * 16 + ((lane >> 4) << 2);
#pragma unroll
    for (int nf = 0; nf < 4; ++nf) {
      const int c0 = col0 + wn + nf * 16 + (lane & 15);
#pragma unroll
      for (int rg = 0; rg < 4; ++rg)
        C[(size_t)(r0 + rg) * Dn + c0] =
            acc[mf][nf][rg] + xres[(size_t)(r0 + rg) * Dn + c0];
    }
  }
}

// ---------------- prep: v-blend, kk-norm, k-mod, ab, bonus dot ----------------

__global__ __launch_bounds__(256) void prep_kernel(
    const __bf16* __restrict__ r, __bf16* __restrict__ k, __bf16* __restrict__ v,
    const __bf16* __restrict__ a, const __bf16* __restrict__ vb,
    const float* __restrict__ v_first, const float* __restrict__ k_k,
    const float* __restrict__ k_a, const float* __restrict__ r_k,
    __bf16* __restrict__ kk_out, __bf16* __restrict__ ab_out,
    float* __restrict__ dot_out) {
  const int t = blockIdx.x;
  const int lane = threadIdx.x & 63, wv = threadIdx.x >> 6;
#pragma unroll 1
  for (int c = 0; c < 8; ++c) {
    const int d = c * 256 + wv * 64 + lane;
    const size_t idx = (size_t)t * Dn + d;
    const float kvv = (float)k[idx];
    const float kh = kvv * k_k[d];
    const float nrm = sqrtf(waveSum(kh * kh)) + 1e-6f;
    const float kkv = kh / nrm;
    const float av = (float)a[idx];
    float vv = (float)v[idx];
    vv = vv + (v_first[idx] - vv) * (float)vb[idx];
    const float kfv = kvv * (1.f + (av - 1.f) * k_a[d]);
    const float dt = waveSum((float)r[idx] * kfv * r_k[d]);
    kk_out[idx] = (__bf16)kkv;
    ab_out[idx] = (__bf16)(kkv * av);
    k[idx] = (__bf16)kfv;
    v[idx] = (__bf16)vv;
    if (lane == 0) dot_out[t * Hn + (d >> 6)] = dt;
  }
}

// ---------------- chunkA: per-chunk decay mats + triangular inverse ----------------

__global__ __launch_bounds__(256) void chunkA_kernel(
    const __bf16* __restrict__ wd, const __bf16* __restrict__ kk,
    const __bf16* __restrict__ ab, const __bf16* __restrict__ kf,
    const __bf16* __restrict__ r,
    __bf16* __restrict__ Atil, __bf16* __restrict__ Rtil,
    __bf16* __restrict__ Bhat, __bf16* __restrict__ Khat,
    __bf16* __restrict__ Pg, __bf16* __restrict__ PKg,
    __bf16* __restrict__ Gbg, __bf16* __restrict__ Gkg,
    float* __restrict__ WCg) {
  const int c = blockIdx.x, h = blockIdx.y;
  const int tid = threadIdx.x;
  __shared__ __bf16 A_l[32][72];
  __shared__ __bf16 B_l[32][72], K_l[32][72], R_l[32][72];
  __shared__ float W_l[33][64];
  __shared__ float Mba[32][36], Mka[32][36];
  __shared__ float P0[32][36], P1[32][36], T0[32][36], T1[32][36];

  const size_t rowbase = (size_t)(c * Cn) * Dn + (size_t)h * 64;
  const int tt = tid >> 3, j0 = (tid & 7) * 8;
  const size_t g = rowbase + (size_t)tt * Dn + j0;
  *(bf16x8*)&A_l[tt][j0] = *(const bf16x8*)(wd + g);
  __syncthreads();
  if (tid < 64) {
    const int j = tid;
    float cur = 1.f;
    W_l[0][j] = 1.f;
    for (int t = 0; t < Cn; ++t) {
      cur *= (float)A_l[t][j];
      W_l[t + 1][j] = cur;
    }
    WCg[((size_t)c * Hn + h) * 64 + j] = cur;
  }
  __syncthreads();
  {
    bf16x8 kkv = *(const bf16x8*)(kk + g);
    bf16x8 abv = *(const bf16x8*)(ab + g);
    bf16x8 kv  = *(const bf16x8*)(kf + g);
    bf16x8 rv  = *(const bf16x8*)(r + g);
    bf16x8 oa, ob, ok, orr, obh, okh;
#pragma unroll
    for (int e = 0; e < 8; ++e) {
      const int j = j0 + e;
      const float Wexc = W_l[tt][j], Winc = W_l[tt + 1][j], WC = W_l[32][j];
      const float inv = 1.f / Winc;
      const float at = -(float)kkv[e] * Wexc;
      const float bt = (float)abv[e] * inv;
      const float kt = (float)kv[e] * inv;
      const float rt = (float)rv[e] * Winc;
      oa[e] = (__bf16)at; ob[e] = (__bf16)bt; ok[e] = (__bf16)kt;
      orr[e] = (__bf16)rt;
      obh[e] = (__bf16)(bt * WC); okh[e] = (__bf16)(kt * WC);
    }
    *(bf16x8*)&A_l[tt][j0] = oa;
    *(bf16x8*)&B_l[tt][j0] = ob;
    *(bf16x8*)&K_l[tt][j0] = ok;
    *(bf16x8*)&R_l[tt][j0] = orr;
    *(bf16x8*)(Atil + g) = oa;
    *(bf16x8*)(Rtil + g) = orr;
    *(bf16x8*)(Bhat + g) = obh;
    *(bf16x8*)(Khat + g) = okh;
  }
  __syncthreads();
  const size_t matbase = ((size_t)c * Hn + h) * (Cn * Cn);
#pragma unroll 1
  for (int rep = 0; rep < 4; ++rep) {
    const int id = rep * 256 + tid;
    const int t = id >> 5, ta = id & 31;
    float d_ab = 0.f, d_ak = 0.f, d_rb = 0.f, d_rk = 0.f;
    for (int j8 = 0; j8 < 8; ++j8) {
      const bf16x8 av = *(const bf16x8*)&A_l[t][j8 * 8];
      const bf16x8 rv = *(const bf16x8*)&R_l[t][j8 * 8];
      const bf16x8 bv = *(const bf16x8*)&B_l[ta][j8 * 8];
      const bf16x8 kv = *(const bf16x8*)&K_l[ta][j8 * 8];
#pragma unroll
      for (int e = 0; e < 8; ++e) {
        const float af = (float)av[e], rf = (float)rv[e];
        const float bf2 = (float)bv[e], kf2 = (float)kv[e];
        d_ab += af * bf2; d_ak += af * kf2;
        d_rb += rf * bf2; d_rk += rf * kf2;
      }
    }
    Mba[t][ta] = (ta < t) ? d_ab : 0.f;
    Mka[t][ta] = (ta < t) ? d_ak : 0.f;
    Gbg[matbase + id] = (__bf16)((ta <= t) ? d_rb : 0.f);
    Gkg[matbase + id] = (__bf16)((ta <= t) ? d_rk : 0.f);
  }
  __syncthreads();
  for (int rep = 0; rep < 4; ++rep) {
    const int id = rep * 256 + tid;
    const int t = id >> 5, ta = id & 31;
    P0[t][ta] = Mba[t][ta] + (t == ta ? 1.f : 0.f);
  }
  __syncthreads();
  auto mm = [&](float (*D)[36], float (*Aa)[36], float (*Bb)[36]) {
    for (int rep = 0; rep < 4; ++rep) {
      const int id = rep * 256 + tid;
      const int t = id >> 5, ta = id & 31;
      float s = 0.f;
      for (int u = 0; u < 32; ++u) s += Aa[t][u] * Bb[u][ta];
      D[t][ta] = s;
    }
    __syncthreads();
  };
  auto mmadd = [&](float (*D)[36], float (*Pp)[36], float (*Tt)[36]) {
    for (int rep = 0; rep < 4; ++rep) {
      const int id = rep * 256 + tid;
      const int t = id >> 5, ta = id & 31;
      float s = Pp[t][ta];
      for (int u = 0; u < 32; ++u) s += Pp[t][u] * Tt[u][ta];
      D[t][ta] = s;
    }
    __syncthreads();
  };
  mm(T0, Mba, Mba);
  mmadd(P1, P0, T0);
  mm(T1, T0, T0);
  mmadd(P0, P1, T1);
  mm(T0, T1, T1);
  mmadd(P1, P0, T0);
  mm(T1, T0, T0);
  mmadd(P0, P1, T1);
  for (int rep = 0; rep < 4; ++rep) {
    const int id = rep * 256 + tid;
    const int t = id >> 5, ta = id & 31;
    Pg[matbase + id] = (__bf16)P0[t][ta];
    float s = 0.f;
    for (int u = 0; u < 32; ++u) s += P0[t][u] * Mka[u][ta];
    PKg[matbase + id] = (__bf16)s;
  }
}

// ---------------- chunkB: sequential over chunks, 256 blocks (h x 8 i-cols) ----------------
// lgkm-only barriers keep the next-chunk register prefetch in flight across
// the whole chunk; XCD-aware swizzle puts all 8 i-cols of a head on one XCD.

__global__ __launch_bounds__(256) void chunkB_kernel(
    const __bf16* __restrict__ Atil, const __bf16* __restrict__ Rtil,
    const __bf16* __restrict__ Bhat, const __bf16* __restrict__ Khat,
    const __bf16* __restrict__ Pg, const __bf16* __restrict__ PKg,
    const __bf16* __restrict__ Gbg, const __bf16* __restrict__ Gkg,
    const float* __restrict__ WCg, const __bf16* __restrict__ vbuf,
    const float* __restrict__ st_in, __bf16* __restrict__ xo,
    float* __restrict__ st_out) {
  // swizzle: xcd = b&7 hosts heads [4*xcd, 4*xcd+4)
  const int b = blockIdx.x;
  const int xcd = b & 7, rest = b >> 3;
  const int h = xcd * 4 + (rest & 3);
  const int io = (rest >> 2) * 8;
  const int tid = threadIdx.x;
  __shared__ __attribute__((aligned(16))) float S_l[8][68];
  __shared__ __attribute__((aligned(16))) float P_l[32][36], PK_l[32][36];
  __shared__ __attribute__((aligned(16))) float Gb_l[32][36], Gk_l[32][36];
  __shared__ __attribute__((aligned(16))) __bf16 A_l[32][72], R_l[32][72];
  __shared__ __attribute__((aligned(16))) __bf16 Bh_l[32][72], Kh_l[32][72];
  __shared__ __attribute__((aligned(16))) float X_l[32][12], SA_l[32][12], V_l[32][12];
  __shared__ float WC_l[64];

  // initial S rows [io..io+8)
  for (int rep = 0; rep < 2; ++rep) {
    const int id = rep * 256 + tid;
    const int i = id >> 6, j = id & 63;
    S_l[i][j] = st_in[(size_t)h * 4096 + (size_t)(io + i) * 64 + j];
  }
  const int t32 = tid >> 3, i8 = tid & 7;     // compute + row-load mapping
  const int j0 = i8 * 8;                       // row-load col base
  const int jl = tid & 63, i4 = tid >> 6;      // S-update mapping

  bf16x8 rA, rR, rB, rK;
  bf16x4 rP, rPK, rGb, rGk;
  __bf16 rV;
  float rWC = 0.f;

  auto load_regs = [&](int c) {
    const size_t rowbase = (size_t)(c * Cn) * Dn + (size_t)h * 64;
    const size_t g = rowbase + (size_t)t32 * Dn + j0;
    rA = *(const bf16x8*)(Atil + g);
    rR = *(const bf16x8*)(Rtil + g);
    rB = *(const bf16x8*)(Bhat + g);
    rK = *(const bf16x8*)(Khat + g);
    const size_t matbase = ((size_t)c * Hn + h) * (Cn * Cn) + (size_t)tid * 4;
    rP  = *(const bf16x4*)(Pg + matbase);
    rPK = *(const bf16x4*)(PKg + matbase);
    rGb = *(const bf16x4*)(Gbg + matbase);
    rGk = *(const bf16x4*)(Gkg + matbase);
    rV = vbuf[rowbase + (size_t)t32 * Dn + io + i8];
    if (tid < 64) rWC = WCg[((size_t)c * Hn + h) * 64 + tid];
  };
  auto store_lds = [&]() {
    *(bf16x8*)&A_l[t32][j0]  = rA;
    *(bf16x8*)&R_l[t32][j0]  = rR;
    *(bf16x8*)&Bh_l[t32][j0] = rB;
    *(bf16x8*)&Kh_l[t32][j0] = rK;
    const int mc = i8 * 4;
#pragma unroll
    for (int e = 0; e < 4; ++e) {
      P_l[t32][mc + e]  = (float)rP[e];
      PK_l[t32][mc + e] = (float)rPK[e];
      Gb_l[t32][mc + e] = (float)rGb[e];
      Gk_l[t32][mc + e] = (float)rGk[e];
    }
    V_l[t32][i8] = (float)rV;
    if (tid < 64) WC_l[tid] = rWC;
  };

  load_regs(0);
  store_lds();
  bar_lgkm();

#pragma unroll 1
  for (int c = 0; c < NCH; ++c) {
    load_regs(c + 1 < NCH ? c + 1 : c);   // prefetch; stays in flight (no vmcnt drain)
    // X[t][i] = sum_j Atil[t][j] * S[i][j]
    {
      float alo = 0.f, ahi = 0.f;
#pragma unroll
      for (int q = 0; q < 8; ++q) {
        const f32x4 slo = *(const f32x4*)&S_l[i8][q * 4];
        const f32x4 shi = *(const f32x4*)&S_l[i8][q * 4 + 32];
        const bf16x4 alo4 = *(const bf16x4*)&A_l[t32][q * 4];
        const bf16x4 ahi4 = *(const bf16x4*)&A_l[t32][q * 4 + 32];
#pragma unroll
        for (int e = 0; e < 4; ++e) {
          alo += slo[e] * (float)alo4[e];
          ahi += shi[e] * (float)ahi4[e];
        }
      }
      X_l[t32][i8] = alo + ahi;
    }
    bar_lgkm();
    // SA = P*X + PK*V
    {
      float alo = 0.f, ahi = 0.f;
#pragma unroll
      for (int u = 0; u < 16; ++u) {
        alo += P_l[t32][u] * X_l[u][i8] + PK_l[t32][u] * V_l[u][i8];
        ahi += P_l[t32][u + 16] * X_l[u + 16][i8] + PK_l[t32][u + 16] * V_l[u + 16][i8];
      }
      SA_l[t32][i8] = alo + ahi;
    }
    bar_lgkm();
    // O = Gb*SA + Gk*V + Rtil*S^T
    {
      float alo = 0.f, ahi = 0.f;
#pragma unroll
      for (int u = 0; u < 16; ++u) {
        alo += Gb_l[t32][u] * SA_l[u][i8] + Gk_l[t32][u] * V_l[u][i8];
        ahi += Gb_l[t32][u + 16] * SA_l[u + 16][i8] + Gk_l[t32][u + 16] * V_l[u + 16][i8];
      }
#pragma unroll
      for (int q = 0; q < 8; ++q) {
        const f32x4 slo = *(const f32x4*)&S_l[i8][q * 4];
        const f32x4 shi = *(const f32x4*)&S_l[i8][q * 4 + 32];
        const bf16x4 rlo4 = *(const bf16x4*)&R_l[t32][q * 4];
        const bf16x4 rhi4 = *(const bf16x4*)&R_l[t32][q * 4 + 32];
#pragma unroll
        for (int e = 0; e < 4; ++e) {
          alo += slo[e] * (float)rlo4[e];
          ahi += shi[e] * (float)rhi4[e];
        }
      }
      xo[(size_t)(c * Cn + t32) * Dn + h * 64 + io + i8] = (__bf16)(alo + ahi);
    }
    bar_lgkm();
    // S update: rows i4 and i4+4, col jl
    {
      const float wc = WC_l[jl];
      float a0 = S_l[i4][jl] * wc;
      float a1 = S_l[i4 + 4][jl] * wc;
#pragma unroll
      for (int u = 0; u < 32; ++u) {
        const float bh = (float)Bh_l[u][jl], kh = (float)Kh_l[u][jl];
        a0 += SA_l[u][i4] * bh + V_l[u][i4] * kh;
        a1 += SA_l[u][i4 + 4] * bh + V_l[u][i4 + 4] * kh;
      }
      S_l[i4][jl] = a0;
      S_l[i4 + 4][jl] = a1;
    }
    bar_lgkm();        // update done + all reads of chunk-c arrays done
    store_lds();       // consume prefetched regs (vmcnt wait lands here)
    bar_lgkm();
  }
  for (int rep = 0; rep < 2; ++rep) {
    const int id = rep * 256 + tid;
    const int i = id >> 6, j = id & 63;
    st_out[(size_t)h * 4096 + (size_t)(io + i) * 64 + j] = S_l[i][j];
  }
}

// ---------------- post: per-head LN + bonus + gate -> bf16 ----------------

__global__ __launch_bounds__(256) void post_kernel(
    const __bf16* __restrict__ xo, const __bf16* __restrict__ v,
    const __bf16* __restrict__ g, const float* __restrict__ dot,
    const float* __restrict__ lnw, const float* __restrict__ lnb,
    __bf16* __restrict__ out) {
  const int t = blockIdx.x;
  const int lane = threadIdx.x & 63, wv = threadIdx.x >> 6;
#pragma unroll 1
  for (int c = 0; c < 8; ++c) {
    const int d = c * 256 + wv * 64 + lane;
    const size_t idx = (size_t)t * Dn + d;
    const float val = (float)xo[idx];
    const float mu = waveSum(val) * (1.f / 64.f);
    const float ctr = val - mu;
    const float var = waveSum(ctr * ctr) * (1.f / 64.f);
    float y = ctr * rsqrtf(var + 0.00064f);
    y = y * lnw[d] + lnb[d];
    const float res = (y + dot[t * Hn + (d >> 6)] * (float)v[idx]) * (float)g[idx];
    out[idx] = (__bf16)res;
  }
}

// ---------------- launcher ----------------

extern "C" void kernel_launch(void* const* d_in, const int* in_sizes, int n_in,
                              void* d_out, int out_size, void* d_ws, size_t ws_size,
                              hipStream_t stream) {
  (void)in_sizes; (void)n_in; (void)out_size; (void)ws_size;
  const float* x       = (const float*)d_in[0];
  const float* state1  = (const float*)d_in[1];
  const float* state2  = (const float*)d_in[2];
  const float* v_first = (const float*)d_in[3];
  const float* ln1_w   = (const float*)d_in[4];
  const float* ln1_b   = (const float*)d_in[5];
  const float* x_r     = (const float*)d_in[6];
  const float* x_w     = (const float*)d_in[7];
  const float* x_k     = (const float*)d_in[8];
  const float* x_v     = (const float*)d_in[9];
  const float* x_a     = (const float*)d_in[10];
  const float* x_g     = (const float*)d_in[11];
  const float* W_r     = (const float*)d_in[12];
  const float* W_k     = (const float*)d_in[13];
  const float* W_v     = (const float*)d_in[14];
  const float* W_o     = (const float*)d_in[15];
  const float* w1      = (const float*)d_in[16];
  const float* w2      = (const float*)d_in[17];
  const float* w0      = (const float*)d_in[18];
  const float* a1      = (const float*)d_in[19];
  const float* a2      = (const float*)d_in[20];
  const float* a0      = (const float*)d_in[21];
  const float* v1      = (const float*)d_in[22];
  const float* v2      = (const float*)d_in[23];
  const float* v0      = (const float*)d_in[24];
  const float* g1      = (const float*)d_in[25];
  const float* g2      = (const float*)d_in[26];
  const float* k_k     = (const float*)d_in[27];
  const float* k_a     = (const float*)d_in[28];
  const float* r_k     = (const float*)d_in[29];
  const float* lnx_w   = (const float*)d_in[30];
  const float* lnx_b   = (const float*)d_in[31];

  char* p = (char*)d_ws;
  const size_t MB = 1ull << 20;
  __bf16* xn    = (__bf16*)(p + 0 * MB);
  __bf16* Atil  = (__bf16*)(p + 0 * MB);
  __bf16* xr_b  = (__bf16*)(p + 8 * MB);
  __bf16* Wo_b  = (__bf16*)(p + 8 * MB);
  __bf16* xw_b  = (__bf16*)(p + 16 * MB);
  __bf16* wdec  = (__bf16*)(p + 16 * MB);
  __bf16* xo_b  = (__bf16*)(p + 16 * MB);
  __bf16* xk_b  = (__bf16*)(p + 24 * MB);
  __bf16* abuf  = (__bf16*)(p + 24 * MB);
  __bf16* Rtil  = (__bf16*)(p + 24 * MB);
  __bf16* xv_b  = (__bf16*)(p + 32 * MB);
  __bf16* vbl   = (__bf16*)(p + 32 * MB);
  __bf16* Bhat  = (__bf16*)(p + 32 * MB);
  __bf16* xa_b  = (__bf16*)(p + 40 * MB);
  __bf16* gbuf  = (__bf16*)(p + 40 * MB);
  __bf16* xg_b  = (__bf16*)(p + 48 * MB);
  __bf16* kkbuf = (__bf16*)(p + 48 * MB);
  __bf16* xobuf = (__bf16*)(p + 48 * MB);
  __bf16* Wr_b  = (__bf16*)(p + 56 * MB);
  __bf16* abbuf = (__bf16*)(p + 56 * MB);
  __bf16* Wk_b  = (__bf16*)(p + 64 * MB);
  __bf16* Khat  = (__bf16*)(p + 64 * MB);
  __bf16* Wv_b  = (__bf16*)(p + 72 * MB);
  __bf16* Pg    = (__bf16*)(p + 72 * MB);
  __bf16* PKg   = (__bf16*)(p + 76 * MB);
  __bf16* rbuf  = (__bf16*)(p + 80 * MB);
  __bf16* kbuf  = (__bf16*)(p + 88 * MB);
  __bf16* vbuf  = (__bf16*)(p + 96 * MB);
  __bf16* Gbg   = (__bf16*)(p + 104 * MB);
  __bf16* Gkg   = (__bf16*)(p + 108 * MB);
  char* q = p + 112 * MB;
  __bf16* yw  = (__bf16*)q; q += (size_t)Tn * 128 * 2;   // padded [T][128]
  __bf16* ya  = (__bf16*)q; q += (size_t)Tn * 128 * 2;
  __bf16* yv  = (__bf16*)q; q += (size_t)Tn * 128 * 2;
  __bf16* yg  = (__bf16*)q; q += (size_t)Tn * 128 * 2;
  __bf16* uwT = (__bf16*)q; q += (size_t)128 * Dn * 2;   // [128][D] padded
  __bf16* uaT = (__bf16*)q; q += (size_t)128 * Dn * 2;
  __bf16* uvT = (__bf16*)q; q += (size_t)128 * Dn * 2;
  __bf16* ugT = (__bf16*)q; q += (size_t)128 * Dn * 2;
  __bf16* w2T = (__bf16*)q; q += (size_t)Dn * 128 * 2;   // [D][128] padded
  __bf16* a2T = (__bf16*)q; q += (size_t)Dn * 128 * 2;
  __bf16* v2T = (__bf16*)q; q += (size_t)Dn * 128 * 2;
  __bf16* g2T = (__bf16*)q; q += (size_t)Dn * 128 * 2;
  float*  dot = (float*)q;  q += (size_t)Tn * Hn * 4;
  float*  WCg = (float*)q;  q += (size_t)NCH * Hn * 64 * 4;

  float* out     = (float*)d_out;
  float* out_xnl = out + (size_t)Tn * Dn;
  float* out_st  = out_xnl + Dn;

  castw3_kernel<<<dim3(4096, 3), 256, 0, stream>>>(W_r, W_k, W_v, Wr_b, Wk_b, Wv_b);
  castT_kernel<<<2048, 256, 0, stream>>>(w2, a2, v2, g2, w2T, a2T, v2T, g2T);
  castU_kernel<<<dim3(2048, 4), 256, 0, stream>>>(w1, a1, v1, g1, uwT, uaT, uvT, ugT);
  ln_kernel<<<2048, 256, 0, stream>>>(x, ln1_w, ln1_b, xn, out_xnl);
  mix_kernel<<<4096, 256, 0, stream>>>(xn, state1, x_r, x_w, x_k, x_v, x_a, x_g,
                                       xr_b, xw_b, xk_b, xv_b, xa_b, xg_b);
  gemm3_kernel<<<dim3(16, 16, 3), 256, 0, stream>>>(
      xr_b, xk_b, xv_b, Wr_b, Wk_b, Wv_b, rbuf, kbuf, vbuf);
  cast1_kernel<<<4096, 256, 0, stream>>>(W_o, Wo_b);
  gemm_l1_kernel<<<dim3(16, 1, 4), 256, 0, stream>>>(
      xw_b, xa_b, xv_b, xg_b, uwT, uaT, uvT, ugT, yw, ya, yv, yg);
  gemm_s2_kernel<<<dim3(16, 16, 4), 256, 0, stream>>>(
      yw, ya, yv, yg, w2T, a2T, v2T, g2T, w0, a0, v0, wdec, abuf, vbl, gbuf);
  prep_kernel<<<2048, 256, 0, stream>>>(rbuf, kbuf, vbuf, abuf, vbl, v_first,
                                        k_k, k_a, r_k, kkbuf, abbuf, dot);
  chunkA_kernel<<<dim3(NCH, Hn), 256, 0, stream>>>(
      wdec, kkbuf, abbuf, kbuf, rbuf,
      Atil, Rtil, Bhat, Khat, Pg, PKg, Gbg, Gkg, WCg);
  chunkB_kernel<<<256, 256, 0, stream>>>(
      Atil, Rtil, Bhat, Khat, Pg, PKg, Gbg, Gkg, WCg, vbuf,
      state2, xobuf, out_st);
  post_kernel<<<2048, 256, 0, stream>>>(xobuf, vbuf, gbuf, dot, lnx_w, lnx_b, xo_b);
  gemm_wo_kernel<<<dim3(16, 16), 256, 0, stream>>>(xo_b, Wo_b, x, out);
}

// Round 11
// 428.150 us; speedup vs baseline: 2.8490x; 1.4256x over previous
//
#include <hip/hip_runtime.h>

#define Tn 2048
#define Dn 2048
#define Hn 32
#define Cn 32
#define NCH (Tn / Cn)

typedef float f32x4 __attribute__((ext_vector_type(4)));
typedef __bf16 bf16x8 __attribute__((ext_vector_type(8)));
typedef __bf16 bf16x4 __attribute__((ext_vector_type(4)));

// ---- fast wave-64 sum: DPP row reductions (VALU) + readlane ----
template <int CTRL>
__device__ __forceinline__ float dpp_add(float x) {
  int xi = __builtin_bit_cast(int, x);
  int sh = __builtin_amdgcn_update_dpp(0, xi, CTRL, 0xf, 0xf, true);
  return x + __builtin_bit_cast(float, sh);
}
__device__ __forceinline__ float rdlane(float x, int l) {
  int xi = __builtin_bit_cast(int, x);
  return __builtin_bit_cast(float, __builtin_amdgcn_readlane(xi, l));
}
__device__ __forceinline__ float waveSum(float v) {
  v = dpp_add<0x111>(v);
  v = dpp_add<0x112>(v);
  v = dpp_add<0x114>(v);
  v = dpp_add<0x118>(v);
  return (rdlane(v, 15) + rdlane(v, 31)) + (rdlane(v, 47) + rdlane(v, 63));
}

__device__ __forceinline__ float sigm(float x) { return 1.f / (1.f + expf(-x)); }

__device__ __forceinline__ void gl_lds16(const void* g, void* l) {
  __builtin_amdgcn_global_load_lds(
      (__attribute__((address_space(1))) void*)(g),
      (__attribute__((address_space(3))) void*)(l), 16, 0, 0);
}

// barrier that drains only LDS (lgkmcnt), leaving global loads in flight
__device__ __forceinline__ void bar_lgkm() {
  asm volatile("s_waitcnt lgkmcnt(0)" ::: "memory");
  __builtin_amdgcn_s_barrier();
}

__device__ __forceinline__ f32x4 mfma16(const __bf16* a, const __bf16* b, f32x4 acc) {
  return __builtin_amdgcn_mfma_f32_16x16x32_bf16(
      *(const bf16x8*)a, *(const bf16x8*)b, acc, 0, 0, 0);
}

// ---------------- weight casts ----------------

__global__ __launch_bounds__(256) void castw3_kernel(
    const float* __restrict__ A, const float* __restrict__ B,
    const float* __restrict__ C, __bf16* __restrict__ o0,
    __bf16* __restrict__ o1, __bf16* __restrict__ o2) {
  const int z = blockIdx.y;
  const float* src = z == 0 ? A : (z == 1 ? B : C);
  __bf16* dst = z == 0 ? o0 : (z == 1 ? o1 : o2);
  const size_t i4 = (size_t)blockIdx.x * 256 + threadIdx.x;
  f32x4 v = *(const f32x4*)(src + i4 * 4);
  bf16x4 o;
  o[0] = (__bf16)v[0]; o[1] = (__bf16)v[1]; o[2] = (__bf16)v[2]; o[3] = (__bf16)v[3];
  ((bf16x4*)dst)[i4] = o;
}

__global__ __launch_bounds__(256) void cast1_kernel(
    const float* __restrict__ src, __bf16* __restrict__ dst) {
  const size_t i4 = (size_t)blockIdx.x * 256 + threadIdx.x;
  f32x4 v = *(const f32x4*)(src + i4 * 4);
  bf16x4 o;
  o[0] = (__bf16)v[0]; o[1] = (__bf16)v[1]; o[2] = (__bf16)v[2]; o[3] = (__bf16)v[3];
  ((bf16x4*)dst)[i4] = o;
}

// stage-2 weights: transpose-cast to [D][128] bf16, zero-padded beyond R
__global__ __launch_bounds__(256) void castT_kernel(
    const float* __restrict__ w2, const float* __restrict__ a2,
    const float* __restrict__ v2, const float* __restrict__ g2,
    __bf16* __restrict__ w2T, __bf16* __restrict__ a2T,
    __bf16* __restrict__ v2T, __bf16* __restrict__ g2T) {
  const int i = blockIdx.x;   // D index
  const int k = threadIdx.x;
  if (k < 128) {
    w2T[(size_t)i * 128 + k] = (k < 64) ? (__bf16)w2[(size_t)k * Dn + i] : (__bf16)0.f;
    a2T[(size_t)i * 128 + k] = (k < 64) ? (__bf16)a2[(size_t)k * Dn + i] : (__bf16)0.f;
    v2T[(size_t)i * 128 + k] = (k < 32) ? (__bf16)v2[(size_t)k * Dn + i] : (__bf16)0.f;
    g2T[(size_t)i * 128 + k] = (__bf16)g2[(size_t)k * Dn + i];
  }
}

// stage-1 (LoRA down) weights: [D][R] f32 -> [128][D] bf16, zero-padded rows
__global__ __launch_bounds__(256) void castU_kernel(
    const float* __restrict__ w1, const float* __restrict__ a1,
    const float* __restrict__ v1, const float* __restrict__ g1,
    __bf16* __restrict__ uwT, __bf16* __restrict__ uaT,
    __bf16* __restrict__ uvT, __bf16* __restrict__ ugT) {
  const int z = blockIdx.y;
  const float* src = z == 0 ? w1 : (z == 1 ? a1 : (z == 2 ? v1 : g1));
  __bf16* dst = z == 0 ? uwT : (z == 1 ? uaT : (z == 2 ? uvT : ugT));
  const int R = z == 0 ? 64 : (z == 1 ? 64 : (z == 2 ? 32 : 128));
  const int d = blockIdx.x;
  const int k = threadIdx.x;
  if (k < 128)
    dst[(size_t)k * Dn + d] = (k < R) ? (__bf16)src[(size_t)d * R + k] : (__bf16)0.f;
}

// ---------------- layernorm (ln1) ----------------

__global__ __launch_bounds__(256) void ln_kernel(
    const float* __restrict__ x, const float* __restrict__ lw,
    const float* __restrict__ lb, __bf16* __restrict__ xn,
    float* __restrict__ xn_last) {
  __shared__ float red[8];
  const int t = blockIdx.x, tid = threadIdx.x;
  const int lane = tid & 63, wv = tid >> 6;
  const float* xr = x + (size_t)t * Dn;
  float v[8];
  float s = 0.f;
#pragma unroll
  for (int c = 0; c < 8; ++c) { v[c] = xr[tid + c * 256]; s += v[c]; }
  s = waveSum(s);
  if (lane == 0) red[wv] = s;
  __syncthreads();
  const float mu = (red[0] + red[1] + red[2] + red[3]) * (1.f / (float)Dn);
  float q = 0.f;
#pragma unroll
  for (int c = 0; c < 8; ++c) { float d0 = v[c] - mu; q += d0 * d0; }
  q = waveSum(q);
  if (lane == 0) red[4 + wv] = q;
  __syncthreads();
  const float var = (red[4] + red[5] + red[6] + red[7]) * (1.f / (float)Dn);
  const float rstd = rsqrtf(var + 1e-5f);
#pragma unroll
  for (int c = 0; c < 8; ++c) {
    const int d = tid + c * 256;
    const float y = (v[c] - mu) * rstd * lw[d] + lb[d];
    xn[(size_t)t * Dn + d] = (__bf16)y;
    if (t == Tn - 1) xn_last[d] = y;
  }
}

// ---------------- token-shift mix ----------------

__global__ __launch_bounds__(256) void mix_kernel(
    const __bf16* __restrict__ xn, const float* __restrict__ state1,
    const float* __restrict__ cr, const float* __restrict__ cw,
    const float* __restrict__ ck, const float* __restrict__ cv,
    const float* __restrict__ ca, const float* __restrict__ cg,
    __bf16* __restrict__ br, __bf16* __restrict__ bw, __bf16* __restrict__ bk,
    __bf16* __restrict__ bv, __bf16* __restrict__ ba, __bf16* __restrict__ bg) {
  const size_t i4 = (size_t)blockIdx.x * 256 + threadIdx.x;
  const int t = (int)(i4 >> 9);
  const int d = (int)(i4 & 511) * 4;
  const bf16x4 cb = ((const bf16x4*)xn)[i4];
  f32x4 cur;
#pragma unroll
  for (int e = 0; e < 4; ++e) cur[e] = (float)cb[e];
  f32x4 prv;
  if (t == 0) {
    prv = *(const f32x4*)(state1 + d);
  } else {
    const bf16x4 pb = ((const bf16x4*)xn)[i4 - 512];
#pragma unroll
    for (int e = 0; e < 4; ++e) prv[e] = (float)pb[e];
  }
  const f32x4 sx = prv - cur;
  auto mix1 = [&](const float* c, __bf16* o) {
    const f32x4 cc = *(const f32x4*)(c + d);
    bf16x4 ob;
#pragma unroll
    for (int e = 0; e < 4; ++e) ob[e] = (__bf16)(cur[e] + sx[e] * cc[e]);
    ((bf16x4*)o)[i4] = ob;
  };
  mix1(cr, br); mix1(cw, bw); mix1(ck, bk);
  mix1(cv, bv); mix1(ca, ba); mix1(cg, bg);
}

// ---------------- MFMA GEMM tile core ----------------

__device__ __forceinline__ void gemm_tile(const __bf16* __restrict__ A,
                                          const __bf16* __restrict__ B,
                                          int K, int row0, int col0,
                                          f32x4 (&acc)[4][4]) {
  __shared__ __attribute__((aligned(16))) __bf16 As[4096];
  __shared__ __attribute__((aligned(16))) __bf16 Bs[4096];
  const int tid = threadIdx.x;
  const int lane = tid & 63, wid = tid >> 6;
  const int wm = (wid >> 1) * 64, wn = (wid & 1) * 64;
  const int lr = lane & 15, lk = (lane >> 4) * 8;
  for (int kt = 0; kt < K; kt += 32) {
#pragma unroll
    for (int it = 0; it < 2; ++it) {
      const int L = it * 256 + tid;
      const int rr = L >> 2, kc = (L & 3) * 8;
      const int lb = (it * 256 + wid * 64) * 8;
      gl_lds16(A + (size_t)(row0 + rr) * K + (kt + kc), &As[lb]);
      gl_lds16(B + (size_t)(col0 + rr) * K + (kt + kc), &Bs[lb]);
    }
    __syncthreads();
    bf16x8 af[4], bfv[4];
#pragma unroll
    for (int mf = 0; mf < 4; ++mf)
      af[mf] = *(const bf16x8*)&As[(wm + mf * 16 + lr) * 32 + lk];
#pragma unroll
    for (int nf = 0; nf < 4; ++nf)
      bfv[nf] = *(const bf16x8*)&Bs[(wn + nf * 16 + lr) * 32 + lk];
#pragma unroll
    for (int mf = 0; mf < 4; ++mf)
#pragma unroll
      for (int nf = 0; nf < 4; ++nf)
        acc[mf][nf] = __builtin_amdgcn_mfma_f32_16x16x32_bf16(
            af[mf], bfv[nf], acc[mf][nf], 0, 0, 0);
    __syncthreads();
  }
}

__global__ __launch_bounds__(256) void gemm3_kernel(
    const __bf16* __restrict__ A0, const __bf16* __restrict__ A1,
    const __bf16* __restrict__ A2, const __bf16* __restrict__ B0,
    const __bf16* __restrict__ B1, const __bf16* __restrict__ B2,
    __bf16* __restrict__ C0, __bf16* __restrict__ C1, __bf16* __restrict__ C2) {
  const int z = blockIdx.z;
  const __bf16* A = z == 0 ? A0 : (z == 1 ? A1 : A2);
  const __bf16* B = z == 0 ? B0 : (z == 1 ? B1 : B2);
  __bf16* C = z == 0 ? C0 : (z == 1 ? C1 : C2);
  const int row0 = blockIdx.x * 128, col0 = blockIdx.y * 128;
  f32x4 acc[4][4] = {};
  gemm_tile(A, B, Dn, row0, col0, acc);
  const int lane = threadIdx.x & 63, wid = threadIdx.x >> 6;
  const int wm = (wid >> 1) * 64, wn = (wid & 1) * 64;
#pragma unroll
  for (int mf = 0; mf < 4; ++mf) {
    const int r0 = row0 + wm + mf * 16 + ((lane >> 4) << 2);
#pragma unroll
    for (int nf = 0; nf < 4; ++nf) {
      const int c0 = col0 + wn + nf * 16 + (lane & 15);
#pragma unroll
      for (int rg = 0; rg < 4; ++rg)
        C[(size_t)(r0 + rg) * Dn + c0] = (__bf16)acc[mf][nf][rg];
    }
  }
}

// LoRA stage-1 as MFMA GEMM
__global__ __launch_bounds__(256) void gemm_l1_kernel(
    const __bf16* __restrict__ Aw, const __bf16* __restrict__ Aa,
    const __bf16* __restrict__ Av, const __bf16* __restrict__ Ag,
    const __bf16* __restrict__ Bw, const __bf16* __restrict__ Ba,
    const __bf16* __restrict__ Bv, const __bf16* __restrict__ Bg,
    __bf16* __restrict__ Cw, __bf16* __restrict__ Ca,
    __bf16* __restrict__ Cv, __bf16* __restrict__ Cg) {
  const int z = blockIdx.z;
  const __bf16* A = z == 0 ? Aw : (z == 1 ? Aa : (z == 2 ? Av : Ag));
  const __bf16* B = z == 0 ? Bw : (z == 1 ? Ba : (z == 2 ? Bv : Bg));
  __bf16* C = z == 0 ? Cw : (z == 1 ? Ca : (z == 2 ? Cv : Cg));
  const int row0 = blockIdx.x * 128;
  f32x4 acc[4][4] = {};
  gemm_tile(A, B, Dn, row0, 0, acc);
  const int lane = threadIdx.x & 63, wid = threadIdx.x >> 6;
  const int wm = (wid >> 1) * 64, wn = (wid & 1) * 64;
#pragma unroll
  for (int mf = 0; mf < 4; ++mf) {
    const int r0 = row0 + wm + mf * 16 + ((lane >> 4) << 2);
#pragma unroll
    for (int nf = 0; nf < 4; ++nf) {
      const int c0 = wn + nf * 16 + (lane & 15);
#pragma unroll
      for (int rg = 0; rg < 4; ++rg) {
        float val = acc[mf][nf][rg];
        if (z == 0)      val = tanhf(val);
        else if (z == 3) val = sigm(val);
        C[(size_t)(r0 + rg) * 128 + c0] = (__bf16)val;
      }
    }
  }
}

// LoRA stage-2 fused, uniform K=128 (zero-padded)
__global__ __launch_bounds__(256) void gemm_s2_kernel(
    const __bf16* __restrict__ Aw, const __bf16* __restrict__ Aa,
    const __bf16* __restrict__ Av, const __bf16* __restrict__ Ag,
    const __bf16* __restrict__ Bw, const __bf16* __restrict__ Ba,
    const __bf16* __restrict__ Bv, const __bf16* __restrict__ Bg,
    const float* __restrict__ w0, const float* __restrict__ a0,
    const float* __restrict__ v0, __bf16* __restrict__ Cw,
    __bf16* __restrict__ Ca, __bf16* __restrict__ Cv, __bf16* __restrict__ Cg) {
  const int z = blockIdx.z;
  const __bf16* A = z == 0 ? Aw : (z == 1 ? Aa : (z == 2 ? Av : Ag));
  const __bf16* B = z == 0 ? Bw : (z == 1 ? Ba : (z == 2 ? Bv : Bg));
  const float* bias = z == 0 ? w0 : (z == 1 ? a0 : (z == 2 ? v0 : (const float*)0));
  __bf16* C = z == 0 ? Cw : (z == 1 ? Ca : (z == 2 ? Cv : Cg));
  const int row0 = blockIdx.x * 128, col0 = blockIdx.y * 128;
  f32x4 acc[4][4] = {};
  gemm_tile(A, B, 128, row0, col0, acc);
  const int lane = threadIdx.x & 63, wid = threadIdx.x >> 6;
  const int wm = (wid >> 1) * 64, wn = (wid & 1) * 64;
#pragma unroll
  for (int mf = 0; mf < 4; ++mf) {
    const int r0 = row0 + wm + mf * 16 + ((lane >> 4) << 2);
#pragma unroll
    for (int nf = 0; nf < 4; ++nf) {
      const int c0 = col0 + wn + nf * 16 + (lane & 15);
#pragma unroll
      for (int rg = 0; rg < 4; ++rg) {
        float val = acc[mf][nf][rg];
        if (z == 0)      val = expf(-0.606531f * sigm(val + bias[c0]));
        else if (z < 3)  val = sigm(val + bias[c0]);
        C[(size_t)(r0 + rg) * Dn + c0] = (__bf16)val;
      }
    }
  }
}

__global__ __launch_bounds__(256) void gemm_wo_kernel(
    const __bf16* __restrict__ A, const __bf16* __restrict__ B,
    const float* __restrict__ xres, float* __restrict__ C) {
  const int row0 = blockIdx.x * 128, col0 = blockIdx.y * 128;
  f32x4 acc[4][4] = {};
  gemm_tile(A, B, Dn, row0, col0, acc);
  const int lane = threadIdx.x & 63, wid = threadIdx.x >> 6;
  const int wm = (wid >> 1) * 64, wn = (wid & 1) * 64;
#pragma unroll
  for (int mf = 0; mf < 4; ++mf) {
    const int r0 = row0 + wm + mf * 16 + ((lane >> 4) << 2);
#pragma unroll
    for (int nf = 0; nf < 4; ++nf) {
      const int c0 = col0 + wn + nf * 16 + (lane & 15);
#pragma unroll
      for (int rg = 0; rg < 4; ++rg)
        C[(size_t)(r0 + rg) * Dn + c0] =
            acc[mf][nf][rg] + xres[(size_t)(r0 + rg) * Dn + c0];
    }
  }
}

// ---------------- prep ----------------

__global__ __launch_bounds__(256) void prep_kernel(
    const __bf16* __restrict__ r, __bf16* __restrict__ k, __bf16* __restrict__ v,
    const __bf16* __restrict__ a, const __bf16* __restrict__ vb,
    const float* __restrict__ v_first, const float* __restrict__ k_k,
    const float* __restrict__ k_a, const float* __restrict__ r_k,
    __bf16* __restrict__ kk_out, __bf16* __restrict__ ab_out,
    float* __restrict__ dot_out) {
  const int t = blockIdx.x;
  const int lane = threadIdx.x & 63, wv = threadIdx.x >> 6;
#pragma unroll 1
  for (int c = 0; c < 8; ++c) {
    const int d = c * 256 + wv * 64 + lane;
    const size_t idx = (size_t)t * Dn + d;
    const float kvv = (float)k[idx];
    const float kh = kvv * k_k[d];
    const float nrm = sqrtf(waveSum(kh * kh)) + 1e-6f;
    const float kkv = kh / nrm;
    const float av = (float)a[idx];
    float vv = (float)v[idx];
    vv = vv + (v_first[idx] - vv) * (float)vb[idx];
    const float kfv = kvv * (1.f + (av - 1.f) * k_a[d]);
    const float dt = waveSum((float)r[idx] * kfv * r_k[d]);
    kk_out[idx] = (__bf16)kkv;
    ab_out[idx] = (__bf16)(kkv * av);
    k[idx] = (__bf16)kfv;
    v[idx] = (__bf16)vv;
    if (lane == 0) dot_out[t * Hn + (d >> 6)] = dt;
  }
}

// ---------------- chunkA: decay mats + triangular inverse; transposed Bh/Kh ----------------

__global__ __launch_bounds__(256) void chunkA_kernel(
    const __bf16* __restrict__ wd, const __bf16* __restrict__ kk,
    const __bf16* __restrict__ ab, const __bf16* __restrict__ kf,
    const __bf16* __restrict__ r,
    __bf16* __restrict__ Atil, __bf16* __restrict__ Rtil,
    __bf16* __restrict__ BhatT, __bf16* __restrict__ KhatT,
    __bf16* __restrict__ Pg, __bf16* __restrict__ PKg,
    __bf16* __restrict__ Gbg, __bf16* __restrict__ Gkg,
    float* __restrict__ WCg) {
  const int c = blockIdx.x, h = blockIdx.y;
  const int tid = threadIdx.x;
  __shared__ __bf16 A_l[32][72];
  __shared__ __bf16 B_l[32][72], K_l[32][72], R_l[32][72];
  __shared__ float W_l[33][64];
  __shared__ float Mba[32][36], Mka[32][36];
  __shared__ float P0[32][36], P1[32][36], T0[32][36], T1[32][36];

  const size_t rowbase = (size_t)(c * Cn) * Dn + (size_t)h * 64;
  const int tt = tid >> 3, j0 = (tid & 7) * 8;
  const size_t g = rowbase + (size_t)tt * Dn + j0;
  *(bf16x8*)&A_l[tt][j0] = *(const bf16x8*)(wd + g);
  __syncthreads();
  if (tid < 64) {
    const int j = tid;
    float cur = 1.f;
    W_l[0][j] = 1.f;
    for (int t = 0; t < Cn; ++t) {
      cur *= (float)A_l[t][j];
      W_l[t + 1][j] = cur;
    }
    WCg[((size_t)c * Hn + h) * 64 + j] = cur;
  }
  __syncthreads();
  {
    bf16x8 kkv = *(const bf16x8*)(kk + g);
    bf16x8 abv = *(const bf16x8*)(ab + g);
    bf16x8 kv  = *(const bf16x8*)(kf + g);
    bf16x8 rv  = *(const bf16x8*)(r + g);
    bf16x8 oa, ob, ok, orr;
    const size_t tb = ((size_t)c * Hn + h) * 2048;
#pragma unroll
    for (int e = 0; e < 8; ++e) {
      const int j = j0 + e;
      const float Wexc = W_l[tt][j], Winc = W_l[tt + 1][j], WC = W_l[32][j];
      const float inv = 1.f / Winc;
      const float at = -(float)kkv[e] * Wexc;
      const float bt = (float)abv[e] * inv;
      const float kt = (float)kv[e] * inv;
      const float rt = (float)rv[e] * Winc;
      oa[e] = (__bf16)at; ob[e] = (__bf16)bt; ok[e] = (__bf16)kt;
      orr[e] = (__bf16)rt;
      BhatT[tb + (size_t)j * 32 + tt] = (__bf16)(bt * WC);
      KhatT[tb + (size_t)j * 32 + tt] = (__bf16)(kt * WC);
    }
    *(bf16x8*)&A_l[tt][j0] = oa;
    *(bf16x8*)&B_l[tt][j0] = ob;
    *(bf16x8*)&K_l[tt][j0] = ok;
    *(bf16x8*)&R_l[tt][j0] = orr;
    *(bf16x8*)(Atil + g) = oa;
    *(bf16x8*)(Rtil + g) = orr;
  }
  __syncthreads();
  const size_t matbase = ((size_t)c * Hn + h) * (Cn * Cn);
#pragma unroll 1
  for (int rep = 0; rep < 4; ++rep) {
    const int id = rep * 256 + tid;
    const int t = id >> 5, ta = id & 31;
    float d_ab = 0.f, d_ak = 0.f, d_rb = 0.f, d_rk = 0.f;
    for (int j8 = 0; j8 < 8; ++j8) {
      const bf16x8 av = *(const bf16x8*)&A_l[t][j8 * 8];
      const bf16x8 rv = *(const bf16x8*)&R_l[t][j8 * 8];
      const bf16x8 bv = *(const bf16x8*)&B_l[ta][j8 * 8];
      const bf16x8 kv = *(const bf16x8*)&K_l[ta][j8 * 8];
#pragma unroll
      for (int e = 0; e < 8; ++e) {
        const float af = (float)av[e], rf = (float)rv[e];
        const float bf2 = (float)bv[e], kf2 = (float)kv[e];
        d_ab += af * bf2; d_ak += af * kf2;
        d_rb += rf * bf2; d_rk += rf * kf2;
      }
    }
    Mba[t][ta] = (ta < t) ? d_ab : 0.f;
    Mka[t][ta] = (ta < t) ? d_ak : 0.f;
    Gbg[matbase + id] = (__bf16)((ta <= t) ? d_rb : 0.f);
    Gkg[matbase + id] = (__bf16)((ta <= t) ? d_rk : 0.f);
  }
  __syncthreads();
  for (int rep = 0; rep < 4; ++rep) {
    const int id = rep * 256 + tid;
    const int t = id >> 5, ta = id & 31;
    P0[t][ta] = Mba[t][ta] + (t == ta ? 1.f : 0.f);
  }
  __syncthreads();
  auto mm = [&](float (*D)[36], float (*Aa)[36], float (*Bb)[36]) {
    for (int rep = 0; rep < 4; ++rep) {
      const int id = rep * 256 + tid;
      const int t = id >> 5, ta = id & 31;
      float s = 0.f;
      for (int u = 0; u < 32; ++u) s += Aa[t][u] * Bb[u][ta];
      D[t][ta] = s;
    }
    __syncthreads();
  };
  auto mmadd = [&](float (*D)[36], float (*Pp)[36], float (*Tt)[36]) {
    for (int rep = 0; rep < 4; ++rep) {
      const int id = rep * 256 + tid;
      const int t = id >> 5, ta = id & 31;
      float s = Pp[t][ta];
      for (int u = 0; u < 32; ++u) s += Pp[t][u] * Tt[u][ta];
      D[t][ta] = s;
    }
    __syncthreads();
  };
  mm(T0, Mba, Mba);
  mmadd(P1, P0, T0);
  mm(T1, T0, T0);
  mmadd(P0, P1, T1);
  mm(T0, T1, T1);
  mmadd(P1, P0, T0);
  mm(T1, T0, T0);
  mmadd(P0, P1, T1);
  for (int rep = 0; rep < 4; ++rep) {
    const int id = rep * 256 + tid;
    const int t = id >> 5, ta = id & 31;
    Pg[matbase + id] = (__bf16)P0[t][ta];
    float s = 0.f;
    for (int u = 0; u < 32; ++u) s += P0[t][u] * Mka[u][ta];
    PKg[matbase + id] = (__bf16)s;
  }
}

// ---------------- vt: vbuf [t][D] -> Vt [c][h][i][t] ----------------

__global__ __launch_bounds__(256) void vt_kernel(
    const __bf16* __restrict__ vbuf, __bf16* __restrict__ Vt) {
  const int c = blockIdx.x, h = blockIdx.y;
  __shared__ __bf16 tile[32][72];
  const int tid = threadIdx.x;
  {
    const int t = tid >> 3, i0 = (tid & 7) * 8;
    *(bf16x8*)&tile[t][i0] =
        *(const bf16x8*)(vbuf + (size_t)(c * Cn + t) * Dn + h * 64 + i0);
  }
  __syncthreads();
  {
    const int i = tid >> 2, t0 = (tid & 3) * 8;
    bf16x8 o;
#pragma unroll
    for (int e = 0; e < 8; ++e) o[e] = tile[t0 + e][i];
    *(bf16x8*)(Vt + ((size_t)c * Hn + h) * 2048 + (size_t)i * 32 + t0) = o;
  }
}

// ---------------- chunkB: MFMA formulation, 64 blocks (head x i-half) ----------------

__global__ __launch_bounds__(256) void chunkB_kernel(
    const __bf16* __restrict__ Atil, const __bf16* __restrict__ Rtil,
    const __bf16* __restrict__ BhatT, const __bf16* __restrict__ KhatT,
    const __bf16* __restrict__ Pg, const __bf16* __restrict__ PKg,
    const __bf16* __restrict__ Gbg, const __bf16* __restrict__ Gkg,
    const float* __restrict__ WCg, const __bf16* __restrict__ Vt,
    const float* __restrict__ st_in, __bf16* __restrict__ xo,
    float* __restrict__ st_out) {
  const int b = blockIdx.x;              // 64 = 8 xcd * 4 heads * 2 io
  const int xcd = b & 7, rest = b >> 3;
  const int h = xcd * 4 + (rest & 3);
  const int io = (rest >> 2) * 32;
  const int tid = threadIdx.x;
  const int lane = tid & 63, wid = tid >> 6;
  const int lr = lane & 15, lg = lane >> 4;   // frag row / k-group
  const int lk = lg * 8;

  __shared__ __attribute__((aligned(16))) float S_l[32][68];
  __shared__ __attribute__((aligned(16))) __bf16 Sb_l[32][72];
  __shared__ __attribute__((aligned(16))) __bf16 A_l[32][72], R_l[32][72];
  __shared__ __attribute__((aligned(16))) __bf16 BhT_l[64][40], KhT_l[64][40];
  __shared__ __attribute__((aligned(16))) __bf16 Vt_l[32][40];
  __shared__ __attribute__((aligned(16))) __bf16 P_l[32][40], PK_l[32][40];
  __shared__ __attribute__((aligned(16))) __bf16 Gb_l[32][40], Gk_l[32][40];
  __shared__ __attribute__((aligned(16))) __bf16 X_l[32][40], SA_l[32][40];
  __shared__ float WC_l[64];

  // initial S rows [io..io+32)
  {
    const int i = tid >> 3, j0 = (tid & 7) * 8;
    const float* src = st_in + (size_t)h * 4096 + (size_t)(io + i) * 64 + j0;
    *(f32x4*)&S_l[i][j0] = *(const f32x4*)src;
    *(f32x4*)&S_l[i][j0 + 4] = *(const f32x4*)(src + 4);
  }

  bf16x8 rA, rR, rBh, rKh;
  bf16x4 rV, rP, rPK, rGb, rGk;
  float rWC = 0.f;

  auto load_regs = [&](int c) {
    const size_t rb = (size_t)(c * Cn) * Dn + (size_t)h * 64;
    {
      const int t = tid >> 3, j0 = (tid & 7) * 8;
      rA = *(const bf16x8*)(Atil + rb + (size_t)t * Dn + j0);
      rR = *(const bf16x8*)(Rtil + rb + (size_t)t * Dn + j0);
    }
    const size_t tb = ((size_t)c * Hn + h) * 2048;
    {
      const int jj = tid >> 2, t0 = (tid & 3) * 8;
      rBh = *(const bf16x8*)(BhatT + tb + (size_t)jj * 32 + t0);
      rKh = *(const bf16x8*)(KhatT + tb + (size_t)jj * 32 + t0);
    }
    {
      const int i = tid >> 3, t0 = (tid & 7) * 4;
      rV = *(const bf16x4*)(Vt + tb + (size_t)(io + i) * 32 + t0);
    }
    const size_t mb = ((size_t)c * Hn + h) * 1024 + (size_t)tid * 4;
    rP  = *(const bf16x4*)(Pg + mb);
    rPK = *(const bf16x4*)(PKg + mb);
    rGb = *(const bf16x4*)(Gbg + mb);
    rGk = *(const bf16x4*)(Gkg + mb);
    if (tid < 64) rWC = WCg[((size_t)c * Hn + h) * 64 + tid];
  };
  auto store_lds = [&]() {
    {
      const int t = tid >> 3, j0 = (tid & 7) * 8;
      *(bf16x8*)&A_l[t][j0] = rA;
      *(bf16x8*)&R_l[t][j0] = rR;
    }
    {
      const int jj = tid >> 2, t0 = (tid & 3) * 8;
      *(bf16x8*)&BhT_l[jj][t0] = rBh;
      *(bf16x8*)&KhT_l[jj][t0] = rKh;
    }
    {
      const int i = tid >> 3, t0 = (tid & 7) * 4;
      *(bf16x4*)&Vt_l[i][t0] = rV;
    }
    {
      const int t = tid >> 3, u0 = (tid & 7) * 4;
      *(bf16x4*)&P_l[t][u0] = rP;
      *(bf16x4*)&PK_l[t][u0] = rPK;
      *(bf16x4*)&Gb_l[t][u0] = rGb;
      *(bf16x4*)&Gk_l[t][u0] = rGk;
    }
    if (tid < 64) WC_l[tid] = rWC;
  };
  auto sb_refresh = [&]() {
    const int i = tid >> 3, j0 = (tid & 7) * 8;
    bf16x8 o;
#pragma unroll
    for (int e = 0; e < 8; ++e) o[e] = (__bf16)S_l[i][j0 + e];
    *(bf16x8*)&Sb_l[i][j0] = o;
  };

  load_regs(0);
  store_lds();
  sb_refresh();   // same-thread S_l rows: no barrier needed before
  bar_lgkm();

  const int tm = (wid >> 1) * 16, tn = (wid & 1) * 16;  // t-tile / i-tile

#pragma unroll 1
  for (int c = 0; c < NCH; ++c) {
    load_regs(c + 1 < NCH ? c + 1 : c);   // prefetch; stays in flight
    // X = Atil * Sb^T   (C[t][i], stored transposed X_l[i][t])
    {
      f32x4 acc = {};
      acc = mfma16(&A_l[tm + lr][lk], &Sb_l[tn + lr][lk], acc);
      acc = mfma16(&A_l[tm + lr][32 + lk], &Sb_l[tn + lr][32 + lk], acc);
      bf16x4 o;
#pragma unroll
      for (int e = 0; e < 4; ++e) o[e] = (__bf16)acc[e];
      *(bf16x4*)&X_l[tn + lr][tm + lg * 4] = o;
    }
    bar_lgkm();
    // SA = P*X + PK*V   (C[t][i], stored transposed SA_l[i][t])
    {
      f32x4 acc = {};
      acc = mfma16(&P_l[tm + lr][lk], &X_l[tn + lr][lk], acc);
      acc = mfma16(&PK_l[tm + lr][lk], &Vt_l[tn + lr][lk], acc);
      bf16x4 o;
#pragma unroll
      for (int e = 0; e < 4; ++e) o[e] = (__bf16)acc[e];
      *(bf16x4*)&SA_l[tn + lr][tm + lg * 4] = o;
    }
    bar_lgkm();
    // O = Gb*SA + Gk*V + Rtil*Sb^T  -> global
    {
      f32x4 acc = {};
      acc = mfma16(&Gb_l[tm + lr][lk], &SA_l[tn + lr][lk], acc);
      acc = mfma16(&Gk_l[tm + lr][lk], &Vt_l[tn + lr][lk], acc);
      acc = mfma16(&R_l[tm + lr][lk], &Sb_l[tn + lr][lk], acc);
      acc = mfma16(&R_l[tm + lr][32 + lk], &Sb_l[tn + lr][32 + lk], acc);
      const int ig = h * 64 + io + tn + lr;
#pragma unroll
      for (int e = 0; e < 4; ++e)
        xo[(size_t)(c * Cn + tm + lg * 4 + e) * Dn + ig] = (__bf16)acc[e];
    }
    // S' = S.*WC + SA^T*Bh + V^T*Kh  (C[i][j] in f32 S_l; tiles disjoint per wave)
#pragma unroll
    for (int tt = 0; tt < 2; ++tt) {
      const int tix = wid + tt * 4;
      const int im = (tix & 1) * 16, jn = (tix >> 1) * 16;
      const float wc = WC_l[jn + lr];
      f32x4 acc;
#pragma unroll
      for (int e = 0; e < 4; ++e) acc[e] = S_l[im + lg * 4 + e][jn + lr] * wc;
      acc = mfma16(&SA_l[im + lr][lk], &BhT_l[jn + lr][lk], acc);
      acc = mfma16(&Vt_l[im + lr][lk], &KhT_l[jn + lr][lk], acc);
#pragma unroll
      for (int e = 0; e < 4; ++e) S_l[im + lg * 4 + e][jn + lr] = acc[e];
    }
    bar_lgkm();
    store_lds();     // consume prefetched regs (vmcnt wait lands here)
    sb_refresh();    // same-thread rows of updated S_l
    bar_lgkm();
  }
  {
    const int i = tid >> 3, j0 = (tid & 7) * 8;
    float* dst = st_out + (size_t)h * 4096 + (size_t)(io + i) * 64 + j0;
    *(f32x4*)dst = *(const f32x4*)&S_l[i][j0];
    *(f32x4*)(dst + 4) = *(const f32x4*)&S_l[i][j0 + 4];
  }
}

// ---------------- post ----------------

__global__ __launch_bounds__(256) void post_kernel(
    const __bf16* __restrict__ xo, const __bf16* __restrict__ v,
    const __bf16* __restrict__ g, const float* __restrict__ dot,
    const float* __restrict__ lnw, const float* __restrict__ lnb,
    __bf16* __restrict__ out) {
  const int t = blockIdx.x;
  const int lane = threadIdx.x & 63, wv = threadIdx.x >> 6;
#pragma unroll 1
  for (int c = 0; c < 8; ++c) {
    const int d = c * 256 + wv * 64 + lane;
    const size_t idx = (size_t)t * Dn + d;
    const float val = (float)xo[idx];
    const float mu = waveSum(val) * (1.f / 64.f);
    const float ctr = val - mu;
    const float var = waveSum(ctr * ctr) * (1.f / 64.f);
    float y = ctr * rsqrtf(var + 0.00064f);
    y = y * lnw[d] + lnb[d];
    const float res = (y + dot[t * Hn + (d >> 6)] * (float)v[idx]) * (float)g[idx];
    out[idx] = (__bf16)res;
  }
}

// ---------------- launcher ----------------

extern "C" void kernel_launch(void* const* d_in, const int* in_sizes, int n_in,
                              void* d_out, int out_size, void* d_ws, size_t ws_size,
                              hipStream_t stream) {
  (void)in_sizes; (void)n_in; (void)out_size; (void)ws_size;
  const float* x       = (const float*)d_in[0];
  const float* state1  = (const float*)d_in[1];
  const float* state2  = (const float*)d_in[2];
  const float* v_first = (const float*)d_in[3];
  const float* ln1_w   = (const float*)d_in[4];
  const float* ln1_b   = (const float*)d_in[5];
  const float* x_r     = (const float*)d_in[6];
  const float* x_w     = (const float*)d_in[7];
  const float* x_k     = (const float*)d_in[8];
  const float* x_v     = (const float*)d_in[9];
  const float* x_a     = (const float*)d_in[10];
  const float* x_g     = (const float*)d_in[11];
  const float* W_r     = (const float*)d_in[12];
  const float* W_k     = (const float*)d_in[13];
  const float* W_v     = (const float*)d_in[14];
  const float* W_o     = (const float*)d_in[15];
  const float* w1      = (const float*)d_in[16];
  const float* w2      = (const float*)d_in[17];
  const float* w0      = (const float*)d_in[18];
  const float* a1      = (const float*)d_in[19];
  const float* a2      = (const float*)d_in[20];
  const float* a0      = (const float*)d_in[21];
  const float* v1      = (const float*)d_in[22];
  const float* v2      = (const float*)d_in[23];
  const float* v0      = (const float*)d_in[24];
  const float* g1      = (const float*)d_in[25];
  const float* g2      = (const float*)d_in[26];
  const float* k_k     = (const float*)d_in[27];
  const float* k_a     = (const float*)d_in[28];
  const float* r_k     = (const float*)d_in[29];
  const float* lnx_w   = (const float*)d_in[30];
  const float* lnx_b   = (const float*)d_in[31];

  char* p = (char*)d_ws;
  const size_t MB = 1ull << 20;
  __bf16* xn    = (__bf16*)(p + 0 * MB);
  __bf16* Atil  = (__bf16*)(p + 0 * MB);
  __bf16* xr_b  = (__bf16*)(p + 8 * MB);
  __bf16* Wo_b  = (__bf16*)(p + 8 * MB);
  __bf16* xw_b  = (__bf16*)(p + 16 * MB);
  __bf16* wdec  = (__bf16*)(p + 16 * MB);
  __bf16* xo_b  = (__bf16*)(p + 16 * MB);
  __bf16* xk_b  = (__bf16*)(p + 24 * MB);
  __bf16* abuf  = (__bf16*)(p + 24 * MB);
  __bf16* Rtil  = (__bf16*)(p + 24 * MB);
  __bf16* xv_b  = (__bf16*)(p + 32 * MB);
  __bf16* vbl   = (__bf16*)(p + 32 * MB);
  __bf16* BhatT = (__bf16*)(p + 32 * MB);
  __bf16* xa_b  = (__bf16*)(p + 40 * MB);
  __bf16* gbuf  = (__bf16*)(p + 40 * MB);
  __bf16* xg_b  = (__bf16*)(p + 48 * MB);
  __bf16* kkbuf = (__bf16*)(p + 48 * MB);
  __bf16* xobuf = (__bf16*)(p + 48 * MB);
  __bf16* Wr_b  = (__bf16*)(p + 56 * MB);
  __bf16* abbuf = (__bf16*)(p + 56 * MB);
  __bf16* Wk_b  = (__bf16*)(p + 64 * MB);
  __bf16* KhatT = (__bf16*)(p + 64 * MB);
  __bf16* Wv_b  = (__bf16*)(p + 72 * MB);
  __bf16* Pg    = (__bf16*)(p + 72 * MB);
  __bf16* PKg   = (__bf16*)(p + 76 * MB);
  __bf16* rbuf  = (__bf16*)(p + 80 * MB);
  __bf16* kbuf  = (__bf16*)(p + 88 * MB);
  __bf16* Vt    = (__bf16*)(p + 88 * MB);   // kbuf dead after chunkA; vt runs after
  __bf16* vbuf  = (__bf16*)(p + 96 * MB);
  __bf16* Gbg   = (__bf16*)(p + 104 * MB);
  __bf16* Gkg   = (__bf16*)(p + 108 * MB);
  char* q = p + 112 * MB;
  __bf16* yw  = (__bf16*)q; q += (size_t)Tn * 128 * 2;
  __bf16* ya  = (__bf16*)q; q += (size_t)Tn * 128 * 2;
  __bf16* yv  = (__bf16*)q; q += (size_t)Tn * 128 * 2;
  __bf16* yg  = (__bf16*)q; q += (size_t)Tn * 128 * 2;
  __bf16* uwT = (__bf16*)q; q += (size_t)128 * Dn * 2;
  __bf16* uaT = (__bf16*)q; q += (size_t)128 * Dn * 2;
  __bf16* uvT = (__bf16*)q; q += (size_t)128 * Dn * 2;
  __bf16* ugT = (__bf16*)q; q += (size_t)128 * Dn * 2;
  __bf16* w2T = (__bf16*)q; q += (size_t)Dn * 128 * 2;
  __bf16* a2T = (__bf16*)q; q += (size_t)Dn * 128 * 2;
  __bf16* v2T = (__bf16*)q; q += (size_t)Dn * 128 * 2;
  __bf16* g2T = (__bf16*)q; q += (size_t)Dn * 128 * 2;
  float*  dot = (float*)q;  q += (size_t)Tn * Hn * 4;
  float*  WCg = (float*)q;  q += (size_t)NCH * Hn * 64 * 4;

  float* out     = (float*)d_out;
  float* out_xnl = out + (size_t)Tn * Dn;
  float* out_st  = out_xnl + Dn;

  castw3_kernel<<<dim3(4096, 3), 256, 0, stream>>>(W_r, W_k, W_v, Wr_b, Wk_b, Wv_b);
  castT_kernel<<<2048, 256, 0, stream>>>(w2, a2, v2, g2, w2T, a2T, v2T, g2T);
  castU_kernel<<<dim3(2048, 4), 256, 0, stream>>>(w1, a1, v1, g1, uwT, uaT, uvT, ugT);
  ln_kernel<<<2048, 256, 0, stream>>>(x, ln1_w, ln1_b, xn, out_xnl);
  mix_kernel<<<4096, 256, 0, stream>>>(xn, state1, x_r, x_w, x_k, x_v, x_a, x_g,
                                       xr_b, xw_b, xk_b, xv_b, xa_b, xg_b);
  gemm3_kernel<<<dim3(16, 16, 3), 256, 0, stream>>>(
      xr_b, xk_b, xv_b, Wr_b, Wk_b, Wv_b, rbuf, kbuf, vbuf);
  cast1_kernel<<<4096, 256, 0, stream>>>(W_o, Wo_b);
  gemm_l1_kernel<<<dim3(16, 1, 4), 256, 0, stream>>>(
      xw_b, xa_b, xv_b, xg_b, uwT, uaT, uvT, ugT, yw, ya, yv, yg);
  gemm_s2_kernel<<<dim3(16, 16, 4), 256, 0, stream>>>(
      yw, ya, yv, yg, w2T, a2T, v2T, g2T, w0, a0, v0, wdec, abuf, vbl, gbuf);
  prep_kernel<<<2048, 256, 0, stream>>>(rbuf, kbuf, vbuf, abuf, vbl, v_first,
                                        k_k, k_a, r_k, kkbuf, abbuf, dot);
  chunkA_kernel<<<dim3(NCH, Hn), 256, 0, stream>>>(
      wdec, kkbuf, abbuf, kbuf, rbuf,
      Atil, Rtil, BhatT, KhatT, Pg, PKg, Gbg, Gkg, WCg);
  vt_kernel<<<dim3(NCH, Hn), 256, 0, stream>>>(vbuf, Vt);
  chunkB_kernel<<<64, 256, 0, stream>>>(
      Atil, Rtil, BhatT, KhatT, Pg, PKg, Gbg, Gkg, WCg, Vt,
      state2, xobuf, out_st);
  post_kernel<<<2048, 256, 0, stream>>>(xobuf, vbuf, gbuf, dot, lnx_w, lnx_b, xo_b);
  gemm_wo_kernel<<<dim3(16, 16), 256, 0, stream>>>(xo_b, Wo_b, x, out);
}